// Round 8
// baseline (367.023 us; speedup 1.0000x reference)
//
#include <hip/hip_runtime.h>
#include <math.h>

// Batched 10-qubit statevector sim: one wave per batch element.
// State = 1024 complex amps = 16 (sr,si) float pairs per lane.
// Amp index a = (lane << 4) | r. Wire w acts on amp bit 9-w:
//   bit>=4 (lane bit b-4): wire0 permlane32-pair, wire1 permlane16-pair,
//     wire2 fmac+DPP row_ror:8, wire3 masked-DPP xor4 (NEW: was ds_swizzle),
//     wire4 fmac+DPP quad[2,3,0,1], wire5 fmac+DPP quad[1,0,3,2]
//   bit<4: in-register local shear.
// Round-8 experiment: remove the DS pipe from the hot loop. Round-7 counters
// fit a DS<->VALU convoy model (VALU 352k cyc/SIMD + DS 333k cyc/CU ~= 775k
// measured): all waves lockstep into wire-3's ds burst, serializing pipes.
// Wire-3 partner (lane^4) now via TWO bank-masked DPP movs
//   (row_ror:12 bank_mask:0x5 -> lanes bit2=0 get src i+4;
//    row_ror:4  bank_mask:0xA -> lanes bit2=1 get src i-4; update_dpp merges)
// + 1 fmac: 3 VALU/float, 0 ds. Everything else identical to round 7.

typedef unsigned int u32;

constexpr int NQ = 10;
constexpr int NCLS = 16;

__device__ __forceinline__ float i2f(int i) { return __builtin_bit_cast(float, i); }
__device__ __forceinline__ int   f2i(float f) { return __builtin_bit_cast(int, f); }
__device__ __forceinline__ u32   f2u(float f) { return __builtin_bit_cast(u32, f); }
__device__ __forceinline__ float u2f(u32 u)   { return __builtin_bit_cast(float, u); }

__device__ __forceinline__ float rdlane(float v, int l) {
    return i2f(__builtin_amdgcn_readlane(f2i(v), l));   // SALU broadcast
}

// ---- lane^4 partner via two bank-masked DPP movs (no DS op) ----
// Convention (GCN): row_ror:n -> dst lane i reads src lane (i-n)&15 in its row.
// bit2==0 lanes (banks 0,2 = mask 0x5) want i+4 == i-12 -> ror:12.
// bit2==1 lanes (banks 1,3 = mask 0xA) want i-4        -> ror:4.
__device__ __forceinline__ float xor4_dpp(float v) {
    const int i = f2i(v);
    int t = __builtin_amdgcn_update_dpp(i, i, 0x12C, 0xF, 0x5, false);
    t     = __builtin_amdgcn_update_dpp(t, i, 0x124, 0xF, 0xA, false);
    return i2f(t);
}

// ---- fused shear for DPP-able masks: st[k] += C * DPP(st[k]), 16 regs/block.
#define DPP16_LO(CTRL, C, sr, si) \
  asm("s_nop 1\n\t" \
      "v_fmac_f32 %0, %0, %16 "  CTRL "\n\t" \
      "v_fmac_f32 %1, %1, %16 "  CTRL "\n\t" \
      "v_fmac_f32 %2, %2, %16 "  CTRL "\n\t" \
      "v_fmac_f32 %3, %3, %16 "  CTRL "\n\t" \
      "v_fmac_f32 %4, %4, %16 "  CTRL "\n\t" \
      "v_fmac_f32 %5, %5, %16 "  CTRL "\n\t" \
      "v_fmac_f32 %6, %6, %16 "  CTRL "\n\t" \
      "v_fmac_f32 %7, %7, %16 "  CTRL "\n\t" \
      "v_fmac_f32 %8, %8, %16 "  CTRL "\n\t" \
      "v_fmac_f32 %9, %9, %16 "  CTRL "\n\t" \
      "v_fmac_f32 %10, %10, %16 " CTRL "\n\t" \
      "v_fmac_f32 %11, %11, %16 " CTRL "\n\t" \
      "v_fmac_f32 %12, %12, %16 " CTRL "\n\t" \
      "v_fmac_f32 %13, %13, %16 " CTRL "\n\t" \
      "v_fmac_f32 %14, %14, %16 " CTRL "\n\t" \
      "v_fmac_f32 %15, %15, %16 " CTRL \
      : "+v"(sr[0]),"+v"(sr[1]),"+v"(sr[2]),"+v"(sr[3]), \
        "+v"(sr[4]),"+v"(sr[5]),"+v"(sr[6]),"+v"(sr[7]), \
        "+v"(si[0]),"+v"(si[1]),"+v"(si[2]),"+v"(si[3]), \
        "+v"(si[4]),"+v"(si[5]),"+v"(si[6]),"+v"(si[7]) \
      : "v"(C))

#define DPP16_HI(CTRL, C, sr, si) \
  asm("s_nop 1\n\t" \
      "v_fmac_f32 %0, %0, %16 "  CTRL "\n\t" \
      "v_fmac_f32 %1, %1, %16 "  CTRL "\n\t" \
      "v_fmac_f32 %2, %2, %16 "  CTRL "\n\t" \
      "v_fmac_f32 %3, %3, %16 "  CTRL "\n\t" \
      "v_fmac_f32 %4, %4, %16 "  CTRL "\n\t" \
      "v_fmac_f32 %5, %5, %16 "  CTRL "\n\t" \
      "v_fmac_f32 %6, %6, %16 "  CTRL "\n\t" \
      "v_fmac_f32 %7, %7, %16 "  CTRL "\n\t" \
      "v_fmac_f32 %8, %8, %16 "  CTRL "\n\t" \
      "v_fmac_f32 %9, %9, %16 "  CTRL "\n\t" \
      "v_fmac_f32 %10, %10, %16 " CTRL "\n\t" \
      "v_fmac_f32 %11, %11, %16 " CTRL "\n\t" \
      "v_fmac_f32 %12, %12, %16 " CTRL "\n\t" \
      "v_fmac_f32 %13, %13, %16 " CTRL "\n\t" \
      "v_fmac_f32 %14, %14, %16 " CTRL "\n\t" \
      "v_fmac_f32 %15, %15, %16 " CTRL \
      : "+v"(sr[8]),"+v"(sr[9]),"+v"(sr[10]),"+v"(sr[11]), \
        "+v"(sr[12]),"+v"(sr[13]),"+v"(sr[14]),"+v"(sr[15]), \
        "+v"(si[8]),"+v"(si[9]),"+v"(si[10]),"+v"(si[11]), \
        "+v"(si[12]),"+v"(si[13]),"+v"(si[14]),"+v"(si[15]) \
      : "v"(C))

#define CTRL_QP1  "quad_perm:[1,0,3,2] row_mask:0xf bank_mask:0xf"   // lane^1
#define CTRL_QP2  "quad_perm:[2,3,0,1] row_mask:0xf bank_mask:0xf"   // lane^2
#define CTRL_ROR8 "row_ror:8 row_mask:0xf bank_mask:0xf"             // lane^8

// ---- permlane pair-trick shear (validated rounds 4-7) ----
template<int M>
__device__ __forceinline__ void pair_shear(float& a, float& b, float t) {
    if constexpr (M == 32) {
        auto p = __builtin_amdgcn_permlane32_swap(f2u(a), f2u(b), false, false);
        const float A = u2f(p[0]), B = u2f(p[1]);
        const float C = fmaf(-t, B, A);
        const float D = fmaf( t, A, B);
        auto q = __builtin_amdgcn_permlane32_swap(f2u(C), f2u(D), false, false);
        a = u2f(q[0]); b = u2f(q[1]);
    } else {
        auto p = __builtin_amdgcn_permlane16_swap(f2u(a), f2u(b), false, false);
        const float A = u2f(p[0]), B = u2f(p[1]);
        const float C = fmaf(-t, B, A);
        const float D = fmaf( t, A, B);
        auto q = __builtin_amdgcn_permlane16_swap(f2u(C), f2u(D), false, false);
        a = u2f(q[0]); b = u2f(q[1]);
    }
}

// ---- partner fetch (epilogue reductions only) ----
template<int MASK>
__device__ __forceinline__ float xp(float v, int lane) {
    if constexpr (MASK == 1) {
        int i = f2i(v);
        return i2f(__builtin_amdgcn_update_dpp(i, i, 0xB1, 0xF, 0xF, false));
    } else if constexpr (MASK == 2) {
        int i = f2i(v);
        return i2f(__builtin_amdgcn_update_dpp(i, i, 0x4E, 0xF, 0xF, false));
    } else if constexpr (MASK == 8) {
        int i = f2i(v);
        return i2f(__builtin_amdgcn_update_dpp(i, i, 0x128, 0xF, 0xF, false));
    } else if constexpr (MASK == 4) {
        return xor4_dpp(v);
    } else if constexpr (MASK == 16) {
        u32 u = f2u(v);
        auto pr = __builtin_amdgcn_permlane16_swap(u, u, false, false);
        return u2f((lane & 16) ? pr[0] : pr[1]);
    } else {  // MASK == 32
        u32 u = f2u(v);
        auto pr = __builtin_amdgcn_permlane32_swap(u, u, false, false);
        return u2f((lane & 32) ? pr[0] : pr[1]);
    }
}

// ---- local shear on r-bit B; NB = compile-time neighbor-sign mask (mod layers)
template<int B, int NB>
__device__ __forceinline__ void local_ry(float (&sr)[16], float (&si)[16], float t) {
#pragma unroll
    for (int r0 = 0; r0 < 16; ++r0) {
        if ((r0 & (1 << B)) == 0) {
            const int r1 = r0 | (1 << B);
            const float tt = (__builtin_popcount(r0 & NB) & 1) ? -t : t;
            const float a0 = sr[r0], a1 = sr[r1];
            sr[r0] = fmaf(-tt, a1, a0);
            sr[r1] = fmaf( tt, a0, a1);
            const float b0 = si[r0], b1 = si[r1];
            si[r0] = fmaf(-tt, b1, b0);
            si[r1] = fmaf( tt, b0, b1);
        }
    }
}

struct Sig { float g16, g53, g42, g31, g20, g1, g0; };

// One RY layer; MOD => CZ-conjugated (t sign-modulated by neighbor bits).
template<bool MOD>
__device__ __forceinline__ void ry_layer(float (&sr)[16], float (&si)[16],
                                         float tp, int base, int lane, const Sig& sg) {
    {   // wire 0: amp bit 9 (lane bit 5), permlane32 pair
        float t = rdlane(tp, base + 0);
        if constexpr (MOD) t *= sg.g16;
#pragma unroll
        for (int r = 0; r < 16; r += 2) {
            pair_shear<32>(sr[r], sr[r+1], t);
            pair_shear<32>(si[r], si[r+1], t);
        }
    }
    {   // wire 1: amp bit 8 (lane bit 4), permlane16 pair
        float t = rdlane(tp, base + 1);
        if constexpr (MOD) t *= sg.g53;
#pragma unroll
        for (int r = 0; r < 16; r += 2) {
            pair_shear<16>(sr[r], sr[r+1], t);
            pair_shear<16>(si[r], si[r+1], t);
        }
    }
    {   // wire 2: lane mask 8, fused fmac+DPP row_ror:8
        float t = rdlane(tp, base + 2);
        if constexpr (MOD) t *= sg.g42;
        const float ts = (lane & 8) ? t : -t;
        DPP16_LO(CTRL_ROR8, ts, sr, si);
        DPP16_HI(CTRL_ROR8, ts, sr, si);
    }
    {   // wire 3: lane mask 4 — masked-DPP xor4 partner, NO ds op
        float t = rdlane(tp, base + 3);
        if constexpr (MOD) t *= sg.g31;
        const float ts = (lane & 4) ? t : -t;
#pragma unroll
        for (int r = 0; r < 16; ++r) {
            sr[r] = fmaf(ts, xor4_dpp(sr[r]), sr[r]);
            si[r] = fmaf(ts, xor4_dpp(si[r]), si[r]);
        }
    }
    {   // wire 4: lane mask 2, fused fmac+DPP quad_perm
        float t = rdlane(tp, base + 4);
        if constexpr (MOD) t *= sg.g20;
        const float ts = (lane & 2) ? t : -t;
        DPP16_LO(CTRL_QP2, ts, sr, si);
        DPP16_HI(CTRL_QP2, ts, sr, si);
    }
    {   // wire 5: lane mask 1, fused fmac+DPP; MOD also flips by r-bit3 (hi half)
        float t = rdlane(tp, base + 5);
        if constexpr (MOD) t *= sg.g1;
        const float ts = (lane & 1) ? t : -t;
        const float th = MOD ? -ts : ts;
        DPP16_LO(CTRL_QP1, ts, sr, si);
        DPP16_HI(CTRL_QP1, th, sr, si);
    }
    {   // wire 6: r bit 3; MOD: lane-bit0 sign + r-bit2 sign
        float t = rdlane(tp, base + 6);
        if constexpr (MOD) t *= sg.g0;
        local_ry<3, MOD ? 0x4 : 0>(sr, si, t);
    }
    local_ry<2, MOD ? 0xA : 0>(sr, si, rdlane(tp, base + 7));   // wire 7
    local_ry<1, MOD ? 0x5 : 0>(sr, si, rdlane(tp, base + 8));   // wire 8
    local_ry<0, MOD ? 0x2 : 0>(sr, si, rdlane(tp, base + 9));   // wire 9
}

__global__ void __launch_bounds__(256) qnn_kernel(
    const float* __restrict__ x,       // (B, 10)
    const float* __restrict__ params,  // (6, 10)
    const float* __restrict__ w_cls,   // (16, 10)
    const float* __restrict__ b_cls,   // (16,)
    float* __restrict__ out,           // (B, 16)
    int batch)
{
    const int lane = threadIdx.x & 63;
    const int wid  = threadIdx.x >> 6;
    const int b    = blockIdx.x * (blockDim.x >> 6) + wid;
    if (b >= batch) return;

    // ---- encoding angles ----
    float cx, sx;
    { const int l = (lane < NQ) ? lane : 0; __sincosf(x[b * NQ + l] * 0.5f, &sx, &cx); }

    // ---- RY params: tan-shear coeffs + deferred cos product ----
    float cp, sp;
    { const int l = (lane < 60) ? lane : 0; __sincosf(params[l] * 0.5f, &sp, &cp); }
    const float tp  = sp / cp;
    const float cpv = (lane < 60) ? cp : 1.f;
    float Cw = cpv;
#pragma unroll
    for (int k = 0; k < 6; ++k) Cw *= __shfl_xor(Cw, 1 << k, 64);
    const float C2 = Cw * Cw;

    // ---- neighbor-sign factors for CZ-conjugated layers ----
    Sig sg;
    sg.g16 = (lane & 16) ? -1.f : 1.f;                           // w0: lane bit4
    sg.g53 = (((lane >> 5) ^ (lane >> 3)) & 1) ? -1.f : 1.f;     // w1: bits 5,3
    sg.g42 = (((lane >> 4) ^ (lane >> 2)) & 1) ? -1.f : 1.f;     // w2: bits 4,2
    sg.g31 = (((lane >> 3) ^ (lane >> 1)) & 1) ? -1.f : 1.f;     // w3: bits 3,1
    sg.g20 = (((lane >> 2) ^ lane) & 1) ? -1.f : 1.f;            // w4: bits 2,0
    sg.g1  = (lane & 2) ? -1.f : 1.f;                            // w5: lane bit1
    sg.g0  = (lane & 1) ? -1.f : 1.f;                            // w6: lane bit0

    // ---- product state with the absorbed initial CZ-sign C|enc> ----
    float F = 1.f;
#pragma unroll
    for (int q = 0; q < 6; ++q) {
        const float cq = rdlane(cx, q), sq = rdlane(sx, q);
        F *= ((lane >> (5 - q)) & 1) ? sq : cq;
    }
    const int lpar = __popc(lane & (lane >> 1) & 0x1F) & 1;      // lane-pair parity
    F = u2f(f2u(F) ^ (u32(lpar) << 31));
    const float c6 = rdlane(cx, 6), s6r = rdlane(sx, 6);
    const float c7 = rdlane(cx, 7), s7  = rdlane(sx, 7);
    const float c8 = rdlane(cx, 8), s8  = rdlane(sx, 8);
    const float c9 = rdlane(cx, 9), s9  = rdlane(sx, 9);
    const float s6m = (lane & 1) ? -s6r : s6r;                   // boundary pair fold
    const float mm[4] = {c8 * c9, c8 * s9, s8 * c9, s8 * s9};
    const float nn[4] = {F * (c6 * c7), F * (c6 * s7), F * (s6m * c7), F * (s6m * s7)};
    const int kl = __popc(lane) & 3;
    const float pa = (kl == 0) ? 1.f : ((kl == 2) ? -1.f : 0.f);
    const float pb = (kl == 1) ? -1.f : ((kl == 3) ? 1.f : 0.f);
    const float phx[4] = {pa, pb, -pa, -pb};
    const float phy[4] = {pb, -pa, -pb, pa};

    float sr[16], si[16];
#pragma unroll
    for (int r = 0; r < 16; ++r) {
        const float Ar = nn[r >> 2] * mm[r & 3];
        const int j = ((__popc(r) & 3) + 2 * (__popc(r & (r >> 1) & 7) & 1)) & 3;
        sr[r] = Ar * phx[j];
        si[r] = Ar * phy[j];
    }

    // ---- layers: R1' R2 R3' R4 R5' R6 (MOD at d=0,2,4; no sign passes) ----
    ry_layer<true >(sr, si, tp,  0, lane, sg);
    ry_layer<false>(sr, si, tp, 10, lane, sg);
    ry_layer<true >(sr, si, tp, 20, lane, sg);
    ry_layer<false>(sr, si, tp, 30, lane, sg);
    ry_layer<true >(sr, si, tp, 40, lane, sg);
    ry_layer<false>(sr, si, tp, 50, lane, sg);

    // ---- probabilities + shared in-register tree (r-wire expvals + pt) ----
    float pp[16];
#pragma unroll
    for (int r = 0; r < 16; ++r) pp[r] = fmaf(sr[r], sr[r], si[r] * si[r]);

    float a4[8]; float f9 = 0.f;
#pragma unroll
    for (int i = 0; i < 8; ++i) { a4[i] = pp[2*i] + pp[2*i+1]; f9 += pp[2*i] - pp[2*i+1]; }
    float b4[4]; float f8 = 0.f;
#pragma unroll
    for (int i = 0; i < 4; ++i) { b4[i] = a4[2*i] + a4[2*i+1]; f8 += a4[2*i] - a4[2*i+1]; }
    const float cc0 = b4[0] + b4[1], cc1 = b4[2] + b4[3];
    float f7 = (b4[0] - b4[1]) + (b4[2] - b4[3]);
    float f6 = cc0 - cc1;
    const float pt = cc0 + cc1;

    // full-wave sums for the r-wire expvals
#pragma unroll
    for (int k = 0; k < 6; ++k) {
        const int m = 1 << k;
        f6 += __shfl_xor(f6, m, 64);
        f7 += __shfl_xor(f7, m, 64);
        f8 += __shfl_xor(f8, m, 64);
        f9 += __shfl_xor(f9, m, 64);
    }

    // one WHT butterfly on pt: lane s ends with sum_l (-1)^{popc(l&s)} pt_l
    float v = pt;
#pragma unroll
    for (int k = 0; k < 6; ++k) {
        const int m = 1 << k;
        const float p = __shfl_xor(v, m, 64);
        const u32 xw = (lane & m) ? 0x80000000u : 0u;
        v = p + u2f(f2u(v) ^ xw);
    }
    const float e0 = rdlane(v, 32), e1 = rdlane(v, 16), e2 = rdlane(v, 8);
    const float e3 = rdlane(v, 4),  e4 = rdlane(v, 2),  e5 = rdlane(v, 1);

    // ---- linear head: lane k emits class k; C2 applied once ----
    if (lane < NCLS) {
        const float* wr = w_cls + lane * NQ;
        float dot = e0 * wr[0];
        dot = fmaf(e1, wr[1], dot);
        dot = fmaf(e2, wr[2], dot);
        dot = fmaf(e3, wr[3], dot);
        dot = fmaf(e4, wr[4], dot);
        dot = fmaf(e5, wr[5], dot);
        dot = fmaf(f6, wr[6], dot);
        dot = fmaf(f7, wr[7], dot);
        dot = fmaf(f8, wr[8], dot);
        dot = fmaf(f9, wr[9], dot);
        out[b * NCLS + lane] = fmaf(C2, dot, b_cls[lane]);
    }
}

extern "C" void kernel_launch(void* const* d_in, const int* in_sizes, int n_in,
                              void* d_out, int out_size, void* d_ws, size_t ws_size,
                              hipStream_t stream) {
    const float* x      = (const float*)d_in[0];
    const float* params = (const float*)d_in[1];
    const float* w_cls  = (const float*)d_in[2];
    const float* b_cls  = (const float*)d_in[3];
    float* out = (float*)d_out;

    const int batch = in_sizes[0] / NQ;            // 65536
    const int WAVES_PER_BLOCK = 4;                 // 256 threads
    dim3 block(64 * WAVES_PER_BLOCK);
    dim3 grid((batch + WAVES_PER_BLOCK - 1) / WAVES_PER_BLOCK);
    hipLaunchKernelGGL(qnn_kernel, grid, block, 0, stream, x, params, w_cls, b_cls, out, batch);
}

// Round 9
// 324.971 us; speedup vs baseline: 1.1294x; 1.1294x over previous
//
#include <hip/hip_runtime.h>
#include <math.h>

// Batched 10-qubit statevector sim: one wave per batch element.
// State = 1024 complex amps = 16 (sr,si) float pairs per lane.
// Amp index a = (lane << 4) | r. Wire w acts on amp bit 9-w:
//   wire0 permlane32-pair, wire1 permlane16-pair, wire2 fmac+DPP row_ror:8,
//   wire3 ds_swizzle xor4 (DS pipe — hidden under VALU, R7/R8 A/B proven),
//   wire4 fmac+DPP quad[2,3,0,1], wire5 fmac+DPP quad[1,0,3,2],
//   wires 6-9 in-register local shear.
// Round-9: instruction diet. Empirical law from R6/R7/R8: dur_us ~= 0.122 x
// VALU-instr/wave; DS ops (<=200/wave) are free. Cuts:
//  (a) wire3 reverted to DS (ds_swizzle 0x101F, no addr VGPR).
//  (b) prep kernel -> d_ws: tan(params/2)[60] + C2. Batch-invariant; main
//      kernel reads wave-uniform (SGPR loads) — kills 60 v_readlane + params
//      sincos + divide + 6-stage product (~92 VALU).
//  (c) HI DPP blocks drop s_nop (prev instr writes a different reg; LO keeps).
//  (d) epilogue: permlane swap-sum (pr0+pr1, no select) for masks 16/32,
//      ds_swizzle for mask 4.
// RY gates stay tan-shear with deferred global cos-product C2; CZ layers stay
// absorbed into sign-modulated shears (R7).

typedef unsigned int u32;

constexpr int NQ = 10;
constexpr int NCLS = 16;

__device__ __forceinline__ float i2f(int i) { return __builtin_bit_cast(float, i); }
__device__ __forceinline__ int   f2i(float f) { return __builtin_bit_cast(int, f); }
__device__ __forceinline__ u32   f2u(float f) { return __builtin_bit_cast(u32, f); }
__device__ __forceinline__ float u2f(u32 u)   { return __builtin_bit_cast(float, u); }

__device__ __forceinline__ float rdlane(float v, int l) {
    return i2f(__builtin_amdgcn_readlane(f2i(v), l));
}

// xor-4 partner via ds_swizzle BitMode (xor_mask=4, and_mask=0x1F)
__device__ __forceinline__ float swz4(float v) {
    return i2f(__builtin_amdgcn_ds_swizzle(f2i(v), 0x101F));
}

// ---- fused shear for DPP-able masks: st[k] += C * DPP(st[k]), 16 regs/block.
// LO keeps s_nop 1: compiler may sink a write of sr/si[0..7] to just before the
// block (they are "+v"-bound), and DPP src0 read needs 2 wait states after a
// VALU write. HI needs none: the preceding instr is LO's last fmac (si[7]),
// and interleaved compiler temps can't alias HI's live "+v" registers.
#define DPP16_LO(CTRL, C, sr, si) \
  asm("s_nop 1\n\t" \
      "v_fmac_f32 %0, %0, %16 "  CTRL "\n\t" \
      "v_fmac_f32 %1, %1, %16 "  CTRL "\n\t" \
      "v_fmac_f32 %2, %2, %16 "  CTRL "\n\t" \
      "v_fmac_f32 %3, %3, %16 "  CTRL "\n\t" \
      "v_fmac_f32 %4, %4, %16 "  CTRL "\n\t" \
      "v_fmac_f32 %5, %5, %16 "  CTRL "\n\t" \
      "v_fmac_f32 %6, %6, %16 "  CTRL "\n\t" \
      "v_fmac_f32 %7, %7, %16 "  CTRL "\n\t" \
      "v_fmac_f32 %8, %8, %16 "  CTRL "\n\t" \
      "v_fmac_f32 %9, %9, %16 "  CTRL "\n\t" \
      "v_fmac_f32 %10, %10, %16 " CTRL "\n\t" \
      "v_fmac_f32 %11, %11, %16 " CTRL "\n\t" \
      "v_fmac_f32 %12, %12, %16 " CTRL "\n\t" \
      "v_fmac_f32 %13, %13, %16 " CTRL "\n\t" \
      "v_fmac_f32 %14, %14, %16 " CTRL "\n\t" \
      "v_fmac_f32 %15, %15, %16 " CTRL \
      : "+v"(sr[0]),"+v"(sr[1]),"+v"(sr[2]),"+v"(sr[3]), \
        "+v"(sr[4]),"+v"(sr[5]),"+v"(sr[6]),"+v"(sr[7]), \
        "+v"(si[0]),"+v"(si[1]),"+v"(si[2]),"+v"(si[3]), \
        "+v"(si[4]),"+v"(si[5]),"+v"(si[6]),"+v"(si[7]) \
      : "v"(C))

#define DPP16_HI(CTRL, C, sr, si) \
  asm("v_fmac_f32 %0, %0, %16 "  CTRL "\n\t" \
      "v_fmac_f32 %1, %1, %16 "  CTRL "\n\t" \
      "v_fmac_f32 %2, %2, %16 "  CTRL "\n\t" \
      "v_fmac_f32 %3, %3, %16 "  CTRL "\n\t" \
      "v_fmac_f32 %4, %4, %16 "  CTRL "\n\t" \
      "v_fmac_f32 %5, %5, %16 "  CTRL "\n\t" \
      "v_fmac_f32 %6, %6, %16 "  CTRL "\n\t" \
      "v_fmac_f32 %7, %7, %16 "  CTRL "\n\t" \
      "v_fmac_f32 %8, %8, %16 "  CTRL "\n\t" \
      "v_fmac_f32 %9, %9, %16 "  CTRL "\n\t" \
      "v_fmac_f32 %10, %10, %16 " CTRL "\n\t" \
      "v_fmac_f32 %11, %11, %16 " CTRL "\n\t" \
      "v_fmac_f32 %12, %12, %16 " CTRL "\n\t" \
      "v_fmac_f32 %13, %13, %16 " CTRL "\n\t" \
      "v_fmac_f32 %14, %14, %16 " CTRL \
      "\n\tv_fmac_f32 %15, %15, %16 " CTRL \
      : "+v"(sr[8]),"+v"(sr[9]),"+v"(sr[10]),"+v"(sr[11]), \
        "+v"(sr[12]),"+v"(sr[13]),"+v"(sr[14]),"+v"(sr[15]), \
        "+v"(si[8]),"+v"(si[9]),"+v"(si[10]),"+v"(si[11]), \
        "+v"(si[12]),"+v"(si[13]),"+v"(si[14]),"+v"(si[15]) \
      : "v"(C))

#define CTRL_QP1  "quad_perm:[1,0,3,2] row_mask:0xf bank_mask:0xf"   // lane^1
#define CTRL_QP2  "quad_perm:[2,3,0,1] row_mask:0xf bank_mask:0xf"   // lane^2
#define CTRL_ROR8 "row_ror:8 row_mask:0xf bank_mask:0xf"             // lane^8

// ---- permlane pair-trick shear (validated rounds 4-8) ----
template<int M>
__device__ __forceinline__ void pair_shear(float& a, float& b, float t) {
    if constexpr (M == 32) {
        auto p = __builtin_amdgcn_permlane32_swap(f2u(a), f2u(b), false, false);
        const float A = u2f(p[0]), B = u2f(p[1]);
        const float C = fmaf(-t, B, A);
        const float D = fmaf( t, A, B);
        auto q = __builtin_amdgcn_permlane32_swap(f2u(C), f2u(D), false, false);
        a = u2f(q[0]); b = u2f(q[1]);
    } else {
        auto p = __builtin_amdgcn_permlane16_swap(f2u(a), f2u(b), false, false);
        const float A = u2f(p[0]), B = u2f(p[1]);
        const float C = fmaf(-t, B, A);
        const float D = fmaf( t, A, B);
        auto q = __builtin_amdgcn_permlane16_swap(f2u(C), f2u(D), false, false);
        a = u2f(q[0]); b = u2f(q[1]);
    }
}

// ---- partner fetch (epilogue) ----
template<int MASK>
__device__ __forceinline__ float xp(float v, int lane) {
    if constexpr (MASK == 1) {
        int i = f2i(v);
        return i2f(__builtin_amdgcn_update_dpp(i, i, 0xB1, 0xF, 0xF, false));
    } else if constexpr (MASK == 2) {
        int i = f2i(v);
        return i2f(__builtin_amdgcn_update_dpp(i, i, 0x4E, 0xF, 0xF, false));
    } else if constexpr (MASK == 8) {
        int i = f2i(v);
        return i2f(__builtin_amdgcn_update_dpp(i, i, 0x128, 0xF, 0xF, false));
    } else if constexpr (MASK == 4) {
        return swz4(v);
    } else if constexpr (MASK == 16) {
        u32 u = f2u(v);
        auto pr = __builtin_amdgcn_permlane16_swap(u, u, false, false);
        return u2f((lane & 16) ? pr[0] : pr[1]);
    } else {
        u32 u = f2u(v);
        auto pr = __builtin_amdgcn_permlane32_swap(u, u, false, false);
        return u2f((lane & 32) ? pr[0] : pr[1]);
    }
}

// full-wave sum: masks 1,2,8 DPP; 4 ds; 16/32 swap-sum (no select)
__device__ __forceinline__ float wave_sum_f(float v) {
    v += i2f(__builtin_amdgcn_update_dpp(f2i(v), f2i(v), 0xB1, 0xF, 0xF, false));
    v += i2f(__builtin_amdgcn_update_dpp(f2i(v), f2i(v), 0x4E, 0xF, 0xF, false));
    v += swz4(v);
    v += i2f(__builtin_amdgcn_update_dpp(f2i(v), f2i(v), 0x128, 0xF, 0xF, false));
    { auto p = __builtin_amdgcn_permlane16_swap(f2u(v), f2u(v), false, false);
      v = u2f(p[0]) + u2f(p[1]); }
    { auto p = __builtin_amdgcn_permlane32_swap(f2u(v), f2u(v), false, false);
      v = u2f(p[0]) + u2f(p[1]); }
    return v;
}

// ---- local shear on r-bit B; NB = compile-time neighbor-sign mask ----
template<int B, int NB>
__device__ __forceinline__ void local_ry(float (&sr)[16], float (&si)[16], float t) {
#pragma unroll
    for (int r0 = 0; r0 < 16; ++r0) {
        if ((r0 & (1 << B)) == 0) {
            const int r1 = r0 | (1 << B);
            const float tt = (__builtin_popcount(r0 & NB) & 1) ? -t : t;
            const float a0 = sr[r0], a1 = sr[r1];
            sr[r0] = fmaf(-tt, a1, a0);
            sr[r1] = fmaf( tt, a0, a1);
            const float b0 = si[r0], b1 = si[r1];
            si[r0] = fmaf(-tt, b1, b0);
            si[r1] = fmaf( tt, b0, b1);
        }
    }
}

struct Sig { float g16, g53, g42, g31, g20, g1, g0; };

// One RY layer; MOD => CZ-conjugated (t sign-modulated by neighbor bits).
// tw = wave-uniform tan table (SGPR loads).
template<bool MOD>
__device__ __forceinline__ void ry_layer(float (&sr)[16], float (&si)[16],
                                         const float* __restrict__ tw, int base,
                                         int lane, const Sig& sg) {
    {   // wire 0: amp bit 9 (lane bit 5), permlane32 pair
        float t = tw[base + 0];
        if constexpr (MOD) t *= sg.g16;
#pragma unroll
        for (int r = 0; r < 16; r += 2) {
            pair_shear<32>(sr[r], sr[r+1], t);
            pair_shear<32>(si[r], si[r+1], t);
        }
    }
    {   // wire 1: amp bit 8 (lane bit 4), permlane16 pair
        float t = tw[base + 1];
        if constexpr (MOD) t *= sg.g53;
#pragma unroll
        for (int r = 0; r < 16; r += 2) {
            pair_shear<16>(sr[r], sr[r+1], t);
            pair_shear<16>(si[r], si[r+1], t);
        }
    }
    {   // wire 2: lane mask 8, fused fmac+DPP row_ror:8
        float t = tw[base + 2];
        if constexpr (MOD) t *= sg.g42;
        const float ts = (lane & 8) ? t : -t;
        DPP16_LO(CTRL_ROR8, ts, sr, si);
        DPP16_HI(CTRL_ROR8, ts, sr, si);
    }
    {   // wire 3: lane mask 4 via ds_swizzle (DS pipe, hidden under VALU)
        float t = tw[base + 3];
        if constexpr (MOD) t *= sg.g31;
        const float ts = (lane & 4) ? t : -t;
#pragma unroll
        for (int r = 0; r < 16; ++r) {
            sr[r] = fmaf(ts, swz4(sr[r]), sr[r]);
            si[r] = fmaf(ts, swz4(si[r]), si[r]);
        }
    }
    {   // wire 4: lane mask 2, fused fmac+DPP quad_perm
        float t = tw[base + 4];
        if constexpr (MOD) t *= sg.g20;
        const float ts = (lane & 2) ? t : -t;
        DPP16_LO(CTRL_QP2, ts, sr, si);
        DPP16_HI(CTRL_QP2, ts, sr, si);
    }
    {   // wire 5: lane mask 1, fused fmac+DPP; MOD also flips by r-bit3 (hi half)
        float t = tw[base + 5];
        if constexpr (MOD) t *= sg.g1;
        const float ts = (lane & 1) ? t : -t;
        const float th = MOD ? -ts : ts;
        DPP16_LO(CTRL_QP1, ts, sr, si);
        DPP16_HI(CTRL_QP1, th, sr, si);
    }
    {   // wire 6: r bit 3; MOD: lane-bit0 sign + r-bit2 sign
        float t = tw[base + 6];
        if constexpr (MOD) t *= sg.g0;
        local_ry<3, MOD ? 0x4 : 0>(sr, si, t);
    }
    local_ry<2, MOD ? 0xA : 0>(sr, si, tw[base + 7]);   // wire 7
    local_ry<1, MOD ? 0x5 : 0>(sr, si, tw[base + 8]);   // wire 8
    local_ry<0, MOD ? 0x2 : 0>(sr, si, tw[base + 9]);   // wire 9
}

// ---- prep kernel: batch-invariant tan table + global C^2 into d_ws ----
__global__ void qnn_prep(const float* __restrict__ params, float* __restrict__ ws) {
    const int l = threadIdx.x;                    // 64 threads
    float s, c;
    const float h = (l < 60) ? params[l] * 0.5f : 0.f;
    __sincosf(h, &s, &c);                         // l>=60: c=1 (identity)
    if (l < 60) ws[l] = s / c;
    float Cw = c;
#pragma unroll
    for (int k = 0; k < 6; ++k) Cw *= __shfl_xor(Cw, 1 << k, 64);
    if (l == 0) ws[60] = Cw * Cw;
}

__global__ void __launch_bounds__(256) qnn_kernel(
    const float* __restrict__ x,       // (B, 10)
    const float* __restrict__ tw,      // (61,) tan table + C2 (wave-uniform)
    const float* __restrict__ w_cls,   // (16, 10)
    const float* __restrict__ b_cls,   // (16,)
    float* __restrict__ out,           // (B, 16)
    int batch)
{
    const int lane = threadIdx.x & 63;
    const int wid  = threadIdx.x >> 6;
    const int b    = blockIdx.x * (blockDim.x >> 6) + wid;

    // ---- encoding angles ----
    float cx, sx;
    { const int l = (lane < NQ) ? lane : 0; __sincosf(x[b * NQ + l] * 0.5f, &sx, &cx); }

    const float C2 = tw[60];

    // ---- neighbor-sign factors for CZ-conjugated layers ----
    Sig sg;
    sg.g16 = (lane & 16) ? -1.f : 1.f;                           // w0: lane bit4
    sg.g53 = (((lane >> 5) ^ (lane >> 3)) & 1) ? -1.f : 1.f;     // w1: bits 5,3
    sg.g42 = (((lane >> 4) ^ (lane >> 2)) & 1) ? -1.f : 1.f;     // w2: bits 4,2
    sg.g31 = (((lane >> 3) ^ (lane >> 1)) & 1) ? -1.f : 1.f;     // w3: bits 3,1
    sg.g20 = (((lane >> 2) ^ lane) & 1) ? -1.f : 1.f;            // w4: bits 2,0
    sg.g1  = (lane & 2) ? -1.f : 1.f;                            // w5: lane bit1
    sg.g0  = (lane & 1) ? -1.f : 1.f;                            // w6: lane bit0

    // ---- product state with the absorbed initial CZ-sign C|enc> ----
    float F = 1.f;
#pragma unroll
    for (int q = 0; q < 6; ++q) {
        const float cq = rdlane(cx, q), sq = rdlane(sx, q);
        F *= ((lane >> (5 - q)) & 1) ? sq : cq;
    }
    const int lpar = __popc(lane & (lane >> 1) & 0x1F) & 1;      // lane-pair parity
    F = u2f(f2u(F) ^ (u32(lpar) << 31));
    const float c6 = rdlane(cx, 6), s6r = rdlane(sx, 6);
    const float c7 = rdlane(cx, 7), s7  = rdlane(sx, 7);
    const float c8 = rdlane(cx, 8), s8  = rdlane(sx, 8);
    const float c9 = rdlane(cx, 9), s9  = rdlane(sx, 9);
    const float s6m = (lane & 1) ? -s6r : s6r;                   // boundary pair fold
    const float mm[4] = {c8 * c9, c8 * s9, s8 * c9, s8 * s9};
    const float nn[4] = {F * (c6 * c7), F * (c6 * s7), F * (s6m * c7), F * (s6m * s7)};
    const int kl = __popc(lane) & 3;
    const float pa = (kl == 0) ? 1.f : ((kl == 2) ? -1.f : 0.f);
    const float pb = (kl == 1) ? -1.f : ((kl == 3) ? 1.f : 0.f);
    const float phx[4] = {pa, pb, -pa, -pb};
    const float phy[4] = {pb, -pa, -pb, pa};

    float sr[16], si[16];
#pragma unroll
    for (int r = 0; r < 16; ++r) {
        const float Ar = nn[r >> 2] * mm[r & 3];
        const int j = ((__popc(r) & 3) + 2 * (__popc(r & (r >> 1) & 7) & 1)) & 3;
        sr[r] = Ar * phx[j];
        si[r] = Ar * phy[j];
    }

    // ---- layers: R1' R2 R3' R4 R5' R6 (MOD at d=0,2,4; no sign passes) ----
    ry_layer<true >(sr, si, tw,  0, lane, sg);
    ry_layer<false>(sr, si, tw, 10, lane, sg);
    ry_layer<true >(sr, si, tw, 20, lane, sg);
    ry_layer<false>(sr, si, tw, 30, lane, sg);
    ry_layer<true >(sr, si, tw, 40, lane, sg);
    ry_layer<false>(sr, si, tw, 50, lane, sg);

    // ---- probabilities + shared in-register tree (r-wire expvals + pt) ----
    float pp[16];
#pragma unroll
    for (int r = 0; r < 16; ++r) pp[r] = fmaf(sr[r], sr[r], si[r] * si[r]);

    float a4[8]; float f9 = 0.f;
#pragma unroll
    for (int i = 0; i < 8; ++i) { a4[i] = pp[2*i] + pp[2*i+1]; f9 += pp[2*i] - pp[2*i+1]; }
    float b4[4]; float f8 = 0.f;
#pragma unroll
    for (int i = 0; i < 4; ++i) { b4[i] = a4[2*i] + a4[2*i+1]; f8 += a4[2*i] - a4[2*i+1]; }
    const float cc0 = b4[0] + b4[1], cc1 = b4[2] + b4[3];
    float f7 = (b4[0] - b4[1]) + (b4[2] - b4[3]);
    float f6 = cc0 - cc1;
    const float pt = cc0 + cc1;

    // full-wave sums for the r-wire expvals
    f6 = wave_sum_f(f6);
    f7 = wave_sum_f(f7);
    f8 = wave_sum_f(f8);
    f9 = wave_sum_f(f9);

    // one WHT butterfly on pt: lane s ends with sum_l (-1)^{popc(l&s)} pt_l
    float v = pt;
#pragma unroll
    for (int k = 0; k < 6; ++k) {
        const int m = 1 << k;
        const float p = xp<0>(v, lane);  // placeholder avoided below
        (void)p;
        break;
    }
    v = pt;
    {
        float p;
        p = xp<1>(v, lane);  v = p + u2f(f2u(v) ^ ((lane & 1)  ? 0x80000000u : 0u));
        p = xp<2>(v, lane);  v = p + u2f(f2u(v) ^ ((lane & 2)  ? 0x80000000u : 0u));
        p = xp<4>(v, lane);  v = p + u2f(f2u(v) ^ ((lane & 4)  ? 0x80000000u : 0u));
        p = xp<8>(v, lane);  v = p + u2f(f2u(v) ^ ((lane & 8)  ? 0x80000000u : 0u));
        p = xp<16>(v, lane); v = p + u2f(f2u(v) ^ ((lane & 16) ? 0x80000000u : 0u));
        p = xp<32>(v, lane); v = p + u2f(f2u(v) ^ ((lane & 32) ? 0x80000000u : 0u));
    }
    const float e0 = rdlane(v, 32), e1 = rdlane(v, 16), e2 = rdlane(v, 8);
    const float e3 = rdlane(v, 4),  e4 = rdlane(v, 2),  e5 = rdlane(v, 1);

    // ---- linear head: lane k emits class k; C2 applied once ----
    if (lane < NCLS) {
        const float* wr = w_cls + lane * NQ;
        float dot = e0 * wr[0];
        dot = fmaf(e1, wr[1], dot);
        dot = fmaf(e2, wr[2], dot);
        dot = fmaf(e3, wr[3], dot);
        dot = fmaf(e4, wr[4], dot);
        dot = fmaf(e5, wr[5], dot);
        dot = fmaf(f6, wr[6], dot);
        dot = fmaf(f7, wr[7], dot);
        dot = fmaf(f8, wr[8], dot);
        dot = fmaf(f9, wr[9], dot);
        out[b * NCLS + lane] = fmaf(C2, dot, b_cls[lane]);
    }
}

extern "C" void kernel_launch(void* const* d_in, const int* in_sizes, int n_in,
                              void* d_out, int out_size, void* d_ws, size_t ws_size,
                              hipStream_t stream) {
    const float* x      = (const float*)d_in[0];
    const float* params = (const float*)d_in[1];
    const float* w_cls  = (const float*)d_in[2];
    const float* b_cls  = (const float*)d_in[3];
    float* out = (float*)d_out;
    float* ws  = (float*)d_ws;

    const int batch = in_sizes[0] / NQ;            // 65536
    const int WAVES_PER_BLOCK = 4;                 // 256 threads

    hipLaunchKernelGGL(qnn_prep, dim3(1), dim3(64), 0, stream, params, ws);

    dim3 block(64 * WAVES_PER_BLOCK);
    dim3 grid(batch / WAVES_PER_BLOCK);            // exact: 65536/4
    hipLaunchKernelGGL(qnn_kernel, grid, block, 0, stream,
                       x, (const float*)ws, w_cls, b_cls, out, batch);
}

// Round 10
// 246.145 us; speedup vs baseline: 1.4911x; 1.3202x over previous
//
#include <hip/hip_runtime.h>
#include <math.h>

// Batched 10-qubit statevector sim: one wave per batch element.
// State = 1024 complex amps = 16 (sr,si) float pairs per lane.
// Amp index a = (lane << 4) | r. Wire w acts on amp bit 9-w:
//   wire0 (lane^32): ds_bpermute  (DS pipe)   <- was permlane32 pair (2 VALU/float)
//   wire1 (lane^16): ds_swizzle 0x401F (DS)   <- was permlane16 pair
//   wire2 (lane^8) : fused fmac+DPP row_ror:8 (1 VALU/float)
//   wire3 (lane^4) : ds_swizzle 0x101F (DS)
//   wire4 (lane^2) : fused fmac+DPP quad[2,3,0,1]
//   wire5 (lane^1) : fused fmac+DPP quad[1,0,3,2]
//   wires6-9: in-register local shear (1 VALU/float)
// Round-10: R9 showed dur ~ VALU-instr count, DS idle (192/wave free).
// Move the 2-VALU/float pair wires onto the DS pipe (1 fma + 1 ds each):
// ~2150 VALU + ~590 ds per wave. All +-1 gate signs (incl. absorbed-CZ
// neighbor signs) are precomputed u32 sign-words applied via one v_xor on
// the wave-uniform tan value. RY = tan-shear + deferred global C2 (R6);
// CZ absorbed into sign-modulated shears (R7); prep kernel tan table (R9).

typedef unsigned int u32;

constexpr int NQ = 10;
constexpr int NCLS = 16;
constexpr u32 SGN = 0x80000000u;

__device__ __forceinline__ float i2f(int i) { return __builtin_bit_cast(float, i); }
__device__ __forceinline__ int   f2i(float f) { return __builtin_bit_cast(int, f); }
__device__ __forceinline__ u32   f2u(float f) { return __builtin_bit_cast(u32, f); }
__device__ __forceinline__ float u2f(u32 u)   { return __builtin_bit_cast(float, u); }

__device__ __forceinline__ float rdlane(float v, int l) {
    return i2f(__builtin_amdgcn_readlane(f2i(v), l));
}

// DS-pipe partner fetches
__device__ __forceinline__ float swz4(float v) {   // lane^4 (BitMode xor=4)
    return i2f(__builtin_amdgcn_ds_swizzle(f2i(v), 0x101F));
}
__device__ __forceinline__ float swz16(float v) {  // lane^16 (BitMode xor=16)
    return i2f(__builtin_amdgcn_ds_swizzle(f2i(v), 0x401F));
}
__device__ __forceinline__ float bp32(float v, int bpa) {  // lane^32 (full-wave crossbar)
    return i2f(__builtin_amdgcn_ds_bpermute(bpa, f2i(v)));
}

// VALU DPP partner-fetch (epilogue use)
__device__ __forceinline__ float dppx(float v, int ctrl) { return v; } // unused generic
__device__ __forceinline__ float dpp1(float v) {
    int i = f2i(v); return i2f(__builtin_amdgcn_update_dpp(i, i, 0xB1, 0xF, 0xF, false));
}
__device__ __forceinline__ float dpp2(float v) {
    int i = f2i(v); return i2f(__builtin_amdgcn_update_dpp(i, i, 0x4E, 0xF, 0xF, false));
}
__device__ __forceinline__ float dpp8(float v) {
    int i = f2i(v); return i2f(__builtin_amdgcn_update_dpp(i, i, 0x128, 0xF, 0xF, false));
}

// ---- fused shear for DPP-able masks: st[k] += C * DPP(st[k]), 16 regs/block.
// LO keeps s_nop 1 (DPP src read needs 2 wait states after a VALU write that
// the compiler may sink right before the block); HI follows LO's last fmac.
#define DPP16_LO(CTRL, C, sr, si) \
  asm("s_nop 1\n\t" \
      "v_fmac_f32 %0, %0, %16 "  CTRL "\n\t" \
      "v_fmac_f32 %1, %1, %16 "  CTRL "\n\t" \
      "v_fmac_f32 %2, %2, %16 "  CTRL "\n\t" \
      "v_fmac_f32 %3, %3, %16 "  CTRL "\n\t" \
      "v_fmac_f32 %4, %4, %16 "  CTRL "\n\t" \
      "v_fmac_f32 %5, %5, %16 "  CTRL "\n\t" \
      "v_fmac_f32 %6, %6, %16 "  CTRL "\n\t" \
      "v_fmac_f32 %7, %7, %16 "  CTRL "\n\t" \
      "v_fmac_f32 %8, %8, %16 "  CTRL "\n\t" \
      "v_fmac_f32 %9, %9, %16 "  CTRL "\n\t" \
      "v_fmac_f32 %10, %10, %16 " CTRL "\n\t" \
      "v_fmac_f32 %11, %11, %16 " CTRL "\n\t" \
      "v_fmac_f32 %12, %12, %16 " CTRL "\n\t" \
      "v_fmac_f32 %13, %13, %16 " CTRL "\n\t" \
      "v_fmac_f32 %14, %14, %16 " CTRL "\n\t" \
      "v_fmac_f32 %15, %15, %16 " CTRL \
      : "+v"(sr[0]),"+v"(sr[1]),"+v"(sr[2]),"+v"(sr[3]), \
        "+v"(sr[4]),"+v"(sr[5]),"+v"(sr[6]),"+v"(sr[7]), \
        "+v"(si[0]),"+v"(si[1]),"+v"(si[2]),"+v"(si[3]), \
        "+v"(si[4]),"+v"(si[5]),"+v"(si[6]),"+v"(si[7]) \
      : "v"(C))

#define DPP16_HI(CTRL, C, sr, si) \
  asm("v_fmac_f32 %0, %0, %16 "  CTRL "\n\t" \
      "v_fmac_f32 %1, %1, %16 "  CTRL "\n\t" \
      "v_fmac_f32 %2, %2, %16 "  CTRL "\n\t" \
      "v_fmac_f32 %3, %3, %16 "  CTRL "\n\t" \
      "v_fmac_f32 %4, %4, %16 "  CTRL "\n\t" \
      "v_fmac_f32 %5, %5, %16 "  CTRL "\n\t" \
      "v_fmac_f32 %6, %6, %16 "  CTRL "\n\t" \
      "v_fmac_f32 %7, %7, %16 "  CTRL "\n\t" \
      "v_fmac_f32 %8, %8, %16 "  CTRL "\n\t" \
      "v_fmac_f32 %9, %9, %16 "  CTRL "\n\t" \
      "v_fmac_f32 %10, %10, %16 " CTRL "\n\t" \
      "v_fmac_f32 %11, %11, %16 " CTRL "\n\t" \
      "v_fmac_f32 %12, %12, %16 " CTRL "\n\t" \
      "v_fmac_f32 %13, %13, %16 " CTRL "\n\t" \
      "v_fmac_f32 %14, %14, %16 " CTRL "\n\t" \
      "v_fmac_f32 %15, %15, %16 " CTRL \
      : "+v"(sr[8]),"+v"(sr[9]),"+v"(sr[10]),"+v"(sr[11]), \
        "+v"(sr[12]),"+v"(sr[13]),"+v"(sr[14]),"+v"(sr[15]), \
        "+v"(si[8]),"+v"(si[9]),"+v"(si[10]),"+v"(si[11]), \
        "+v"(si[12]),"+v"(si[13]),"+v"(si[14]),"+v"(si[15]) \
      : "v"(C))

#define CTRL_QP1  "quad_perm:[1,0,3,2] row_mask:0xf bank_mask:0xf"   // lane^1
#define CTRL_QP2  "quad_perm:[2,3,0,1] row_mask:0xf bank_mask:0xf"   // lane^2
#define CTRL_ROR8 "row_ror:8 row_mask:0xf bank_mask:0xf"             // lane^8

// ---- local shear on r-bit B; NB = compile-time neighbor-sign mask ----
template<int B, int NB>
__device__ __forceinline__ void local_ry(float (&sr)[16], float (&si)[16], float t) {
#pragma unroll
    for (int r0 = 0; r0 < 16; ++r0) {
        if ((r0 & (1 << B)) == 0) {
            const int r1 = r0 | (1 << B);
            const float tt = (__builtin_popcount(r0 & NB) & 1) ? -t : t;
            const float a0 = sr[r0], a1 = sr[r1];
            sr[r0] = fmaf(-tt, a1, a0);
            sr[r1] = fmaf( tt, a0, a1);
            const float b0 = si[r0], b1 = si[r1];
            si[r0] = fmaf(-tt, b1, b0);
            si[r1] = fmaf( tt, b0, b1);
        }
    }
}

// precomputed per-lane sign words: nX = plain layer, mX = CZ-conjugated layer
struct Sgn { u32 n0, m0, n1, m1, n2, m2, n3, m3, n4, m4, n5, m5, gb0; };

// One RY layer; MOD => CZ-conjugated (neighbor-sign-modulated shears).
template<bool MOD>
__device__ __forceinline__ void ry_layer(float (&sr)[16], float (&si)[16],
                                         const float* __restrict__ tw, int base,
                                         int bpa, const Sgn& sg) {
    {   // wire 0: lane^32 via ds_bpermute (DS pipe)
        const float ts = u2f(f2u(tw[base + 0]) ^ (MOD ? sg.m0 : sg.n0));
#pragma unroll
        for (int r = 0; r < 16; ++r) {
            sr[r] = fmaf(ts, bp32(sr[r], bpa), sr[r]);
            si[r] = fmaf(ts, bp32(si[r], bpa), si[r]);
        }
    }
    {   // wire 1: lane^16 via ds_swizzle (DS pipe)
        const float ts = u2f(f2u(tw[base + 1]) ^ (MOD ? sg.m1 : sg.n1));
#pragma unroll
        for (int r = 0; r < 16; ++r) {
            sr[r] = fmaf(ts, swz16(sr[r]), sr[r]);
            si[r] = fmaf(ts, swz16(si[r]), si[r]);
        }
    }
    {   // wire 2: lane^8, fused fmac+DPP row_ror:8
        const float ts = u2f(f2u(tw[base + 2]) ^ (MOD ? sg.m2 : sg.n2));
        DPP16_LO(CTRL_ROR8, ts, sr, si);
        DPP16_HI(CTRL_ROR8, ts, sr, si);
    }
    {   // wire 3: lane^4 via ds_swizzle (DS pipe)
        const float ts = u2f(f2u(tw[base + 3]) ^ (MOD ? sg.m3 : sg.n3));
#pragma unroll
        for (int r = 0; r < 16; ++r) {
            sr[r] = fmaf(ts, swz4(sr[r]), sr[r]);
            si[r] = fmaf(ts, swz4(si[r]), si[r]);
        }
    }
    {   // wire 4: lane^2, fused fmac+DPP quad_perm
        const float ts = u2f(f2u(tw[base + 4]) ^ (MOD ? sg.m4 : sg.n4));
        DPP16_LO(CTRL_QP2, ts, sr, si);
        DPP16_HI(CTRL_QP2, ts, sr, si);
    }
    {   // wire 5: lane^1, fused fmac+DPP; MOD: hi half (r bit3) extra flip
        const float ts = u2f(f2u(tw[base + 5]) ^ (MOD ? sg.m5 : sg.n5));
        const float th = MOD ? u2f(f2u(ts) ^ SGN) : ts;
        DPP16_LO(CTRL_QP1, ts, sr, si);
        DPP16_HI(CTRL_QP1, th, sr, si);
    }
    {   // wire 6: r bit 3; MOD: lane-bit0 sign (xor) + r-bit2 sign (compile-time)
        float t = tw[base + 6];
        if constexpr (MOD) t = u2f(f2u(t) ^ sg.gb0);
        local_ry<3, MOD ? 0x4 : 0>(sr, si, t);
    }
    local_ry<2, MOD ? 0xA : 0>(sr, si, tw[base + 7]);   // wire 7
    local_ry<1, MOD ? 0x5 : 0>(sr, si, tw[base + 8]);   // wire 8
    local_ry<0, MOD ? 0x2 : 0>(sr, si, tw[base + 9]);   // wire 9
}

// ---- prep kernel: batch-invariant tan table + global C^2 into d_ws ----
__global__ void qnn_prep(const float* __restrict__ params, float* __restrict__ ws) {
    const int l = threadIdx.x;                    // 64 threads
    float s, c;
    const float h = (l < 60) ? params[l] * 0.5f : 0.f;
    __sincosf(h, &s, &c);                         // l>=60: c=1 (identity)
    if (l < 60) ws[l] = s / c;
    float Cw = c;
#pragma unroll
    for (int k = 0; k < 6; ++k) Cw *= __shfl_xor(Cw, 1 << k, 64);
    if (l == 0) ws[60] = Cw * Cw;
}

__global__ void __launch_bounds__(256) qnn_kernel(
    const float* __restrict__ x,       // (B, 10)
    const float* __restrict__ tw,      // (61,) tan table + C2 (wave-uniform)
    const float* __restrict__ w_cls,   // (16, 10)
    const float* __restrict__ b_cls,   // (16,)
    float* __restrict__ out,           // (B, 16)
    int batch)
{
    const int lane = threadIdx.x & 63;
    const int wid  = threadIdx.x >> 6;
    const int b    = blockIdx.x * (blockDim.x >> 6) + wid;

    const int bpa = (lane ^ 32) << 2;             // bpermute addr (lane^32)

    // ---- encoding angles ----
    float cx, sx;
    { const int l = (lane < NQ) ? lane : 0; __sincosf(x[b * NQ + l] * 0.5f, &sx, &cx); }

    const float C2 = tw[60];

    // ---- sign words (plain + CZ-conjugated) ----
    const u32 gb16 = (lane & 16) ? SGN : 0;
    const u32 gb53 = (((lane >> 5) ^ (lane >> 3)) & 1) ? SGN : 0;
    const u32 gb42 = (((lane >> 4) ^ (lane >> 2)) & 1) ? SGN : 0;
    const u32 gb31 = (((lane >> 3) ^ (lane >> 1)) & 1) ? SGN : 0;
    const u32 gb20 = (((lane >> 2) ^ lane) & 1) ? SGN : 0;
    const u32 gb1  = (lane & 2) ? SGN : 0;
    Sgn sg;
    sg.gb0 = (lane & 1) ? SGN : 0;
    sg.n0 = (lane & 32) ? 0 : SGN;  sg.m0 = sg.n0 ^ gb16;
    sg.n1 = (lane & 16) ? 0 : SGN;  sg.m1 = sg.n1 ^ gb53;
    sg.n2 = (lane & 8)  ? 0 : SGN;  sg.m2 = sg.n2 ^ gb42;
    sg.n3 = (lane & 4)  ? 0 : SGN;  sg.m3 = sg.n3 ^ gb31;
    sg.n4 = (lane & 2)  ? 0 : SGN;  sg.m4 = sg.n4 ^ gb20;
    sg.n5 = (lane & 1)  ? 0 : SGN;  sg.m5 = sg.n5 ^ gb1;

    // ---- product state with the absorbed initial CZ-sign C|enc> ----
    float F = 1.f;
#pragma unroll
    for (int q = 0; q < 6; ++q) {
        const float cq = rdlane(cx, q), sq = rdlane(sx, q);
        F *= ((lane >> (5 - q)) & 1) ? sq : cq;
    }
    const int lpar = __popc(lane & (lane >> 1) & 0x1F) & 1;      // lane-pair parity
    F = u2f(f2u(F) ^ (u32(lpar) << 31));
    const float c6 = rdlane(cx, 6), s6r = rdlane(sx, 6);
    const float c7 = rdlane(cx, 7), s7  = rdlane(sx, 7);
    const float c8 = rdlane(cx, 8), s8  = rdlane(sx, 8);
    const float c9 = rdlane(cx, 9), s9  = rdlane(sx, 9);
    const float s6m = (lane & 1) ? -s6r : s6r;                   // boundary pair fold
    const float mm[4] = {c8 * c9, c8 * s9, s8 * c9, s8 * s9};
    const float nn[4] = {F * (c6 * c7), F * (c6 * s7), F * (s6m * c7), F * (s6m * s7)};
    const int kl = __popc(lane) & 3;
    const float pa = (kl == 0) ? 1.f : ((kl == 2) ? -1.f : 0.f);
    const float pb = (kl == 1) ? -1.f : ((kl == 3) ? 1.f : 0.f);
    const float phx[4] = {pa, pb, -pa, -pb};
    const float phy[4] = {pb, -pa, -pb, pa};

    float sr[16], si[16];
#pragma unroll
    for (int r = 0; r < 16; ++r) {
        const float Ar = nn[r >> 2] * mm[r & 3];
        const int j = ((__popc(r) & 3) + 2 * (__popc(r & (r >> 1) & 7) & 1)) & 3;
        sr[r] = Ar * phx[j];
        si[r] = Ar * phy[j];
    }

    // ---- layers: R1' R2 R3' R4 R5' R6 (MOD at d=0,2,4; no sign passes) ----
    ry_layer<true >(sr, si, tw,  0, bpa, sg);
    ry_layer<false>(sr, si, tw, 10, bpa, sg);
    ry_layer<true >(sr, si, tw, 20, bpa, sg);
    ry_layer<false>(sr, si, tw, 30, bpa, sg);
    ry_layer<true >(sr, si, tw, 40, bpa, sg);
    ry_layer<false>(sr, si, tw, 50, bpa, sg);

    // ---- probabilities + shared in-register tree (r-wire expvals + pt) ----
    float pp[16];
#pragma unroll
    for (int r = 0; r < 16; ++r) pp[r] = fmaf(sr[r], sr[r], si[r] * si[r]);

    float a4[8]; float f9 = 0.f;
#pragma unroll
    for (int i = 0; i < 8; ++i) { a4[i] = pp[2*i] + pp[2*i+1]; f9 += pp[2*i] - pp[2*i+1]; }
    float b4[4]; float f8 = 0.f;
#pragma unroll
    for (int i = 0; i < 4; ++i) { b4[i] = a4[2*i] + a4[2*i+1]; f8 += a4[2*i] - a4[2*i+1]; }
    const float cc0 = b4[0] + b4[1], cc1 = b4[2] + b4[3];
    float f7 = (b4[0] - b4[1]) + (b4[2] - b4[3]);
    float f6 = cc0 - cc1;
    const float pt = cc0 + cc1;

    // full-wave sums for the r-wire expvals (DPP for 1,2,8; DS for 4,16,32)
#pragma unroll
    for (int q = 0; q < 4; ++q) {
        float v = (q == 0) ? f6 : (q == 1) ? f7 : (q == 2) ? f8 : f9;
        v += dpp1(v);
        v += dpp2(v);
        v += swz4(v);
        v += dpp8(v);
        v += swz16(v);
        v += bp32(v, bpa);
        if (q == 0) f6 = v; else if (q == 1) f7 = v; else if (q == 2) f8 = v; else f9 = v;
    }

    // one WHT butterfly on pt: lane s ends with sum_l (-1)^{popc(l&s)} pt_l
    float v = pt;
    {
        float p;
        p = dpp1(v);        v = p + u2f(f2u(v) ^ ((lane & 1)  ? SGN : 0u));
        p = dpp2(v);        v = p + u2f(f2u(v) ^ ((lane & 2)  ? SGN : 0u));
        p = swz4(v);        v = p + u2f(f2u(v) ^ ((lane & 4)  ? SGN : 0u));
        p = dpp8(v);        v = p + u2f(f2u(v) ^ ((lane & 8)  ? SGN : 0u));
        p = swz16(v);       v = p + u2f(f2u(v) ^ ((lane & 16) ? SGN : 0u));
        p = bp32(v, bpa);   v = p + u2f(f2u(v) ^ ((lane & 32) ? SGN : 0u));
    }
    const float e0 = rdlane(v, 32), e1 = rdlane(v, 16), e2 = rdlane(v, 8);
    const float e3 = rdlane(v, 4),  e4 = rdlane(v, 2),  e5 = rdlane(v, 1);

    // ---- linear head: lane k emits class k; C2 applied once ----
    if (lane < NCLS) {
        const float* wr = w_cls + lane * NQ;
        float dot = e0 * wr[0];
        dot = fmaf(e1, wr[1], dot);
        dot = fmaf(e2, wr[2], dot);
        dot = fmaf(e3, wr[3], dot);
        dot = fmaf(e4, wr[4], dot);
        dot = fmaf(e5, wr[5], dot);
        dot = fmaf(f6, wr[6], dot);
        dot = fmaf(f7, wr[7], dot);
        dot = fmaf(f8, wr[8], dot);
        dot = fmaf(f9, wr[9], dot);
        out[b * NCLS + lane] = fmaf(C2, dot, b_cls[lane]);
    }
}

extern "C" void kernel_launch(void* const* d_in, const int* in_sizes, int n_in,
                              void* d_out, int out_size, void* d_ws, size_t ws_size,
                              hipStream_t stream) {
    const float* x      = (const float*)d_in[0];
    const float* params = (const float*)d_in[1];
    const float* w_cls  = (const float*)d_in[2];
    const float* b_cls  = (const float*)d_in[3];
    float* out = (float*)d_out;
    float* ws  = (float*)d_ws;

    const int batch = in_sizes[0] / NQ;            // 65536
    const int WAVES_PER_BLOCK = 4;                 // 256 threads

    hipLaunchKernelGGL(qnn_prep, dim3(1), dim3(64), 0, stream, params, ws);

    dim3 block(64 * WAVES_PER_BLOCK);
    dim3 grid(batch / WAVES_PER_BLOCK);            // exact: 65536/4
    hipLaunchKernelGGL(qnn_kernel, grid, block, 0, stream,
                       x, (const float*)ws, w_cls, b_cls, out, batch);
}

// Round 12
// 214.010 us; speedup vs baseline: 1.7150x; 1.1502x over previous
//
#include <hip/hip_runtime.h>
#include <math.h>

// Batched 10-qubit statevector sim: one wave per batch element.
// State = 1024 complex amps = 16 packed-f16 (re,im) regs per lane.
// Amp index a = (lane << 4) | r. Wire w acts on amp bit 9-w:
//   wire0 (lane^32): ds_bpermute      wire1 (lane^16): ds_swizzle 0x401F
//   wire2 (lane^8) : DPP row_ror:8    wire3 (lane^4) : ds_swizzle 0x101F
//   wire4 (lane^2) : DPP quad[2,3,0,1]  wire5 (lane^1): DPP quad[1,0,3,2]
//   wires6-9: in-register local shear.
// Round-12 = round-11 + compile fix: cvt_pkrtz returns __fp16x2, bit_cast to h2.
// PACKED F16 state: one v_pk_fma_f16 advances re+im (single-pass full rate).
// DS wires move 16 regs not 32 (~320 ds/wave), local wires 16 pk_fma not 32
// fma, probs via one v_dot2_f32_f16 per reg.
// f16 RANGE SAFETY: per-layer gamma_d = prod(layer cos) scale keeps running
// norm == 1 (tan-shears otherwise grow norm by ~1e7 over 60 gates).
// CZ layers absorbed into sign-modulated shears (R7); signs precomputed as
// 0x80008000 words xor'ed onto the packed wave-uniform t (R10).

typedef unsigned int u32;
typedef _Float16 h2 __attribute__((ext_vector_type(2)));

constexpr int NQ = 10;
constexpr int NCLS = 16;
constexpr u32 SGN  = 0x80000000u;
constexpr u32 SGN2 = 0x80008000u;

__device__ __forceinline__ float i2f(int i) { return __builtin_bit_cast(float, i); }
__device__ __forceinline__ int   f2i(float f) { return __builtin_bit_cast(int, f); }
__device__ __forceinline__ u32   f2u(float f) { return __builtin_bit_cast(u32, f); }
__device__ __forceinline__ float u2f(u32 u)   { return __builtin_bit_cast(float, u); }
__device__ __forceinline__ u32   h2u(h2 v)    { return __builtin_bit_cast(u32, v); }
__device__ __forceinline__ h2    u2h(u32 u)   { return __builtin_bit_cast(h2, u); }

__device__ __forceinline__ float rdlane(float v, int l) {
    return i2f(__builtin_amdgcn_readlane(f2i(v), l));
}

__device__ __forceinline__ h2 fma2(h2 a, h2 b, h2 c) {
    return __builtin_elementwise_fma(a, b, c);          // v_pk_fma_f16
}

// ---- DS-pipe partner fetches on packed state (move both f16 halves) ----
__device__ __forceinline__ h2 swz4h(h2 v) {   // lane^4
    return u2h((u32)__builtin_amdgcn_ds_swizzle(__builtin_bit_cast(int, v), 0x101F));
}
__device__ __forceinline__ h2 swz16h(h2 v) {  // lane^16
    return u2h((u32)__builtin_amdgcn_ds_swizzle(__builtin_bit_cast(int, v), 0x401F));
}
__device__ __forceinline__ h2 bp32h(h2 v, int bpa) {  // lane^32
    return u2h((u32)__builtin_amdgcn_ds_bpermute(bpa, __builtin_bit_cast(int, v)));
}

// ---- DPP partner fetches (compiler inserts hazard waits) ----
__device__ __forceinline__ h2 dpp1h(h2 v) {   // lane^1: quad_perm [1,0,3,2]
    int i = __builtin_bit_cast(int, v);
    return u2h((u32)__builtin_amdgcn_update_dpp(i, i, 0xB1, 0xF, 0xF, false));
}
__device__ __forceinline__ h2 dpp2h(h2 v) {   // lane^2: quad_perm [2,3,0,1]
    int i = __builtin_bit_cast(int, v);
    return u2h((u32)__builtin_amdgcn_update_dpp(i, i, 0x4E, 0xF, 0xF, false));
}
__device__ __forceinline__ h2 dpp8h(h2 v) {   // lane^8: row_ror:8
    int i = __builtin_bit_cast(int, v);
    return u2h((u32)__builtin_amdgcn_update_dpp(i, i, 0x128, 0xF, 0xF, false));
}

// f32 epilogue fetches (R10)
__device__ __forceinline__ float dpp1f(float v) {
    int i = f2i(v); return i2f(__builtin_amdgcn_update_dpp(i, i, 0xB1, 0xF, 0xF, false));
}
__device__ __forceinline__ float dpp2f(float v) {
    int i = f2i(v); return i2f(__builtin_amdgcn_update_dpp(i, i, 0x4E, 0xF, 0xF, false));
}
__device__ __forceinline__ float dpp8f(float v) {
    int i = f2i(v); return i2f(__builtin_amdgcn_update_dpp(i, i, 0x128, 0xF, 0xF, false));
}
__device__ __forceinline__ float swz4f(float v) {
    return i2f(__builtin_amdgcn_ds_swizzle(f2i(v), 0x101F));
}
__device__ __forceinline__ float swz16f(float v) {
    return i2f(__builtin_amdgcn_ds_swizzle(f2i(v), 0x401F));
}
__device__ __forceinline__ float bp32f(float v, int bpa) {
    return i2f(__builtin_amdgcn_ds_bpermute(bpa, f2i(v)));
}

// ---- local shear on r-bit B; NB = compile-time neighbor-sign mask ----
template<int B, int NB>
__device__ __forceinline__ void local_ry(h2 (&st)[16], h2 t) {
#pragma unroll
    for (int r0 = 0; r0 < 16; ++r0) {
        if ((r0 & (1 << B)) == 0) {
            const int r1 = r0 | (1 << B);
            const h2 a0 = st[r0], a1 = st[r1];
            if ((__builtin_popcount(r0 & NB) & 1) == 0) {
                st[r0] = fma2(t, -a1, a0);
                st[r1] = fma2(t,  a0, a1);
            } else {
                st[r0] = fma2(t,  a1, a0);
                st[r1] = fma2(t, -a0, a1);
            }
        }
    }
}

// per-lane sign words (0x80008000-style): nX plain layer, mX CZ-conjugated
struct Sgn { u32 n0, m0, n1, m1, n2, m2, n3, m3, n4, m4, n5, m5, gb0; };

// One RY layer + per-layer gamma scale; MOD => CZ-conjugated.
template<bool MOD>
__device__ __forceinline__ void ry_layer(h2 (&st)[16], const u32* __restrict__ tw,
                                         int base, int gi, int bpa, const Sgn& sg) {
    {   // wire 0: lane^32 via ds_bpermute
        const h2 ts = u2h(tw[base + 0] ^ (MOD ? sg.m0 : sg.n0));
#pragma unroll
        for (int r = 0; r < 16; ++r) st[r] = fma2(ts, bp32h(st[r], bpa), st[r]);
    }
    {   // wire 1: lane^16 via ds_swizzle
        const h2 ts = u2h(tw[base + 1] ^ (MOD ? sg.m1 : sg.n1));
#pragma unroll
        for (int r = 0; r < 16; ++r) st[r] = fma2(ts, swz16h(st[r]), st[r]);
    }
    {   // wire 2: lane^8 via DPP row_ror:8
        const h2 ts = u2h(tw[base + 2] ^ (MOD ? sg.m2 : sg.n2));
#pragma unroll
        for (int r = 0; r < 16; ++r) st[r] = fma2(ts, dpp8h(st[r]), st[r]);
    }
    {   // wire 3: lane^4 via ds_swizzle
        const h2 ts = u2h(tw[base + 3] ^ (MOD ? sg.m3 : sg.n3));
#pragma unroll
        for (int r = 0; r < 16; ++r) st[r] = fma2(ts, swz4h(st[r]), st[r]);
    }
    {   // wire 4: lane^2 via DPP quad_perm
        const h2 ts = u2h(tw[base + 4] ^ (MOD ? sg.m4 : sg.n4));
#pragma unroll
        for (int r = 0; r < 16; ++r) st[r] = fma2(ts, dpp2h(st[r]), st[r]);
    }
    {   // wire 5: lane^1 via DPP; MOD: hi half (r bit3) extra flip
        const h2 ts = u2h(tw[base + 5] ^ (MOD ? sg.m5 : sg.n5));
        const h2 th = MOD ? u2h(h2u(ts) ^ SGN2) : ts;
#pragma unroll
        for (int r = 0; r < 8; ++r)  st[r] = fma2(ts, dpp1h(st[r]), st[r]);
#pragma unroll
        for (int r = 8; r < 16; ++r) st[r] = fma2(th, dpp1h(st[r]), st[r]);
    }
    {   // wire 6: r bit 3; MOD: lane-bit0 sign + r-bit2 compile-time sign
        const h2 t = u2h(tw[base + 6] ^ (MOD ? sg.gb0 : 0u));
        local_ry<3, MOD ? 0x4 : 0>(st, t);
    }
    local_ry<2, MOD ? 0xA : 0>(st, u2h(tw[base + 7]));   // wire 7
    local_ry<1, MOD ? 0x5 : 0>(st, u2h(tw[base + 8]));   // wire 8
    local_ry<0, MOD ? 0x2 : 0>(st, u2h(tw[base + 9]));   // wire 9
    {   // per-layer cosine-product scale: keeps running norm == 1 (f16 range)
        const h2 g = u2h(tw[gi]);
#pragma unroll
        for (int r = 0; r < 16; ++r) st[r] = g * st[r];  // v_pk_mul_f16
    }
}

// ---- prep: packed-h2 tan table [0..59] + per-layer gamma [60..65] ----
__global__ void __launch_bounds__(64) qnn_prep(const float* __restrict__ params,
                                               u32* __restrict__ ws) {
    const int l = threadIdx.x;                    // 64 threads
    if (l < 60) {
        float s, c;
        __sincosf(params[l] * 0.5f, &s, &c);
        const float t = s / c;
        const h2 t2 = { (_Float16)t, (_Float16)t };
        ws[l] = h2u(t2);
    }
    if (l < 6) {
        float g = 1.f;
        for (int k = 0; k < 10; ++k) g *= __cosf(params[l * 10 + k] * 0.5f);
        const h2 g2 = { (_Float16)g, (_Float16)g };
        ws[60 + l] = h2u(g2);
    }
}

__global__ void __launch_bounds__(256) qnn_kernel(
    const float* __restrict__ x,       // (B, 10)
    const u32*   __restrict__ tw,      // (66,) packed tan + gamma tables
    const float* __restrict__ w_cls,   // (16, 10)
    const float* __restrict__ b_cls,   // (16,)
    float* __restrict__ out,           // (B, 16)
    int batch)
{
    const int lane = threadIdx.x & 63;
    const int wid  = threadIdx.x >> 6;
    const int b    = blockIdx.x * (blockDim.x >> 6) + wid;

    const int bpa = (lane ^ 32) << 2;             // bpermute addr (lane^32)

    // ---- encoding angles ----
    float cx, sx;
    { const int l = (lane < NQ) ? lane : 0; __sincosf(x[b * NQ + l] * 0.5f, &sx, &cx); }

    // ---- sign words (plain + CZ-conjugated), packed to both f16 halves ----
    Sgn sg;
    sg.gb0 = (lane & 1) ? SGN2 : 0;
    sg.n0 = (lane & 32) ? 0 : SGN2;  sg.m0 = sg.n0 ^ ((lane & 16) ? SGN2 : 0);
    sg.n1 = (lane & 16) ? 0 : SGN2;  sg.m1 = sg.n1 ^ ((((lane >> 5) ^ (lane >> 3)) & 1) ? SGN2 : 0);
    sg.n2 = (lane & 8)  ? 0 : SGN2;  sg.m2 = sg.n2 ^ ((((lane >> 4) ^ (lane >> 2)) & 1) ? SGN2 : 0);
    sg.n3 = (lane & 4)  ? 0 : SGN2;  sg.m3 = sg.n3 ^ ((((lane >> 3) ^ (lane >> 1)) & 1) ? SGN2 : 0);
    sg.n4 = (lane & 2)  ? 0 : SGN2;  sg.m4 = sg.n4 ^ ((((lane >> 2) ^ lane) & 1) ? SGN2 : 0);
    sg.n5 = (lane & 1)  ? 0 : SGN2;  sg.m5 = sg.n5 ^ ((lane & 2) ? SGN2 : 0);

    // ---- product state with absorbed initial CZ-sign (validated R7-R10) ----
    float F = 1.f;
#pragma unroll
    for (int q = 0; q < 6; ++q) {
        const float cq = rdlane(cx, q), sq = rdlane(sx, q);
        F *= ((lane >> (5 - q)) & 1) ? sq : cq;
    }
    const int lpar = __popc(lane & (lane >> 1) & 0x1F) & 1;      // lane-pair parity
    F = u2f(f2u(F) ^ (u32(lpar) << 31));
    const float c6 = rdlane(cx, 6), s6r = rdlane(sx, 6);
    const float c7 = rdlane(cx, 7), s7  = rdlane(sx, 7);
    const float c8 = rdlane(cx, 8), s8  = rdlane(sx, 8);
    const float c9 = rdlane(cx, 9), s9  = rdlane(sx, 9);
    const float s6m = (lane & 1) ? -s6r : s6r;                   // boundary pair fold
    const float mm[4] = {c8 * c9, c8 * s9, s8 * c9, s8 * s9};
    const float nn[4] = {F * (c6 * c7), F * (c6 * s7), F * (s6m * c7), F * (s6m * s7)};
    const int kl = __popc(lane) & 3;
    const float pa = (kl == 0) ? 1.f : ((kl == 2) ? -1.f : 0.f);
    const float pb = (kl == 1) ? -1.f : ((kl == 3) ? 1.f : 0.f);
    const float phx[4] = {pa, pb, -pa, -pb};
    const float phy[4] = {pb, -pa, -pb, pa};

    h2 st[16];
#pragma unroll
    for (int r = 0; r < 16; ++r) {
        const float Ar = nn[r >> 2] * mm[r & 3];
        const int j = ((__popc(r) & 3) + 2 * (__popc(r & (r >> 1) & 7) & 1)) & 3;
        st[r] = __builtin_bit_cast(h2, __builtin_amdgcn_cvt_pkrtz(Ar * phx[j], Ar * phy[j]));
    }

    // ---- layers: R1' R2 R3' R4 R5' R6 (MOD at d=0,2,4), gamma per layer ----
    ry_layer<true >(st, tw,  0, 60, bpa, sg);
    ry_layer<false>(st, tw, 10, 61, bpa, sg);
    ry_layer<true >(st, tw, 20, 62, bpa, sg);
    ry_layer<false>(st, tw, 30, 63, bpa, sg);
    ry_layer<true >(st, tw, 40, 64, bpa, sg);
    ry_layer<false>(st, tw, 50, 65, bpa, sg);

    // ---- probabilities: one v_dot2_f32_f16 per packed reg ----
    float pp[16];
#pragma unroll
    for (int r = 0; r < 16; ++r)
        pp[r] = __builtin_amdgcn_fdot2(st[r], st[r], 0.f, false);

    // shared in-register tree (r-wire expvals + pt)
    float a4[8]; float f9 = 0.f;
#pragma unroll
    for (int i = 0; i < 8; ++i) { a4[i] = pp[2*i] + pp[2*i+1]; f9 += pp[2*i] - pp[2*i+1]; }
    float b4[4]; float f8 = 0.f;
#pragma unroll
    for (int i = 0; i < 4; ++i) { b4[i] = a4[2*i] + a4[2*i+1]; f8 += a4[2*i] - a4[2*i+1]; }
    const float cc0 = b4[0] + b4[1], cc1 = b4[2] + b4[3];
    float f7 = (b4[0] - b4[1]) + (b4[2] - b4[3]);
    float f6 = cc0 - cc1;
    const float pt = cc0 + cc1;

    // full-wave sums for the r-wire expvals (DPP for 1,2,8; DS for 4,16,32)
#pragma unroll
    for (int q = 0; q < 4; ++q) {
        float v = (q == 0) ? f6 : (q == 1) ? f7 : (q == 2) ? f8 : f9;
        v += dpp1f(v);
        v += dpp2f(v);
        v += swz4f(v);
        v += dpp8f(v);
        v += swz16f(v);
        v += bp32f(v, bpa);
        if (q == 0) f6 = v; else if (q == 1) f7 = v; else if (q == 2) f8 = v; else f9 = v;
    }

    // one WHT butterfly on pt: lane s ends with sum_l (-1)^{popc(l&s)} pt_l
    float v = pt;
    {
        float p;
        p = dpp1f(v);       v = p + u2f(f2u(v) ^ ((lane & 1)  ? SGN : 0u));
        p = dpp2f(v);       v = p + u2f(f2u(v) ^ ((lane & 2)  ? SGN : 0u));
        p = swz4f(v);       v = p + u2f(f2u(v) ^ ((lane & 4)  ? SGN : 0u));
        p = dpp8f(v);       v = p + u2f(f2u(v) ^ ((lane & 8)  ? SGN : 0u));
        p = swz16f(v);      v = p + u2f(f2u(v) ^ ((lane & 16) ? SGN : 0u));
        p = bp32f(v, bpa);  v = p + u2f(f2u(v) ^ ((lane & 32) ? SGN : 0u));
    }
    const float e0 = rdlane(v, 32), e1 = rdlane(v, 16), e2 = rdlane(v, 8);
    const float e3 = rdlane(v, 4),  e4 = rdlane(v, 2),  e5 = rdlane(v, 1);

    // ---- linear head: lane k emits class k (state already normalized) ----
    if (lane < NCLS) {
        const float* wr = w_cls + lane * NQ;
        float dot = e0 * wr[0];
        dot = fmaf(e1, wr[1], dot);
        dot = fmaf(e2, wr[2], dot);
        dot = fmaf(e3, wr[3], dot);
        dot = fmaf(e4, wr[4], dot);
        dot = fmaf(e5, wr[5], dot);
        dot = fmaf(f6, wr[6], dot);
        dot = fmaf(f7, wr[7], dot);
        dot = fmaf(f8, wr[8], dot);
        dot = fmaf(f9, wr[9], dot);
        out[b * NCLS + lane] = dot + b_cls[lane];
    }
}

extern "C" void kernel_launch(void* const* d_in, const int* in_sizes, int n_in,
                              void* d_out, int out_size, void* d_ws, size_t ws_size,
                              hipStream_t stream) {
    const float* x      = (const float*)d_in[0];
    const float* params = (const float*)d_in[1];
    const float* w_cls  = (const float*)d_in[2];
    const float* b_cls  = (const float*)d_in[3];
    float* out = (float*)d_out;
    u32*   ws  = (u32*)d_ws;

    const int batch = in_sizes[0] / NQ;            // 65536
    const int WAVES_PER_BLOCK = 4;                 // 256 threads

    hipLaunchKernelGGL(qnn_prep, dim3(1), dim3(64), 0, stream, params, ws);

    dim3 block(64 * WAVES_PER_BLOCK);
    dim3 grid(batch / WAVES_PER_BLOCK);            // exact: 65536/4
    hipLaunchKernelGGL(qnn_kernel, grid, block, 0, stream,
                       x, (const u32*)ws, w_cls, b_cls, out, batch);
}

// Round 13
// 211.452 us; speedup vs baseline: 1.7357x; 1.0121x over previous
//
#include <hip/hip_runtime.h>
#include <math.h>

// Batched 10-qubit statevector sim: one wave per batch element.
// State = 1024 complex amps = 16 packed-f16 (re,im) regs per lane.
// Amp index a = (lane << 4) | r. Wire w acts on amp bit 9-w.
// Round-13: ALL SIX cross wires on the DS pipe (1 pk_fma + 1 ds/reg):
//   wire0 (lane^32): ds_bpermute          wire1 (lane^16): ds_swizzle 0x401F
//   wire2 (lane^8) : ds_swizzle 0x201F    wire3 (lane^4) : ds_swizzle 0x101F
//   wire4 (lane^2) : ds_swizzle 0x081F    wire5 (lane^1) : ds_swizzle 0x041F
//   wires6-9: in-register local shear (v_pk_fma_f16).
// Rationale: VOP3P (pk_fma) can't take DPP, so DPP wires cost 2 VALU/reg
// (mov_dpp + fma). Cross-round law: dur ~ 0.12-0.14us x VALU-instr/wave;
// DS was hidden at 600 ops/wave (R10 @246us). VALU ~1560 -> ~1220;
// ds ~320 -> ~660. If DS binds instead, this round pins its cost.
// gamma-scale now folded every OTHER layer (range growth <= ~12x, fine in
// f16). CZ layers absorbed as sign-modulated shears (R7); signs are
// 0x80008000 words xor'ed onto the packed wave-uniform tan (R10).

typedef unsigned int u32;
typedef _Float16 h2 __attribute__((ext_vector_type(2)));

constexpr int NQ = 10;
constexpr int NCLS = 16;
constexpr u32 SGN  = 0x80000000u;
constexpr u32 SGN2 = 0x80008000u;

__device__ __forceinline__ float i2f(int i) { return __builtin_bit_cast(float, i); }
__device__ __forceinline__ int   f2i(float f) { return __builtin_bit_cast(int, f); }
__device__ __forceinline__ u32   f2u(float f) { return __builtin_bit_cast(u32, f); }
__device__ __forceinline__ float u2f(u32 u)   { return __builtin_bit_cast(float, u); }
__device__ __forceinline__ u32   h2u(h2 v)    { return __builtin_bit_cast(u32, v); }
__device__ __forceinline__ h2    u2h(u32 u)   { return __builtin_bit_cast(h2, u); }

__device__ __forceinline__ float rdlane(float v, int l) {
    return i2f(__builtin_amdgcn_readlane(f2i(v), l));
}

__device__ __forceinline__ h2 fma2(h2 a, h2 b, h2 c) {
    return __builtin_elementwise_fma(a, b, c);          // v_pk_fma_f16
}

// ---- DS-pipe partner fetches (crossbar; BitMode xor within 32-halves) ----
template<int SWZ>
__device__ __forceinline__ h2 swzh(h2 v) {
    return u2h((u32)__builtin_amdgcn_ds_swizzle(__builtin_bit_cast(int, v), SWZ));
}
__device__ __forceinline__ h2 bp32h(h2 v, int bpa) {  // lane^32 (full-wave crossbar)
    return u2h((u32)__builtin_amdgcn_ds_bpermute(bpa, __builtin_bit_cast(int, v)));
}
template<int SWZ>
__device__ __forceinline__ float swzf(float v) {
    return i2f(__builtin_amdgcn_ds_swizzle(f2i(v), SWZ));
}
__device__ __forceinline__ float bp32f(float v, int bpa) {
    return i2f(__builtin_amdgcn_ds_bpermute(bpa, f2i(v)));
}

constexpr int SW1  = 0x041F;   // lane^1
constexpr int SW2  = 0x081F;   // lane^2
constexpr int SW4  = 0x101F;   // lane^4
constexpr int SW8  = 0x201F;   // lane^8
constexpr int SW16 = 0x401F;   // lane^16

// ---- local shear on r-bit B; NB = compile-time neighbor-sign mask ----
template<int B, int NB>
__device__ __forceinline__ void local_ry(h2 (&st)[16], h2 t) {
#pragma unroll
    for (int r0 = 0; r0 < 16; ++r0) {
        if ((r0 & (1 << B)) == 0) {
            const int r1 = r0 | (1 << B);
            const h2 a0 = st[r0], a1 = st[r1];
            if ((__builtin_popcount(r0 & NB) & 1) == 0) {
                st[r0] = fma2(t, -a1, a0);
                st[r1] = fma2(t,  a0, a1);
            } else {
                st[r0] = fma2(t,  a1, a0);
                st[r1] = fma2(t, -a0, a1);
            }
        }
    }
}

// per-lane sign words (0x80008000-style): nX plain layer, mX CZ-conjugated
struct Sgn { u32 n0, m0, n1, m1, n2, m2, n3, m3, n4, m4, n5, m5, gb0; };

// One RY layer; MOD => CZ-conjugated; GS => apply 2-layer gamma scale.
template<bool MOD, bool GS>
__device__ __forceinline__ void ry_layer(h2 (&st)[16], const u32* __restrict__ tw,
                                         int base, int gi, int bpa, const Sgn& sg) {
    {   // wire 0: lane^32 via ds_bpermute
        const h2 ts = u2h(tw[base + 0] ^ (MOD ? sg.m0 : sg.n0));
#pragma unroll
        for (int r = 0; r < 16; ++r) st[r] = fma2(ts, bp32h(st[r], bpa), st[r]);
    }
    {   // wire 1: lane^16
        const h2 ts = u2h(tw[base + 1] ^ (MOD ? sg.m1 : sg.n1));
#pragma unroll
        for (int r = 0; r < 16; ++r) st[r] = fma2(ts, swzh<SW16>(st[r]), st[r]);
    }
    {   // wire 2: lane^8
        const h2 ts = u2h(tw[base + 2] ^ (MOD ? sg.m2 : sg.n2));
#pragma unroll
        for (int r = 0; r < 16; ++r) st[r] = fma2(ts, swzh<SW8>(st[r]), st[r]);
    }
    {   // wire 3: lane^4
        const h2 ts = u2h(tw[base + 3] ^ (MOD ? sg.m3 : sg.n3));
#pragma unroll
        for (int r = 0; r < 16; ++r) st[r] = fma2(ts, swzh<SW4>(st[r]), st[r]);
    }
    {   // wire 4: lane^2
        const h2 ts = u2h(tw[base + 4] ^ (MOD ? sg.m4 : sg.n4));
#pragma unroll
        for (int r = 0; r < 16; ++r) st[r] = fma2(ts, swzh<SW2>(st[r]), st[r]);
    }
    {   // wire 5: lane^1; MOD: hi half (r bit3) extra flip
        const h2 ts = u2h(tw[base + 5] ^ (MOD ? sg.m5 : sg.n5));
        const h2 th = MOD ? u2h(h2u(ts) ^ SGN2) : ts;
#pragma unroll
        for (int r = 0; r < 8; ++r)  st[r] = fma2(ts, swzh<SW1>(st[r]), st[r]);
#pragma unroll
        for (int r = 8; r < 16; ++r) st[r] = fma2(th, swzh<SW1>(st[r]), st[r]);
    }
    {   // wire 6: r bit 3; MOD: lane-bit0 sign + r-bit2 compile-time sign
        const h2 t = u2h(tw[base + 6] ^ (MOD ? sg.gb0 : 0u));
        local_ry<3, MOD ? 0x4 : 0>(st, t);
    }
    local_ry<2, MOD ? 0xA : 0>(st, u2h(tw[base + 7]));   // wire 7
    local_ry<1, MOD ? 0x5 : 0>(st, u2h(tw[base + 8]));   // wire 8
    local_ry<0, MOD ? 0x2 : 0>(st, u2h(tw[base + 9]));   // wire 9
    if constexpr (GS) {   // 2-layer cosine-product scale (f16 range control)
        const h2 g = u2h(tw[gi]);
#pragma unroll
        for (int r = 0; r < 16; ++r) st[r] = g * st[r];  // v_pk_mul_f16
    }
}

// ---- prep: packed-h2 tan table [0..59] + 2-layer gamma [60..62] ----
__global__ void __launch_bounds__(64) qnn_prep(const float* __restrict__ params,
                                               u32* __restrict__ ws) {
    const int l = threadIdx.x;                    // 64 threads
    if (l < 60) {
        float s, c;
        __sincosf(params[l] * 0.5f, &s, &c);
        const float t = s / c;
        const h2 t2 = { (_Float16)t, (_Float16)t };
        ws[l] = h2u(t2);
    }
    if (l < 3) {
        float g = 1.f;
        for (int k = 0; k < 20; ++k) g *= __cosf(params[l * 20 + k] * 0.5f);
        const h2 g2 = { (_Float16)g, (_Float16)g };
        ws[60 + l] = h2u(g2);
    }
}

__global__ void __launch_bounds__(256) qnn_kernel(
    const float* __restrict__ x,       // (B, 10)
    const u32*   __restrict__ tw,      // (63,) packed tan + gamma tables
    const float* __restrict__ w_cls,   // (16, 10)
    const float* __restrict__ b_cls,   // (16,)
    float* __restrict__ out,           // (B, 16)
    int batch)
{
    const int lane = threadIdx.x & 63;
    const int wid  = threadIdx.x >> 6;
    const int b    = blockIdx.x * (blockDim.x >> 6) + wid;

    const int bpa = (lane ^ 32) << 2;             // bpermute addr (lane^32)

    // ---- encoding angles ----
    float cx, sx;
    { const int l = (lane < NQ) ? lane : 0; __sincosf(x[b * NQ + l] * 0.5f, &sx, &cx); }

    // ---- sign words (plain + CZ-conjugated), packed to both f16 halves ----
    Sgn sg;
    sg.gb0 = (lane & 1) ? SGN2 : 0;
    sg.n0 = (lane & 32) ? 0 : SGN2;  sg.m0 = sg.n0 ^ ((lane & 16) ? SGN2 : 0);
    sg.n1 = (lane & 16) ? 0 : SGN2;  sg.m1 = sg.n1 ^ ((((lane >> 5) ^ (lane >> 3)) & 1) ? SGN2 : 0);
    sg.n2 = (lane & 8)  ? 0 : SGN2;  sg.m2 = sg.n2 ^ ((((lane >> 4) ^ (lane >> 2)) & 1) ? SGN2 : 0);
    sg.n3 = (lane & 4)  ? 0 : SGN2;  sg.m3 = sg.n3 ^ ((((lane >> 3) ^ (lane >> 1)) & 1) ? SGN2 : 0);
    sg.n4 = (lane & 2)  ? 0 : SGN2;  sg.m4 = sg.n4 ^ ((((lane >> 2) ^ lane) & 1) ? SGN2 : 0);
    sg.n5 = (lane & 1)  ? 0 : SGN2;  sg.m5 = sg.n5 ^ ((lane & 2) ? SGN2 : 0);

    // ---- product state with absorbed initial CZ-sign (validated R7-R12) ----
    float F = 1.f;
#pragma unroll
    for (int q = 0; q < 6; ++q) {
        const float cq = rdlane(cx, q), sq = rdlane(sx, q);
        F *= ((lane >> (5 - q)) & 1) ? sq : cq;
    }
    const int lpar = __popc(lane & (lane >> 1) & 0x1F) & 1;      // lane-pair parity
    F = u2f(f2u(F) ^ (u32(lpar) << 31));
    const float c6 = rdlane(cx, 6), s6r = rdlane(sx, 6);
    const float c7 = rdlane(cx, 7), s7  = rdlane(sx, 7);
    const float c8 = rdlane(cx, 8), s8  = rdlane(sx, 8);
    const float c9 = rdlane(cx, 9), s9  = rdlane(sx, 9);
    const float s6m = (lane & 1) ? -s6r : s6r;                   // boundary pair fold
    const float mm[4] = {c8 * c9, c8 * s9, s8 * c9, s8 * s9};
    const float nn[4] = {F * (c6 * c7), F * (c6 * s7), F * (s6m * c7), F * (s6m * s7)};
    const int kl = __popc(lane) & 3;
    const float pa = (kl == 0) ? 1.f : ((kl == 2) ? -1.f : 0.f);
    const float pb = (kl == 1) ? -1.f : ((kl == 3) ? 1.f : 0.f);
    const float phx[4] = {pa, pb, -pa, -pb};
    const float phy[4] = {pb, -pa, -pb, pa};

    h2 st[16];
#pragma unroll
    for (int r = 0; r < 16; ++r) {
        const float Ar = nn[r >> 2] * mm[r & 3];
        const int j = ((__popc(r) & 3) + 2 * (__popc(r & (r >> 1) & 7) & 1)) & 3;
        st[r] = __builtin_bit_cast(h2, __builtin_amdgcn_cvt_pkrtz(Ar * phx[j], Ar * phy[j]));
    }

    // ---- layers: R1' R2 R3' R4 R5' R6 (MOD at d=0,2,4); gamma at 1,3,5 ----
    ry_layer<true , false>(st, tw,  0,  0, bpa, sg);
    ry_layer<false, true >(st, tw, 10, 60, bpa, sg);
    ry_layer<true , false>(st, tw, 20,  0, bpa, sg);
    ry_layer<false, true >(st, tw, 30, 61, bpa, sg);
    ry_layer<true , false>(st, tw, 40,  0, bpa, sg);
    ry_layer<false, true >(st, tw, 50, 62, bpa, sg);

    // ---- probabilities: one v_dot2_f32_f16 per packed reg ----
    float pp[16];
#pragma unroll
    for (int r = 0; r < 16; ++r)
        pp[r] = __builtin_amdgcn_fdot2(st[r], st[r], 0.f, false);

    // shared in-register tree (r-wire expvals + pt)
    float a4[8]; float f9 = 0.f;
#pragma unroll
    for (int i = 0; i < 8; ++i) { a4[i] = pp[2*i] + pp[2*i+1]; f9 += pp[2*i] - pp[2*i+1]; }
    float b4[4]; float f8 = 0.f;
#pragma unroll
    for (int i = 0; i < 4; ++i) { b4[i] = a4[2*i] + a4[2*i+1]; f8 += a4[2*i] - a4[2*i+1]; }
    const float cc0 = b4[0] + b4[1], cc1 = b4[2] + b4[3];
    float f7 = (b4[0] - b4[1]) + (b4[2] - b4[3]);
    float f6 = cc0 - cc1;
    const float pt = cc0 + cc1;

    // full-wave sums for the r-wire expvals (all-DS butterfly)
#pragma unroll
    for (int q = 0; q < 4; ++q) {
        float v = (q == 0) ? f6 : (q == 1) ? f7 : (q == 2) ? f8 : f9;
        v += swzf<SW1>(v);
        v += swzf<SW2>(v);
        v += swzf<SW4>(v);
        v += swzf<SW8>(v);
        v += swzf<SW16>(v);
        v += bp32f(v, bpa);
        if (q == 0) f6 = v; else if (q == 1) f7 = v; else if (q == 2) f8 = v; else f9 = v;
    }

    // one WHT butterfly on pt: lane s ends with sum_l (-1)^{popc(l&s)} pt_l
    float v = pt;
    {
        float p;
        p = swzf<SW1>(v);   v = p + u2f(f2u(v) ^ ((lane & 1)  ? SGN : 0u));
        p = swzf<SW2>(v);   v = p + u2f(f2u(v) ^ ((lane & 2)  ? SGN : 0u));
        p = swzf<SW4>(v);   v = p + u2f(f2u(v) ^ ((lane & 4)  ? SGN : 0u));
        p = swzf<SW8>(v);   v = p + u2f(f2u(v) ^ ((lane & 8)  ? SGN : 0u));
        p = swzf<SW16>(v);  v = p + u2f(f2u(v) ^ ((lane & 16) ? SGN : 0u));
        p = bp32f(v, bpa);  v = p + u2f(f2u(v) ^ ((lane & 32) ? SGN : 0u));
    }
    const float e0 = rdlane(v, 32), e1 = rdlane(v, 16), e2 = rdlane(v, 8);
    const float e3 = rdlane(v, 4),  e4 = rdlane(v, 2),  e5 = rdlane(v, 1);

    // ---- linear head: lane k emits class k (state already normalized) ----
    if (lane < NCLS) {
        const float* wr = w_cls + lane * NQ;
        float dot = e0 * wr[0];
        dot = fmaf(e1, wr[1], dot);
        dot = fmaf(e2, wr[2], dot);
        dot = fmaf(e3, wr[3], dot);
        dot = fmaf(e4, wr[4], dot);
        dot = fmaf(e5, wr[5], dot);
        dot = fmaf(f6, wr[6], dot);
        dot = fmaf(f7, wr[7], dot);
        dot = fmaf(f8, wr[8], dot);
        dot = fmaf(f9, wr[9], dot);
        out[b * NCLS + lane] = dot + b_cls[lane];
    }
}

extern "C" void kernel_launch(void* const* d_in, const int* in_sizes, int n_in,
                              void* d_out, int out_size, void* d_ws, size_t ws_size,
                              hipStream_t stream) {
    const float* x      = (const float*)d_in[0];
    const float* params = (const float*)d_in[1];
    const float* w_cls  = (const float*)d_in[2];
    const float* b_cls  = (const float*)d_in[3];
    float* out = (float*)d_out;
    u32*   ws  = (u32*)d_ws;

    const int batch = in_sizes[0] / NQ;            // 65536
    const int WAVES_PER_BLOCK = 4;                 // 256 threads

    hipLaunchKernelGGL(qnn_prep, dim3(1), dim3(64), 0, stream, params, ws);

    dim3 block(64 * WAVES_PER_BLOCK);
    dim3 grid(batch / WAVES_PER_BLOCK);            // exact: 65536/4
    hipLaunchKernelGGL(qnn_kernel, grid, block, 0, stream,
                       x, (const u32*)ws, w_cls, b_cls, out, batch);
}

// Round 14
// 196.835 us; speedup vs baseline: 1.8646x; 1.0743x over previous
//
#include <hip/hip_runtime.h>
#include <math.h>

// Batched 10-qubit statevector sim: one wave per batch element.
// State = 1024 complex amps = 16 packed-f16 (re,im) regs per lane.
// Amp index a = (lane << 4) | r. Wire w acts on amp bit 9-w.
// Round-14: PIPE REBALANCE. R13 counters: VALUBusy 69%, DS-bound
// (660 ds/wave x 0.32us = 211us; VALU 1220 x 0.12us = 146us). Min-max over
// "k wires moved DS->DPP" says k=2 is optimal:
//   wire0 (lane^32): ds_bpermute          wire1 (lane^16): ds_swizzle 0x401F
//   wire2 (lane^8) : mov_dpp row_ror:8 + pk_fma   (VALU, R12-proven)
//   wire3 (lane^4) : ds_swizzle 0x101F
//   wire4 (lane^2) : mov_dpp quad[2,3,0,1] + pk_fma (VALU)
//   wire5 (lane^1) : ds_swizzle 0x041F
//   wires6-9: in-register local shear (v_pk_fma_f16).
// Epilogue: f6/f7 and f8/f9 wave-sums packed into two h2 butterflies
// (pk_add; -12 ds, -18 VALU; f16 rounding ~2e-3 abs, ample headroom).
// gamma-scale every other layer (f16 range); CZ absorbed as sign-modulated
// shears (R7); signs as 0x80008000 words xor'ed onto packed tan (R10).

typedef unsigned int u32;
typedef _Float16 h2 __attribute__((ext_vector_type(2)));

constexpr int NQ = 10;
constexpr int NCLS = 16;
constexpr u32 SGN  = 0x80000000u;
constexpr u32 SGN2 = 0x80008000u;

__device__ __forceinline__ float i2f(int i) { return __builtin_bit_cast(float, i); }
__device__ __forceinline__ int   f2i(float f) { return __builtin_bit_cast(int, f); }
__device__ __forceinline__ u32   f2u(float f) { return __builtin_bit_cast(u32, f); }
__device__ __forceinline__ float u2f(u32 u)   { return __builtin_bit_cast(float, u); }
__device__ __forceinline__ u32   h2u(h2 v)    { return __builtin_bit_cast(u32, v); }
__device__ __forceinline__ h2    u2h(u32 u)   { return __builtin_bit_cast(h2, u); }

__device__ __forceinline__ float rdlane(float v, int l) {
    return i2f(__builtin_amdgcn_readlane(f2i(v), l));
}

__device__ __forceinline__ h2 fma2(h2 a, h2 b, h2 c) {
    return __builtin_elementwise_fma(a, b, c);          // v_pk_fma_f16
}

// ---- DS-pipe partner fetches (crossbar) ----
template<int SWZ>
__device__ __forceinline__ h2 swzh(h2 v) {
    return u2h((u32)__builtin_amdgcn_ds_swizzle(__builtin_bit_cast(int, v), SWZ));
}
__device__ __forceinline__ h2 bp32h(h2 v, int bpa) {  // lane^32 (full-wave crossbar)
    return u2h((u32)__builtin_amdgcn_ds_bpermute(bpa, __builtin_bit_cast(int, v)));
}
template<int SWZ>
__device__ __forceinline__ float swzf(float v) {
    return i2f(__builtin_amdgcn_ds_swizzle(f2i(v), SWZ));
}
__device__ __forceinline__ float bp32f(float v, int bpa) {
    return i2f(__builtin_amdgcn_ds_bpermute(bpa, f2i(v)));
}

constexpr int SW1  = 0x041F;   // lane^1
constexpr int SW2  = 0x081F;   // lane^2
constexpr int SW4  = 0x101F;   // lane^4
constexpr int SW8  = 0x201F;   // lane^8
constexpr int SW16 = 0x401F;   // lane^16

// ---- VALU DPP partner fetches (compiler inserts hazard waits) ----
__device__ __forceinline__ h2 dpp2h(h2 v) {   // lane^2: quad_perm [2,3,0,1]
    int i = __builtin_bit_cast(int, v);
    return u2h((u32)__builtin_amdgcn_update_dpp(i, i, 0x4E, 0xF, 0xF, false));
}
__device__ __forceinline__ h2 dpp8h(h2 v) {   // lane^8: row_ror:8
    int i = __builtin_bit_cast(int, v);
    return u2h((u32)__builtin_amdgcn_update_dpp(i, i, 0x128, 0xF, 0xF, false));
}

// ---- local shear on r-bit B; NB = compile-time neighbor-sign mask ----
template<int B, int NB>
__device__ __forceinline__ void local_ry(h2 (&st)[16], h2 t) {
#pragma unroll
    for (int r0 = 0; r0 < 16; ++r0) {
        if ((r0 & (1 << B)) == 0) {
            const int r1 = r0 | (1 << B);
            const h2 a0 = st[r0], a1 = st[r1];
            if ((__builtin_popcount(r0 & NB) & 1) == 0) {
                st[r0] = fma2(t, -a1, a0);
                st[r1] = fma2(t,  a0, a1);
            } else {
                st[r0] = fma2(t,  a1, a0);
                st[r1] = fma2(t, -a0, a1);
            }
        }
    }
}

// per-lane sign words (0x80008000-style): nX plain layer, mX CZ-conjugated
struct Sgn { u32 n0, m0, n1, m1, n2, m2, n3, m3, n4, m4, n5, m5, gb0; };

// One RY layer; MOD => CZ-conjugated; GS => apply 2-layer gamma scale.
template<bool MOD, bool GS>
__device__ __forceinline__ void ry_layer(h2 (&st)[16], const u32* __restrict__ tw,
                                         int base, int gi, int bpa, const Sgn& sg) {
    {   // wire 0: lane^32 via ds_bpermute (DS)
        const h2 ts = u2h(tw[base + 0] ^ (MOD ? sg.m0 : sg.n0));
#pragma unroll
        for (int r = 0; r < 16; ++r) st[r] = fma2(ts, bp32h(st[r], bpa), st[r]);
    }
    {   // wire 1: lane^16 via ds_swizzle (DS)
        const h2 ts = u2h(tw[base + 1] ^ (MOD ? sg.m1 : sg.n1));
#pragma unroll
        for (int r = 0; r < 16; ++r) st[r] = fma2(ts, swzh<SW16>(st[r]), st[r]);
    }
    {   // wire 2: lane^8 via mov_dpp row_ror:8 + pk_fma (VALU)
        const h2 ts = u2h(tw[base + 2] ^ (MOD ? sg.m2 : sg.n2));
#pragma unroll
        for (int r = 0; r < 16; ++r) st[r] = fma2(ts, dpp8h(st[r]), st[r]);
    }
    {   // wire 3: lane^4 via ds_swizzle (DS)
        const h2 ts = u2h(tw[base + 3] ^ (MOD ? sg.m3 : sg.n3));
#pragma unroll
        for (int r = 0; r < 16; ++r) st[r] = fma2(ts, swzh<SW4>(st[r]), st[r]);
    }
    {   // wire 4: lane^2 via mov_dpp quad_perm + pk_fma (VALU)
        const h2 ts = u2h(tw[base + 4] ^ (MOD ? sg.m4 : sg.n4));
#pragma unroll
        for (int r = 0; r < 16; ++r) st[r] = fma2(ts, dpp2h(st[r]), st[r]);
    }
    {   // wire 5: lane^1 via ds_swizzle (DS); MOD: hi half (r bit3) extra flip
        const h2 ts = u2h(tw[base + 5] ^ (MOD ? sg.m5 : sg.n5));
        const h2 th = MOD ? u2h(h2u(ts) ^ SGN2) : ts;
#pragma unroll
        for (int r = 0; r < 8; ++r)  st[r] = fma2(ts, swzh<SW1>(st[r]), st[r]);
#pragma unroll
        for (int r = 8; r < 16; ++r) st[r] = fma2(th, swzh<SW1>(st[r]), st[r]);
    }
    {   // wire 6: r bit 3; MOD: lane-bit0 sign + r-bit2 compile-time sign
        const h2 t = u2h(tw[base + 6] ^ (MOD ? sg.gb0 : 0u));
        local_ry<3, MOD ? 0x4 : 0>(st, t);
    }
    local_ry<2, MOD ? 0xA : 0>(st, u2h(tw[base + 7]));   // wire 7
    local_ry<1, MOD ? 0x5 : 0>(st, u2h(tw[base + 8]));   // wire 8
    local_ry<0, MOD ? 0x2 : 0>(st, u2h(tw[base + 9]));   // wire 9
    if constexpr (GS) {   // 2-layer cosine-product scale (f16 range control)
        const h2 g = u2h(tw[gi]);
#pragma unroll
        for (int r = 0; r < 16; ++r) st[r] = g * st[r];  // v_pk_mul_f16
    }
}

// ---- prep: packed-h2 tan table [0..59] + 2-layer gamma [60..62] ----
__global__ void __launch_bounds__(64) qnn_prep(const float* __restrict__ params,
                                               u32* __restrict__ ws) {
    const int l = threadIdx.x;                    // 64 threads
    if (l < 60) {
        float s, c;
        __sincosf(params[l] * 0.5f, &s, &c);
        const float t = s / c;
        const h2 t2 = { (_Float16)t, (_Float16)t };
        ws[l] = h2u(t2);
    }
    if (l < 3) {
        float g = 1.f;
        for (int k = 0; k < 20; ++k) g *= __cosf(params[l * 20 + k] * 0.5f);
        const h2 g2 = { (_Float16)g, (_Float16)g };
        ws[60 + l] = h2u(g2);
    }
}

__global__ void __launch_bounds__(256) qnn_kernel(
    const float* __restrict__ x,       // (B, 10)
    const u32*   __restrict__ tw,      // (63,) packed tan + gamma tables
    const float* __restrict__ w_cls,   // (16, 10)
    const float* __restrict__ b_cls,   // (16,)
    float* __restrict__ out,           // (B, 16)
    int batch)
{
    const int lane = threadIdx.x & 63;
    const int wid  = threadIdx.x >> 6;
    const int b    = blockIdx.x * (blockDim.x >> 6) + wid;

    const int bpa = (lane ^ 32) << 2;             // bpermute addr (lane^32)

    // ---- encoding angles ----
    float cx, sx;
    { const int l = (lane < NQ) ? lane : 0; __sincosf(x[b * NQ + l] * 0.5f, &sx, &cx); }

    // ---- sign words (plain + CZ-conjugated), packed to both f16 halves ----
    Sgn sg;
    sg.gb0 = (lane & 1) ? SGN2 : 0;
    sg.n0 = (lane & 32) ? 0 : SGN2;  sg.m0 = sg.n0 ^ ((lane & 16) ? SGN2 : 0);
    sg.n1 = (lane & 16) ? 0 : SGN2;  sg.m1 = sg.n1 ^ ((((lane >> 5) ^ (lane >> 3)) & 1) ? SGN2 : 0);
    sg.n2 = (lane & 8)  ? 0 : SGN2;  sg.m2 = sg.n2 ^ ((((lane >> 4) ^ (lane >> 2)) & 1) ? SGN2 : 0);
    sg.n3 = (lane & 4)  ? 0 : SGN2;  sg.m3 = sg.n3 ^ ((((lane >> 3) ^ (lane >> 1)) & 1) ? SGN2 : 0);
    sg.n4 = (lane & 2)  ? 0 : SGN2;  sg.m4 = sg.n4 ^ ((((lane >> 2) ^ lane) & 1) ? SGN2 : 0);
    sg.n5 = (lane & 1)  ? 0 : SGN2;  sg.m5 = sg.n5 ^ ((lane & 2) ? SGN2 : 0);

    // ---- product state with absorbed initial CZ-sign (validated R7-R13) ----
    float F = 1.f;
#pragma unroll
    for (int q = 0; q < 6; ++q) {
        const float cq = rdlane(cx, q), sq = rdlane(sx, q);
        F *= ((lane >> (5 - q)) & 1) ? sq : cq;
    }
    const int lpar = __popc(lane & (lane >> 1) & 0x1F) & 1;      // lane-pair parity
    F = u2f(f2u(F) ^ (u32(lpar) << 31));
    const float c6 = rdlane(cx, 6), s6r = rdlane(sx, 6);
    const float c7 = rdlane(cx, 7), s7  = rdlane(sx, 7);
    const float c8 = rdlane(cx, 8), s8  = rdlane(sx, 8);
    const float c9 = rdlane(cx, 9), s9  = rdlane(sx, 9);
    const float s6m = (lane & 1) ? -s6r : s6r;                   // boundary pair fold
    const float mm[4] = {c8 * c9, c8 * s9, s8 * c9, s8 * s9};
    const float nn[4] = {F * (c6 * c7), F * (c6 * s7), F * (s6m * c7), F * (s6m * s7)};
    const int kl = __popc(lane) & 3;
    const float pa = (kl == 0) ? 1.f : ((kl == 2) ? -1.f : 0.f);
    const float pb = (kl == 1) ? -1.f : ((kl == 3) ? 1.f : 0.f);
    const float phx[4] = {pa, pb, -pa, -pb};
    const float phy[4] = {pb, -pa, -pb, pa};

    h2 st[16];
#pragma unroll
    for (int r = 0; r < 16; ++r) {
        const float Ar = nn[r >> 2] * mm[r & 3];
        const int j = ((__popc(r) & 3) + 2 * (__popc(r & (r >> 1) & 7) & 1)) & 3;
        st[r] = __builtin_bit_cast(h2, __builtin_amdgcn_cvt_pkrtz(Ar * phx[j], Ar * phy[j]));
    }

    // ---- layers: R1' R2 R3' R4 R5' R6 (MOD at d=0,2,4); gamma at 1,3,5 ----
    ry_layer<true , false>(st, tw,  0,  0, bpa, sg);
    ry_layer<false, true >(st, tw, 10, 60, bpa, sg);
    ry_layer<true , false>(st, tw, 20,  0, bpa, sg);
    ry_layer<false, true >(st, tw, 30, 61, bpa, sg);
    ry_layer<true , false>(st, tw, 40,  0, bpa, sg);
    ry_layer<false, true >(st, tw, 50, 62, bpa, sg);

    // ---- probabilities: one v_dot2_f32_f16 per packed reg ----
    float pp[16];
#pragma unroll
    for (int r = 0; r < 16; ++r)
        pp[r] = __builtin_amdgcn_fdot2(st[r], st[r], 0.f, false);

    // shared in-register tree (r-wire expvals + pt)
    float a4[8]; float f9 = 0.f;
#pragma unroll
    for (int i = 0; i < 8; ++i) { a4[i] = pp[2*i] + pp[2*i+1]; f9 += pp[2*i] - pp[2*i+1]; }
    float b4[4]; float f8 = 0.f;
#pragma unroll
    for (int i = 0; i < 4; ++i) { b4[i] = a4[2*i] + a4[2*i+1]; f8 += a4[2*i] - a4[2*i+1]; }
    const float cc0 = b4[0] + b4[1], cc1 = b4[2] + b4[3];
    float f7 = (b4[0] - b4[1]) + (b4[2] - b4[3]);
    float f6 = cc0 - cc1;
    const float pt = cc0 + cc1;

    // full-wave sums for f6..f9: packed pairwise into two h2 butterflies
    h2 v67 = __builtin_bit_cast(h2, __builtin_amdgcn_cvt_pkrtz(f6, f7));
    h2 v89 = __builtin_bit_cast(h2, __builtin_amdgcn_cvt_pkrtz(f8, f9));
    v67 += swzh<SW1>(v67);   v89 += swzh<SW1>(v89);
    v67 += swzh<SW2>(v67);   v89 += swzh<SW2>(v89);
    v67 += swzh<SW4>(v67);   v89 += swzh<SW4>(v89);
    v67 += swzh<SW8>(v67);   v89 += swzh<SW8>(v89);
    v67 += swzh<SW16>(v67);  v89 += swzh<SW16>(v89);
    v67 += bp32h(v67, bpa);  v89 += bp32h(v89, bpa);
    f6 = (float)v67[0]; f7 = (float)v67[1];
    f8 = (float)v89[0]; f9 = (float)v89[1];

    // one WHT butterfly on pt: lane s ends with sum_l (-1)^{popc(l&s)} pt_l
    float v = pt;
    {
        float p;
        p = swzf<SW1>(v);   v = p + u2f(f2u(v) ^ ((lane & 1)  ? SGN : 0u));
        p = swzf<SW2>(v);   v = p + u2f(f2u(v) ^ ((lane & 2)  ? SGN : 0u));
        p = swzf<SW4>(v);   v = p + u2f(f2u(v) ^ ((lane & 4)  ? SGN : 0u));
        p = swzf<SW8>(v);   v = p + u2f(f2u(v) ^ ((lane & 8)  ? SGN : 0u));
        p = swzf<SW16>(v);  v = p + u2f(f2u(v) ^ ((lane & 16) ? SGN : 0u));
        p = bp32f(v, bpa);  v = p + u2f(f2u(v) ^ ((lane & 32) ? SGN : 0u));
    }
    const float e0 = rdlane(v, 32), e1 = rdlane(v, 16), e2 = rdlane(v, 8);
    const float e3 = rdlane(v, 4),  e4 = rdlane(v, 2),  e5 = rdlane(v, 1);

    // ---- linear head: lane k emits class k (state already normalized) ----
    if (lane < NCLS) {
        const float* wr = w_cls + lane * NQ;
        float dot = e0 * wr[0];
        dot = fmaf(e1, wr[1], dot);
        dot = fmaf(e2, wr[2], dot);
        dot = fmaf(e3, wr[3], dot);
        dot = fmaf(e4, wr[4], dot);
        dot = fmaf(e5, wr[5], dot);
        dot = fmaf(f6, wr[6], dot);
        dot = fmaf(f7, wr[7], dot);
        dot = fmaf(f8, wr[8], dot);
        dot = fmaf(f9, wr[9], dot);
        out[b * NCLS + lane] = dot + b_cls[lane];
    }
}

extern "C" void kernel_launch(void* const* d_in, const int* in_sizes, int n_in,
                              void* d_out, int out_size, void* d_ws, size_t ws_size,
                              hipStream_t stream) {
    const float* x      = (const float*)d_in[0];
    const float* params = (const float*)d_in[1];
    const float* w_cls  = (const float*)d_in[2];
    const float* b_cls  = (const float*)d_in[3];
    float* out = (float*)d_out;
    u32*   ws  = (u32*)d_ws;

    const int batch = in_sizes[0] / NQ;            // 65536
    const int WAVES_PER_BLOCK = 4;                 // 256 threads

    hipLaunchKernelGGL(qnn_prep, dim3(1), dim3(64), 0, stream, params, ws);

    dim3 block(64 * WAVES_PER_BLOCK);
    dim3 grid(batch / WAVES_PER_BLOCK);            // exact: 65536/4
    hipLaunchKernelGGL(qnn_kernel, grid, block, 0, stream,
                       x, (const u32*)ws, w_cls, b_cls, out, batch);
}

// Round 15
// 161.056 us; speedup vs baseline: 2.2789x; 1.2222x over previous
//
#include <hip/hip_runtime.h>
#include <math.h>

// Batched 10-qubit statevector sim — FOUR batch elements per wave.
// Each 16-lane group owns one element: amp a = (lane&15)<<6 | r, r in [0,64).
// State = 64 packed-f16 (re,im) regs per lane. Wire w acts on amp bit 9-w:
//   wires 0-3: cross within 16-group, masks 8/4/2/1 via ds_swizzle (DS pipe)
//   wires 4-9: in-register local shear on r bits 5..0 (v_pk_fma_f16)
// vs R14: cross wires 6->4, DPP movs gone, bpermute gone, prologue/epilogue
// amortized over 4 elements. VALU total 94M->~77M, DS ~26M (hidden).
// Sign machinery (R7 CZ absorption) re-derived for the new bit split:
//   CZ pairs: lane-lane (bits 9-8,8-7,7-6 -> lpar mask 0x7), boundary
//   (bit6=lane b0, bit5=r b5 -> s4-fold), r-r (bits 5..0 -> phase mask 0x1F).
//   MOD layer wire signs: w0<-lane b2; w1<-b3^b1; w2<-b2^b0; w3<-b1 (+r b5
//   runtime half-flip); w4<-lane b0 (xor word) + r b4 (NB 0x10); w5..w9 <-
//   NB masks 0x28,0x14,0x0A,0x05,0x02.
// gamma-scale every other layer (f16 range); tan-shear + prep table (R9+).

typedef unsigned int u32;
typedef _Float16 h2 __attribute__((ext_vector_type(2)));

constexpr int NQ = 10;
constexpr int NCLS = 16;
constexpr u32 SGN  = 0x80000000u;
constexpr u32 SGN2 = 0x80008000u;

__device__ __forceinline__ float i2f(int i) { return __builtin_bit_cast(float, i); }
__device__ __forceinline__ int   f2i(float f) { return __builtin_bit_cast(int, f); }
__device__ __forceinline__ u32   f2u(float f) { return __builtin_bit_cast(u32, f); }
__device__ __forceinline__ float u2f(u32 u)   { return __builtin_bit_cast(float, u); }
__device__ __forceinline__ u32   h2u(h2 v)    { return __builtin_bit_cast(u32, v); }
__device__ __forceinline__ h2    u2h(u32 u)   { return __builtin_bit_cast(h2, u); }

__device__ __forceinline__ h2 fma2(h2 a, h2 b, h2 c) {
    return __builtin_elementwise_fma(a, b, c);          // v_pk_fma_f16
}

template<int SWZ>
__device__ __forceinline__ h2 swzh(h2 v) {
    return u2h((u32)__builtin_amdgcn_ds_swizzle(__builtin_bit_cast(int, v), SWZ));
}
template<int SWZ>
__device__ __forceinline__ float swzf(float v) {
    return i2f(__builtin_amdgcn_ds_swizzle(f2i(v), SWZ));
}

constexpr int SW1 = 0x041F;   // lane^1 (within 16-group)
constexpr int SW2 = 0x081F;   // lane^2
constexpr int SW4 = 0x101F;   // lane^4
constexpr int SW8 = 0x201F;   // lane^8
#define GBC(q) (0x10 | ((q) << 5))   // 16-group broadcast of group-lane q

// ---- cross shear: st[r] += ts * partner(st[r]) over all 64 regs ----
template<int SWZ>
__device__ __forceinline__ void cross_ry(h2 (&st)[64], h2 ts) {
#pragma unroll
    for (int r = 0; r < 64; ++r) st[r] = fma2(ts, swzh<SWZ>(st[r]), st[r]);
}

// ---- local shear on r-bit B; NB = compile-time neighbor-sign mask ----
template<int B, int NB>
__device__ __forceinline__ void local_ry(h2 (&st)[64], h2 t) {
#pragma unroll
    for (int r0 = 0; r0 < 64; ++r0) {
        if ((r0 & (1 << B)) == 0) {
            const int r1 = r0 | (1 << B);
            const h2 a0 = st[r0], a1 = st[r1];
            if ((__builtin_popcount(r0 & NB) & 1) == 0) {
                st[r0] = fma2(t, -a1, a0);
                st[r1] = fma2(t,  a0, a1);
            } else {
                st[r0] = fma2(t,  a1, a0);
                st[r1] = fma2(t, -a0, a1);
            }
        }
    }
}

// per-lane sign words: nX plain, mX CZ-conjugated; g4 = wire4 MOD lane word
struct Sgn { u32 n0, m0, n1, m1, n2, m2, n3, m3, g4; };

template<bool MOD, bool GS>
__device__ __forceinline__ void ry_layer(h2 (&st)[64], const u32* __restrict__ tw,
                                         int base, int gi, const Sgn& sg) {
    { const h2 ts = u2h(tw[base + 0] ^ (MOD ? sg.m0 : sg.n0)); cross_ry<SW8>(st, ts); }
    { const h2 ts = u2h(tw[base + 1] ^ (MOD ? sg.m1 : sg.n1)); cross_ry<SW4>(st, ts); }
    { const h2 ts = u2h(tw[base + 2] ^ (MOD ? sg.m2 : sg.n2)); cross_ry<SW2>(st, ts); }
    {   // wire 3 (mask 1); MOD: extra flip on r bit5 half
        const h2 ts = u2h(tw[base + 3] ^ (MOD ? sg.m3 : sg.n3));
        if constexpr (MOD) {
            const h2 th = u2h(h2u(ts) ^ SGN2);
#pragma unroll
            for (int r = 0; r < 32; ++r)  st[r] = fma2(ts, swzh<SW1>(st[r]), st[r]);
#pragma unroll
            for (int r = 32; r < 64; ++r) st[r] = fma2(th, swzh<SW1>(st[r]), st[r]);
        } else {
            cross_ry<SW1>(st, ts);
        }
    }
    { const h2 t = u2h(tw[base + 4] ^ (MOD ? sg.g4 : 0u));
      local_ry<5, MOD ? 0x10 : 0>(st, t); }                    // wire 4
    local_ry<4, MOD ? 0x28 : 0>(st, u2h(tw[base + 5]));        // wire 5
    local_ry<3, MOD ? 0x14 : 0>(st, u2h(tw[base + 6]));        // wire 6
    local_ry<2, MOD ? 0x0A : 0>(st, u2h(tw[base + 7]));        // wire 7
    local_ry<1, MOD ? 0x05 : 0>(st, u2h(tw[base + 8]));        // wire 8
    local_ry<0, MOD ? 0x02 : 0>(st, u2h(tw[base + 9]));        // wire 9
    if constexpr (GS) {
        const h2 g = u2h(tw[gi]);
#pragma unroll
        for (int r = 0; r < 64; ++r) st[r] = g * st[r];        // v_pk_mul_f16
    }
}

// ---- prep: packed-h2 tan table [0..59] + 2-layer gamma [60..62] ----
__global__ void __launch_bounds__(64) qnn_prep(const float* __restrict__ params,
                                               u32* __restrict__ ws) {
    const int l = threadIdx.x;
    if (l < 60) {
        float s, c;
        __sincosf(params[l] * 0.5f, &s, &c);
        const float t = s / c;
        const h2 t2 = { (_Float16)t, (_Float16)t };
        ws[l] = h2u(t2);
    }
    if (l < 3) {
        float g = 1.f;
        for (int k = 0; k < 20; ++k) g *= __cosf(params[l * 20 + k] * 0.5f);
        const h2 g2 = { (_Float16)g, (_Float16)g };
        ws[60 + l] = h2u(g2);
    }
}

__global__ void __launch_bounds__(256) qnn_kernel(
    const float* __restrict__ x,       // (B, 10)
    const u32*   __restrict__ tw,      // (63,) packed tan + gamma tables
    const float* __restrict__ w_cls,   // (16, 10)
    const float* __restrict__ b_cls,   // (16,)
    float* __restrict__ out,           // (B, 16)
    int batch)
{
    const int lane = threadIdx.x & 63;
    const int wid  = threadIdx.x >> 6;
    const int wave = blockIdx.x * (blockDim.x >> 6) + wid;
    const int g    = lane & 15;                   // group lane
    const int b    = wave * 4 + (lane >> 4);      // this lane's batch element

    // ---- encoding angles: group lane q (<10) owns wire q of its element ----
    float cx, sx;
    { const int q = (g < NQ) ? g : 0; __sincosf(x[b * NQ + q] * 0.5f, &sx, &cx); }

    // group-local broadcasts of all 10 (c,s) pairs
#define BCQ(Q) const float c##Q = swzf<GBC(Q)>(cx), s##Q = swzf<GBC(Q)>(sx);
    BCQ(0) BCQ(1) BCQ(2) BCQ(3) BCQ(4) BCQ(5) BCQ(6) BCQ(7) BCQ(8) BCQ(9)
#undef BCQ

    // ---- sign words ----
    Sgn sg;
    sg.n0 = (g & 8) ? 0 : SGN2;  sg.m0 = sg.n0 ^ ((g & 4) ? SGN2 : 0);
    sg.n1 = (g & 4) ? 0 : SGN2;  sg.m1 = sg.n1 ^ ((((g >> 3) ^ (g >> 1)) & 1) ? SGN2 : 0);
    sg.n2 = (g & 2) ? 0 : SGN2;  sg.m2 = sg.n2 ^ ((((g >> 2) ^ g) & 1) ? SGN2 : 0);
    sg.n3 = (g & 1) ? 0 : SGN2;  sg.m3 = sg.n3 ^ (((g >> 1) & 1) ? SGN2 : 0);
    sg.g4 = (g & 1) ? SGN2 : 0;

    // ---- product state with absorbed initial CZ sign ----
    float F = ((g >> 3) & 1 ? s0 : c0) * ((g >> 2) & 1 ? s1 : c1)
            * ((g >> 1) & 1 ? s2 : c2) * ((g & 1) ? s3 : c3);
    const int lpar = __popc(g & (g >> 1) & 0x7) & 1;     // lane-lane CZ pairs
    F = u2f(f2u(F) ^ (u32(lpar) << 31));
    const float s4m = (g & 1) ? -s4 : s4;                // boundary pair fold
    float uu[8], vv[8];
    {
        const float a0 = F * c4, a1 = F * s4m;
        const float b0 = c5, b1 = s5;
        const float t00 = a0 * b0, t01 = a0 * b1, t10 = a1 * b0, t11 = a1 * b1;
        uu[0] = t00 * c6; uu[1] = t00 * s6; uu[2] = t01 * c6; uu[3] = t01 * s6;
        uu[4] = t10 * c6; uu[5] = t10 * s6; uu[6] = t11 * c6; uu[7] = t11 * s6;
        const float p00 = c7 * c8, p01 = c7 * s8, p10 = s7 * c8, p11 = s7 * s8;
        vv[0] = p00 * c9; vv[1] = p00 * s9; vv[2] = p01 * c9; vv[3] = p01 * s9;
        vv[4] = p10 * c9; vv[5] = p10 * s9; vv[6] = p11 * c9; vv[7] = p11 * s9;
    }
    const int kl = __popc(g) & 3;
    const float pa = (kl == 0) ? 1.f : ((kl == 2) ? -1.f : 0.f);
    const float pb = (kl == 1) ? -1.f : ((kl == 3) ? 1.f : 0.f);
    const float phx[4] = {pa, pb, -pa, -pb};
    const float phy[4] = {pb, -pa, -pb, pa};

    h2 st[64];
#pragma unroll
    for (int r = 0; r < 64; ++r) {
        const float Ar = uu[r >> 3] * vv[r & 7];
        const int j = ((__popc(r) & 3) + 2 * (__popc(r & (r >> 1) & 0x1F) & 1)) & 3;
        st[r] = __builtin_bit_cast(h2, __builtin_amdgcn_cvt_pkrtz(Ar * phx[j], Ar * phy[j]));
    }

    // ---- layers: R1' R2 R3' R4 R5' R6 (MOD at d=0,2,4); gamma at 1,3,5 ----
    ry_layer<true , false>(st, tw,  0,  0, sg);
    ry_layer<false, true >(st, tw, 10, 60, sg);
    ry_layer<true , false>(st, tw, 20,  0, sg);
    ry_layer<false, true >(st, tw, 30, 61, sg);
    ry_layer<true , false>(st, tw, 40,  0, sg);
    ry_layer<false, true >(st, tw, 50, 62, sg);

    // ---- probabilities ----
    float pp[64];
#pragma unroll
    for (int r = 0; r < 64; ++r)
        pp[r] = __builtin_amdgcn_fdot2(st[r], st[r], 0.f, false);

    // in-register tree: f4..f9 (r-bit expvals) + pt
    float a32[32]; float f9 = 0.f;
#pragma unroll
    for (int i = 0; i < 32; ++i) { a32[i] = pp[2*i] + pp[2*i+1]; f9 += pp[2*i] - pp[2*i+1]; }
    float b16[16]; float f8 = 0.f;
#pragma unroll
    for (int i = 0; i < 16; ++i) { b16[i] = a32[2*i] + a32[2*i+1]; f8 += a32[2*i] - a32[2*i+1]; }
    float c8a[8]; float f7 = 0.f;
#pragma unroll
    for (int i = 0; i < 8; ++i) { c8a[i] = b16[2*i] + b16[2*i+1]; f7 += b16[2*i] - b16[2*i+1]; }
    float d4[4]; float f6 = 0.f;
#pragma unroll
    for (int i = 0; i < 4; ++i) { d4[i] = c8a[2*i] + c8a[2*i+1]; f6 += c8a[2*i] - c8a[2*i+1]; }
    const float e20 = d4[0] + d4[1], e21 = d4[2] + d4[3];
    const float f5 = (d4[0] - d4[1]) + (d4[2] - d4[3]);
    const float f4 = e20 - e21;
    const float pt = e20 + e21;

    // group sums for f4..f9: packed pairwise, 4-stage butterflies
    h2 p45 = __builtin_bit_cast(h2, __builtin_amdgcn_cvt_pkrtz(f4, f5));
    h2 p67 = __builtin_bit_cast(h2, __builtin_amdgcn_cvt_pkrtz(f6, f7));
    h2 p89 = __builtin_bit_cast(h2, __builtin_amdgcn_cvt_pkrtz(f8, f9));
    p45 += swzh<SW1>(p45);  p67 += swzh<SW1>(p67);  p89 += swzh<SW1>(p89);
    p45 += swzh<SW2>(p45);  p67 += swzh<SW2>(p67);  p89 += swzh<SW2>(p89);
    p45 += swzh<SW4>(p45);  p67 += swzh<SW4>(p67);  p89 += swzh<SW4>(p89);
    p45 += swzh<SW8>(p45);  p67 += swzh<SW8>(p67);  p89 += swzh<SW8>(p89);
    const float g4v = (float)p45[0], g5v = (float)p45[1];
    const float g6v = (float)p67[0], g7v = (float)p67[1];
    const float g8v = (float)p89[0], g9v = (float)p89[1];

    // 4-stage WHT on pt within group: group-lane s = sum_l (-1)^{popc(l&s)} pt_l
    float v = pt;
    {
        float p;
        p = swzf<SW1>(v);  v = p + u2f(f2u(v) ^ ((g & 1) ? SGN : 0u));
        p = swzf<SW2>(v);  v = p + u2f(f2u(v) ^ ((g & 2) ? SGN : 0u));
        p = swzf<SW4>(v);  v = p + u2f(f2u(v) ^ ((g & 4) ? SGN : 0u));
        p = swzf<SW8>(v);  v = p + u2f(f2u(v) ^ ((g & 8) ? SGN : 0u));
    }
    const float e0 = swzf<GBC(8)>(v);   // wire0 <- group lane 8
    const float e1 = swzf<GBC(4)>(v);   // wire1
    const float e2 = swzf<GBC(2)>(v);   // wire2
    const float e3 = swzf<GBC(1)>(v);   // wire3

    // ---- linear head: every lane writes class g of its element ----
    {
        const float* wr = w_cls + g * NQ;
        float dot = e0 * wr[0];
        dot = fmaf(e1,  wr[1], dot);
        dot = fmaf(e2,  wr[2], dot);
        dot = fmaf(e3,  wr[3], dot);
        dot = fmaf(g4v, wr[4], dot);
        dot = fmaf(g5v, wr[5], dot);
        dot = fmaf(g6v, wr[6], dot);
        dot = fmaf(g7v, wr[7], dot);
        dot = fmaf(g8v, wr[8], dot);
        dot = fmaf(g9v, wr[9], dot);
        out[b * NCLS + g] = dot + b_cls[g];
    }
}

extern "C" void kernel_launch(void* const* d_in, const int* in_sizes, int n_in,
                              void* d_out, int out_size, void* d_ws, size_t ws_size,
                              hipStream_t stream) {
    const float* x      = (const float*)d_in[0];
    const float* params = (const float*)d_in[1];
    const float* w_cls  = (const float*)d_in[2];
    const float* b_cls  = (const float*)d_in[3];
    float* out = (float*)d_out;
    u32*   ws  = (u32*)d_ws;

    const int batch = in_sizes[0] / NQ;            // 65536
    const int WAVES_PER_BLOCK = 4;                 // 256 threads
    const int ELEMS_PER_BLOCK = WAVES_PER_BLOCK * 4;

    hipLaunchKernelGGL(qnn_prep, dim3(1), dim3(64), 0, stream, params, ws);

    dim3 block(64 * WAVES_PER_BLOCK);
    dim3 grid(batch / ELEMS_PER_BLOCK);            // 65536/16 = 4096
    hipLaunchKernelGGL(qnn_kernel, grid, block, 0, stream,
                       x, (const u32*)ws, w_cls, b_cls, out, batch);
}

// Round 16
// 160.040 us; speedup vs baseline: 2.2933x; 1.0063x over previous
//
#include <hip/hip_runtime.h>
#include <math.h>

// Batched 10-qubit statevector sim — FOUR batch elements per wave.
// Each 16-lane group owns one element: amp a = (lane&15)<<6 | r, r in [0,64).
// State = 64 packed-f16 (re,im) regs per lane. Wire w acts on amp bit 9-w:
//   wires 0-3: cross within 16-group, masks 8/4/2/1 via ds_swizzle (DS pipe)
//   wires 4-9: in-register local shear on r bits 5..0 (v_pk_fma_f16)
// Round-16: STREAMING EPILOGUE. R15 counters: occupancy 41% (peak regs
// ~128+: pp[64] materialized while st[64] fully live), VALUBusy 78% (DS
// latency unhidden at 3.2 waves/SIMD). Fix: fold probs into 7 running
// accumulators in 8-reg blocks — st[r] dies at its fdot2; peak ~80 regs.
// Gate loop identical to R15:
//   CZ absorbed (R7) with bit split: lane-lane pairs mask 0x7, boundary
//   (lane b0 x r b5) via s4-fold + runtime half-flip, r-r phase mask 0x1F.
//   MOD wire signs: w0<-lane b2; w1<-b3^b1; w2<-b2^b0; w3<-b1 (+r b5 flip);
//   w4<-lane b0 + r b4 (NB 0x10); w5..w9 <- NB 0x28,0x14,0x0A,0x05,0x02.
// gamma-scale every other layer (f16 range); tan-shear + prep table (R9+).

typedef unsigned int u32;
typedef _Float16 h2 __attribute__((ext_vector_type(2)));

constexpr int NQ = 10;
constexpr int NCLS = 16;
constexpr u32 SGN  = 0x80000000u;
constexpr u32 SGN2 = 0x80008000u;

__device__ __forceinline__ float i2f(int i) { return __builtin_bit_cast(float, i); }
__device__ __forceinline__ int   f2i(float f) { return __builtin_bit_cast(int, f); }
__device__ __forceinline__ u32   f2u(float f) { return __builtin_bit_cast(u32, f); }
__device__ __forceinline__ float u2f(u32 u)   { return __builtin_bit_cast(float, u); }
__device__ __forceinline__ u32   h2u(h2 v)    { return __builtin_bit_cast(u32, v); }
__device__ __forceinline__ h2    u2h(u32 u)   { return __builtin_bit_cast(h2, u); }

__device__ __forceinline__ h2 fma2(h2 a, h2 b, h2 c) {
    return __builtin_elementwise_fma(a, b, c);          // v_pk_fma_f16
}

template<int SWZ>
__device__ __forceinline__ h2 swzh(h2 v) {
    return u2h((u32)__builtin_amdgcn_ds_swizzle(__builtin_bit_cast(int, v), SWZ));
}
template<int SWZ>
__device__ __forceinline__ float swzf(float v) {
    return i2f(__builtin_amdgcn_ds_swizzle(f2i(v), SWZ));
}

constexpr int SW1 = 0x041F;   // lane^1 (within 16-group)
constexpr int SW2 = 0x081F;   // lane^2
constexpr int SW4 = 0x101F;   // lane^4
constexpr int SW8 = 0x201F;   // lane^8
#define GBC(q) (0x10 | ((q) << 5))   // 16-group broadcast of group-lane q

// ---- cross shear: st[r] += ts * partner(st[r]) over all 64 regs ----
template<int SWZ>
__device__ __forceinline__ void cross_ry(h2 (&st)[64], h2 ts) {
#pragma unroll
    for (int r = 0; r < 64; ++r) st[r] = fma2(ts, swzh<SWZ>(st[r]), st[r]);
}

// ---- local shear on r-bit B; NB = compile-time neighbor-sign mask ----
template<int B, int NB>
__device__ __forceinline__ void local_ry(h2 (&st)[64], h2 t) {
#pragma unroll
    for (int r0 = 0; r0 < 64; ++r0) {
        if ((r0 & (1 << B)) == 0) {
            const int r1 = r0 | (1 << B);
            const h2 a0 = st[r0], a1 = st[r1];
            if ((__builtin_popcount(r0 & NB) & 1) == 0) {
                st[r0] = fma2(t, -a1, a0);
                st[r1] = fma2(t,  a0, a1);
            } else {
                st[r0] = fma2(t,  a1, a0);
                st[r1] = fma2(t, -a0, a1);
            }
        }
    }
}

// per-lane sign words: nX plain, mX CZ-conjugated; g4 = wire4 MOD lane word
struct Sgn { u32 n0, m0, n1, m1, n2, m2, n3, m3, g4; };

template<bool MOD, bool GS>
__device__ __forceinline__ void ry_layer(h2 (&st)[64], const u32* __restrict__ tw,
                                         int base, int gi, const Sgn& sg) {
    { const h2 ts = u2h(tw[base + 0] ^ (MOD ? sg.m0 : sg.n0)); cross_ry<SW8>(st, ts); }
    { const h2 ts = u2h(tw[base + 1] ^ (MOD ? sg.m1 : sg.n1)); cross_ry<SW4>(st, ts); }
    { const h2 ts = u2h(tw[base + 2] ^ (MOD ? sg.m2 : sg.n2)); cross_ry<SW2>(st, ts); }
    {   // wire 3 (mask 1); MOD: extra flip on r bit5 half
        const h2 ts = u2h(tw[base + 3] ^ (MOD ? sg.m3 : sg.n3));
        if constexpr (MOD) {
            const h2 th = u2h(h2u(ts) ^ SGN2);
#pragma unroll
            for (int r = 0; r < 32; ++r)  st[r] = fma2(ts, swzh<SW1>(st[r]), st[r]);
#pragma unroll
            for (int r = 32; r < 64; ++r) st[r] = fma2(th, swzh<SW1>(st[r]), st[r]);
        } else {
            cross_ry<SW1>(st, ts);
        }
    }
    { const h2 t = u2h(tw[base + 4] ^ (MOD ? sg.g4 : 0u));
      local_ry<5, MOD ? 0x10 : 0>(st, t); }                    // wire 4
    local_ry<4, MOD ? 0x28 : 0>(st, u2h(tw[base + 5]));        // wire 5
    local_ry<3, MOD ? 0x14 : 0>(st, u2h(tw[base + 6]));        // wire 6
    local_ry<2, MOD ? 0x0A : 0>(st, u2h(tw[base + 7]));        // wire 7
    local_ry<1, MOD ? 0x05 : 0>(st, u2h(tw[base + 8]));        // wire 8
    local_ry<0, MOD ? 0x02 : 0>(st, u2h(tw[base + 9]));        // wire 9
    if constexpr (GS) {
        const h2 g = u2h(tw[gi]);
#pragma unroll
        for (int r = 0; r < 64; ++r) st[r] = g * st[r];        // v_pk_mul_f16
    }
}

// ---- prep: packed-h2 tan table [0..59] + 2-layer gamma [60..62] ----
__global__ void __launch_bounds__(64) qnn_prep(const float* __restrict__ params,
                                               u32* __restrict__ ws) {
    const int l = threadIdx.x;
    if (l < 60) {
        float s, c;
        __sincosf(params[l] * 0.5f, &s, &c);
        const float t = s / c;
        const h2 t2 = { (_Float16)t, (_Float16)t };
        ws[l] = h2u(t2);
    }
    if (l < 3) {
        float g = 1.f;
        for (int k = 0; k < 20; ++k) g *= __cosf(params[l * 20 + k] * 0.5f);
        const h2 g2 = { (_Float16)g, (_Float16)g };
        ws[60 + l] = h2u(g2);
    }
}

__global__ void __launch_bounds__(256) qnn_kernel(
    const float* __restrict__ x,       // (B, 10)
    const u32*   __restrict__ tw,      // (63,) packed tan + gamma tables
    const float* __restrict__ w_cls,   // (16, 10)
    const float* __restrict__ b_cls,   // (16,)
    float* __restrict__ out,           // (B, 16)
    int batch)
{
    const int lane = threadIdx.x & 63;
    const int wid  = threadIdx.x >> 6;
    const int wave = blockIdx.x * (blockDim.x >> 6) + wid;
    const int g    = lane & 15;                   // group lane
    const int b    = wave * 4 + (lane >> 4);      // this lane's batch element

    // ---- encoding angles: group lane q (<10) owns wire q of its element ----
    float cx, sx;
    { const int q = (g < NQ) ? g : 0; __sincosf(x[b * NQ + q] * 0.5f, &sx, &cx); }

    // group-local broadcasts of all 10 (c,s) pairs
#define BCQ(Q) const float c##Q = swzf<GBC(Q)>(cx), s##Q = swzf<GBC(Q)>(sx);
    BCQ(0) BCQ(1) BCQ(2) BCQ(3) BCQ(4) BCQ(5) BCQ(6) BCQ(7) BCQ(8) BCQ(9)
#undef BCQ

    // ---- sign words ----
    Sgn sg;
    sg.n0 = (g & 8) ? 0 : SGN2;  sg.m0 = sg.n0 ^ ((g & 4) ? SGN2 : 0);
    sg.n1 = (g & 4) ? 0 : SGN2;  sg.m1 = sg.n1 ^ ((((g >> 3) ^ (g >> 1)) & 1) ? SGN2 : 0);
    sg.n2 = (g & 2) ? 0 : SGN2;  sg.m2 = sg.n2 ^ ((((g >> 2) ^ g) & 1) ? SGN2 : 0);
    sg.n3 = (g & 1) ? 0 : SGN2;  sg.m3 = sg.n3 ^ (((g >> 1) & 1) ? SGN2 : 0);
    sg.g4 = (g & 1) ? SGN2 : 0;

    // ---- product state with absorbed initial CZ sign ----
    float F = ((g >> 3) & 1 ? s0 : c0) * ((g >> 2) & 1 ? s1 : c1)
            * ((g >> 1) & 1 ? s2 : c2) * ((g & 1) ? s3 : c3);
    const int lpar = __popc(g & (g >> 1) & 0x7) & 1;     // lane-lane CZ pairs
    F = u2f(f2u(F) ^ (u32(lpar) << 31));
    const float s4m = (g & 1) ? -s4 : s4;                // boundary pair fold
    float uu[8], vv[8];
    {
        const float a0 = F * c4, a1 = F * s4m;
        const float b0 = c5, b1 = s5;
        const float t00 = a0 * b0, t01 = a0 * b1, t10 = a1 * b0, t11 = a1 * b1;
        uu[0] = t00 * c6; uu[1] = t00 * s6; uu[2] = t01 * c6; uu[3] = t01 * s6;
        uu[4] = t10 * c6; uu[5] = t10 * s6; uu[6] = t11 * c6; uu[7] = t11 * s6;
        const float p00 = c7 * c8, p01 = c7 * s8, p10 = s7 * c8, p11 = s7 * s8;
        vv[0] = p00 * c9; vv[1] = p00 * s9; vv[2] = p01 * c9; vv[3] = p01 * s9;
        vv[4] = p10 * c9; vv[5] = p10 * s9; vv[6] = p11 * c9; vv[7] = p11 * s9;
    }
    const int kl = __popc(g) & 3;
    const float pa = (kl == 0) ? 1.f : ((kl == 2) ? -1.f : 0.f);
    const float pb = (kl == 1) ? -1.f : ((kl == 3) ? 1.f : 0.f);
    const float phx[4] = {pa, pb, -pa, -pb};
    const float phy[4] = {pb, -pa, -pb, pa};

    h2 st[64];
#pragma unroll
    for (int r = 0; r < 64; ++r) {
        const float Ar = uu[r >> 3] * vv[r & 7];
        const int j = ((__popc(r) & 3) + 2 * (__popc(r & (r >> 1) & 0x1F) & 1)) & 3;
        st[r] = __builtin_bit_cast(h2, __builtin_amdgcn_cvt_pkrtz(Ar * phx[j], Ar * phy[j]));
    }

    // ---- layers: R1' R2 R3' R4 R5' R6 (MOD at d=0,2,4); gamma at 1,3,5 ----
    ry_layer<true , false>(st, tw,  0,  0, sg);
    ry_layer<false, true >(st, tw, 10, 60, sg);
    ry_layer<true , false>(st, tw, 20,  0, sg);
    ry_layer<false, true >(st, tw, 30, 61, sg);
    ry_layer<true , false>(st, tw, 40,  0, sg);
    ry_layer<false, true >(st, tw, 50, 62, sg);

    // ---- STREAMING probabilities + tree: st[r] dies at its fdot2 ----
    // r = 8i+j. j bits 2..0 = r bits 2..0 = wires 7,8,9 (f7,f8,f9);
    //          i bits 2..0 = r bits 5..3 = wires 4,5,6 (f4,f5,f6).
    float f4 = 0.f, f5 = 0.f, f6 = 0.f, f7 = 0.f, f8 = 0.f, f9 = 0.f, pt = 0.f;
#pragma unroll
    for (int i = 0; i < 8; ++i) {
        float p[8];
#pragma unroll
        for (int j = 0; j < 8; ++j)
            p[j] = __builtin_amdgcn_fdot2(st[8*i + j], st[8*i + j], 0.f, false);
        const float a0 = p[0] + p[1], a1 = p[2] + p[3];
        const float a2 = p[4] + p[5], a3 = p[6] + p[7];
        f9 += (p[0] - p[1]) + (p[2] - p[3]) + (p[4] - p[5]) + (p[6] - p[7]);
        const float b0 = a0 + a1, b1 = a2 + a3;
        f8 += (a0 - a1) + (a2 - a3);
        const float c = b0 + b1;
        f7 += b0 - b1;
        f6 += (i & 1) ? -c : c;
        f5 += (i & 2) ? -c : c;
        f4 += (i & 4) ? -c : c;
        pt += c;
    }

    // group sums for f4..f9: packed pairwise, 4-stage butterflies
    h2 p45 = __builtin_bit_cast(h2, __builtin_amdgcn_cvt_pkrtz(f4, f5));
    h2 p67 = __builtin_bit_cast(h2, __builtin_amdgcn_cvt_pkrtz(f6, f7));
    h2 p89 = __builtin_bit_cast(h2, __builtin_amdgcn_cvt_pkrtz(f8, f9));
    p45 += swzh<SW1>(p45);  p67 += swzh<SW1>(p67);  p89 += swzh<SW1>(p89);
    p45 += swzh<SW2>(p45);  p67 += swzh<SW2>(p67);  p89 += swzh<SW2>(p89);
    p45 += swzh<SW4>(p45);  p67 += swzh<SW4>(p67);  p89 += swzh<SW4>(p89);
    p45 += swzh<SW8>(p45);  p67 += swzh<SW8>(p67);  p89 += swzh<SW8>(p89);
    const float g4v = (float)p45[0], g5v = (float)p45[1];
    const float g6v = (float)p67[0], g7v = (float)p67[1];
    const float g8v = (float)p89[0], g9v = (float)p89[1];

    // 4-stage WHT on pt within group: group-lane s = sum_l (-1)^{popc(l&s)} pt_l
    float v = pt;
    {
        float p;
        p = swzf<SW1>(v);  v = p + u2f(f2u(v) ^ ((g & 1) ? SGN : 0u));
        p = swzf<SW2>(v);  v = p + u2f(f2u(v) ^ ((g & 2) ? SGN : 0u));
        p = swzf<SW4>(v);  v = p + u2f(f2u(v) ^ ((g & 4) ? SGN : 0u));
        p = swzf<SW8>(v);  v = p + u2f(f2u(v) ^ ((g & 8) ? SGN : 0u));
    }
    const float e0 = swzf<GBC(8)>(v);   // wire0 <- group lane 8
    const float e1 = swzf<GBC(4)>(v);   // wire1
    const float e2 = swzf<GBC(2)>(v);   // wire2
    const float e3 = swzf<GBC(1)>(v);   // wire3

    // ---- linear head: every lane writes class g of its element ----
    {
        const float* wr = w_cls + g * NQ;
        float dot = e0 * wr[0];
        dot = fmaf(e1,  wr[1], dot);
        dot = fmaf(e2,  wr[2], dot);
        dot = fmaf(e3,  wr[3], dot);
        dot = fmaf(g4v, wr[4], dot);
        dot = fmaf(g5v, wr[5], dot);
        dot = fmaf(g6v, wr[6], dot);
        dot = fmaf(g7v, wr[7], dot);
        dot = fmaf(g8v, wr[8], dot);
        dot = fmaf(g9v, wr[9], dot);
        out[b * NCLS + g] = dot + b_cls[g];
    }
}

extern "C" void kernel_launch(void* const* d_in, const int* in_sizes, int n_in,
                              void* d_out, int out_size, void* d_ws, size_t ws_size,
                              hipStream_t stream) {
    const float* x      = (const float*)d_in[0];
    const float* params = (const float*)d_in[1];
    const float* w_cls  = (const float*)d_in[2];
    const float* b_cls  = (const float*)d_in[3];
    float* out = (float*)d_out;
    u32*   ws  = (u32*)d_ws;

    const int batch = in_sizes[0] / NQ;            // 65536
    const int WAVES_PER_BLOCK = 4;                 // 256 threads
    const int ELEMS_PER_BLOCK = WAVES_PER_BLOCK * 4;

    hipLaunchKernelGGL(qnn_prep, dim3(1), dim3(64), 0, stream, params, ws);

    dim3 block(64 * WAVES_PER_BLOCK);
    dim3 grid(batch / ELEMS_PER_BLOCK);            // 65536/16 = 4096
    hipLaunchKernelGGL(qnn_kernel, grid, block, 0, stream,
                       x, (const u32*)ws, w_cls, b_cls, out, batch);
}

// Round 18
// 142.048 us; speedup vs baseline: 2.5838x; 1.1267x over previous
//
#include <hip/hip_runtime.h>
#include <math.h>

// Batched 10-qubit statevector sim — FOUR batch elements per wave.
// Each 16-lane group owns one element: amp a = (lane&15)<<6 | r, r in [0,64).
// State = 64 packed-f16 (re,im) regs per lane. Wire w acts on amp bit 9-w:
//   wires 0-3: cross within 16-group, masks 8/4/2/1 via ds_swizzle (DS pipe)
//   wires 4-9: in-register local shear (v_pk_fma_f16)
// Round-18 = Round-17 + overflow fix. R17's inf: deferring gamma_B to the
// OUTPUT left the epilogue prob-sums at ~1/gB^2 (1e3-1e4); the packed-f16
// group butterflies (x16 over 4 stages) overflowed f16 -> inf. Fix: scale
// the seven f32 accumulators (pt, f4..f9) by gB^2 BEFORE any f16 packing
// (7 f32 muls); head no longer applies gB^2. Gate path unchanged (amps
// <= 1/gB ~ hundreds, f16-safe).
// R17 structure: layer-0 folded into init via complex product state
// X = C R0 |enc>, per-wire 2-vector [ct*c + i st*s, st*c - i ct*s];
// layers base10(plain) 20(MOD) 30(plain) 40(MOD) 50(plain); gamma_A (rows
// 1-2) in-state after base20; gamma_B (rows 3-5) via accumulator scale.
// CZ absorbed (R7): lane-lane pairs mask 0x7 -> F sign; boundary (lane b0
// x r b5) -> negate beta4 on odd lanes; r-r pairs mask 0x1F -> sign at init.

typedef unsigned int u32;
typedef _Float16 h2 __attribute__((ext_vector_type(2)));

constexpr int NQ = 10;
constexpr int NCLS = 16;
constexpr u32 SGN  = 0x80000000u;
constexpr u32 SGN2 = 0x80008000u;

__device__ __forceinline__ float i2f(int i) { return __builtin_bit_cast(float, i); }
__device__ __forceinline__ int   f2i(float f) { return __builtin_bit_cast(int, f); }
__device__ __forceinline__ u32   f2u(float f) { return __builtin_bit_cast(u32, f); }
__device__ __forceinline__ float u2f(u32 u)   { return __builtin_bit_cast(float, u); }
__device__ __forceinline__ u32   h2u(h2 v)    { return __builtin_bit_cast(u32, v); }
__device__ __forceinline__ h2    u2h(u32 u)   { return __builtin_bit_cast(h2, u); }

__device__ __forceinline__ h2 fma2(h2 a, h2 b, h2 c) {
    return __builtin_elementwise_fma(a, b, c);          // v_pk_fma_f16
}

template<int SWZ>
__device__ __forceinline__ h2 swzh(h2 v) {
    return u2h((u32)__builtin_amdgcn_ds_swizzle(__builtin_bit_cast(int, v), SWZ));
}
template<int SWZ>
__device__ __forceinline__ float swzf(float v) {
    return i2f(__builtin_amdgcn_ds_swizzle(f2i(v), SWZ));
}

constexpr int SW1 = 0x041F;   // lane^1 (within 16-group)
constexpr int SW2 = 0x081F;   // lane^2
constexpr int SW4 = 0x101F;   // lane^4
constexpr int SW8 = 0x201F;   // lane^8
#define GBC(q) (0x10 | ((q) << 5))   // 16-group broadcast of group-lane q

// ---- complex f32 helpers ----
struct c32 { float re, im; };
__device__ __forceinline__ c32 cmul(c32 a, c32 b) {
    return { fmaf(a.re, b.re, -(a.im * b.im)),
             fmaf(a.re, b.im,  a.im * b.re) };
}

// ---- cross shear: st[r] += ts * partner(st[r]) over all 64 regs ----
template<int SWZ>
__device__ __forceinline__ void cross_ry(h2 (&st)[64], h2 ts) {
#pragma unroll
    for (int r = 0; r < 64; ++r) st[r] = fma2(ts, swzh<SWZ>(st[r]), st[r]);
}

// ---- local shear on r-bit B; NB = compile-time neighbor-sign mask ----
template<int B, int NB>
__device__ __forceinline__ void local_ry(h2 (&st)[64], h2 t) {
#pragma unroll
    for (int r0 = 0; r0 < 64; ++r0) {
        if ((r0 & (1 << B)) == 0) {
            const int r1 = r0 | (1 << B);
            const h2 a0 = st[r0], a1 = st[r1];
            if ((__builtin_popcount(r0 & NB) & 1) == 0) {
                st[r0] = fma2(t, -a1, a0);
                st[r1] = fma2(t,  a0, a1);
            } else {
                st[r0] = fma2(t,  a1, a0);
                st[r1] = fma2(t, -a0, a1);
            }
        }
    }
}

// per-lane sign words: nX plain, mX CZ-conjugated; g4 = wire4 MOD lane word
struct Sgn { u32 n0, m0, n1, m1, n2, m2, n3, m3, g4; };

template<bool MOD, bool GS>
__device__ __forceinline__ void ry_layer(h2 (&st)[64], const u32* __restrict__ tw,
                                         int base, int gi, const Sgn& sg) {
    { const h2 ts = u2h(tw[base + 0] ^ (MOD ? sg.m0 : sg.n0)); cross_ry<SW8>(st, ts); }
    { const h2 ts = u2h(tw[base + 1] ^ (MOD ? sg.m1 : sg.n1)); cross_ry<SW4>(st, ts); }
    { const h2 ts = u2h(tw[base + 2] ^ (MOD ? sg.m2 : sg.n2)); cross_ry<SW2>(st, ts); }
    {   // wire 3 (mask 1); MOD: extra flip on r bit5 half
        const h2 ts = u2h(tw[base + 3] ^ (MOD ? sg.m3 : sg.n3));
        if constexpr (MOD) {
            const h2 th = u2h(h2u(ts) ^ SGN2);
#pragma unroll
            for (int r = 0; r < 32; ++r)  st[r] = fma2(ts, swzh<SW1>(st[r]), st[r]);
#pragma unroll
            for (int r = 32; r < 64; ++r) st[r] = fma2(th, swzh<SW1>(st[r]), st[r]);
        } else {
            cross_ry<SW1>(st, ts);
        }
    }
    { const h2 t = u2h(tw[base + 4] ^ (MOD ? sg.g4 : 0u));
      local_ry<5, MOD ? 0x10 : 0>(st, t); }                    // wire 4
    local_ry<4, MOD ? 0x28 : 0>(st, u2h(tw[base + 5]));        // wire 5
    local_ry<3, MOD ? 0x14 : 0>(st, u2h(tw[base + 6]));        // wire 6
    local_ry<2, MOD ? 0x0A : 0>(st, u2h(tw[base + 7]));        // wire 7
    local_ry<1, MOD ? 0x05 : 0>(st, u2h(tw[base + 8]));        // wire 8
    local_ry<0, MOD ? 0x02 : 0>(st, u2h(tw[base + 9]));        // wire 9
    if constexpr (GS) {
        const h2 g = u2h(tw[gi]);
#pragma unroll
        for (int r = 0; r < 64; ++r) st[r] = g * st[r];        // v_pk_mul_f16
    }
}

// ---- prep: tan table [10..59], gamma_A h2 [60], gamma_B^2 f32 [61],
//            layer-0 (cos,sin) f32 pairs [64..83] ----
__global__ void __launch_bounds__(64) qnn_prep(const float* __restrict__ params,
                                               u32* __restrict__ ws) {
    const int l = threadIdx.x;
    if (l < 60) {
        float s, c;
        __sincosf(params[l] * 0.5f, &s, &c);
        const float t = s / c;
        const h2 t2 = { (_Float16)t, (_Float16)t };
        ws[l] = h2u(t2);
    }
    if (l < 10) {
        float s, c;
        __sincosf(params[l] * 0.5f, &s, &c);
        ws[64 + 2*l]     = f2u(c);
        ws[64 + 2*l + 1] = f2u(s);
    }
    if (l == 0) {
        float gA = 1.f;
        for (int k = 10; k < 30; ++k) gA *= __cosf(params[k] * 0.5f);
        const h2 g2 = { (_Float16)gA, (_Float16)gA };
        ws[60] = h2u(g2);
        float gB = 1.f;
        for (int k = 30; k < 60; ++k) gB *= __cosf(params[k] * 0.5f);
        ws[61] = f2u(gB * gB);
    }
}

__global__ void __launch_bounds__(256) qnn_kernel(
    const float* __restrict__ x,       // (B, 10)
    const u32*   __restrict__ tw,      // (84,) tables (see prep)
    const float* __restrict__ w_cls,   // (16, 10)
    const float* __restrict__ b_cls,   // (16,)
    float* __restrict__ out,           // (B, 16)
    int batch)
{
    const int lane = threadIdx.x & 63;
    const int wid  = threadIdx.x >> 6;
    const int wave = blockIdx.x * (blockDim.x >> 6) + wid;
    const int g    = lane & 15;                   // group lane
    const int b    = wave * 4 + (lane >> 4);      // this lane's batch element

    // ---- own wire's complex 2-vector after RY layer 0:
    //      alpha = (ct*c, st*s), beta = (st*c, -ct*s) ----
    float Are, Aim, Bre, Bim;
    {
        const int q = (g < NQ) ? g : 0;
        float cxe, sxe;
        __sincosf(x[b * NQ + q] * 0.5f, &sxe, &cxe);
        const float ct = u2f(tw[64 + 2*q]), st_ = u2f(tw[64 + 2*q + 1]);
        Are = ct * cxe;  Aim = st_ * sxe;
        Bre = st_ * cxe; Bim = -(ct * sxe);
    }

    // group-local broadcasts of all 10 wires' (A,B)
#define BCW(Q) const float Ar##Q = swzf<GBC(Q)>(Are), Ai##Q = swzf<GBC(Q)>(Aim), \
                           Br##Q = swzf<GBC(Q)>(Bre), Bi##Q = swzf<GBC(Q)>(Bim);
    BCW(0) BCW(1) BCW(2) BCW(3) BCW(4) BCW(5) BCW(6) BCW(7) BCW(8) BCW(9)
#undef BCW

    // ---- sign words (unchanged from R15/16) ----
    Sgn sg;
    sg.n0 = (g & 8) ? 0 : SGN2;  sg.m0 = sg.n0 ^ ((g & 4) ? SGN2 : 0);
    sg.n1 = (g & 4) ? 0 : SGN2;  sg.m1 = sg.n1 ^ ((((g >> 3) ^ (g >> 1)) & 1) ? SGN2 : 0);
    sg.n2 = (g & 2) ? 0 : SGN2;  sg.m2 = sg.n2 ^ ((((g >> 2) ^ g) & 1) ? SGN2 : 0);
    sg.n3 = (g & 1) ? 0 : SGN2;  sg.m3 = sg.n3 ^ (((g >> 1) & 1) ? SGN2 : 0);
    sg.g4 = (g & 1) ? SGN2 : 0;

    // ---- X = C * R0 * |enc> built directly (complex tensor product) ----
    const c32 w0 = (g & 8) ? c32{Br0, Bi0} : c32{Ar0, Ai0};
    const c32 w1 = (g & 4) ? c32{Br1, Bi1} : c32{Ar1, Ai1};
    const c32 w2 = (g & 2) ? c32{Br2, Bi2} : c32{Ar2, Ai2};
    const c32 w3 = (g & 1) ? c32{Br3, Bi3} : c32{Ar3, Ai3};
    c32 F = cmul(cmul(w0, w1), cmul(w2, w3));
    const u32 lps = (__popc(g & (g >> 1) & 0x7) & 1) ? SGN : 0;  // lane-lane CZ
    F.re = u2f(f2u(F.re) ^ lps);
    F.im = u2f(f2u(F.im) ^ lps);

    // boundary CZ pair (wire3 = g.b0, wire4 = r.b5): negate beta4 on odd lanes
    const u32 bs = (g & 1) ? SGN : 0;
    const c32 a4 = {Ar4, Ai4};
    const c32 b4 = {u2f(f2u(Br4) ^ bs), u2f(f2u(Bi4) ^ bs)};

    // uu[k], k = r>>3 bits (r.b5, r.b4, r.b3) = wires 4,5,6
    c32 uu[8];
    {
        const c32 u0 = cmul(F, a4), u1 = cmul(F, b4);
        const c32 a5 = {Ar5, Ai5}, b5 = {Br5, Bi5};
        const c32 t00 = cmul(u0, a5), t01 = cmul(u0, b5);
        const c32 t10 = cmul(u1, a5), t11 = cmul(u1, b5);
        const c32 a6 = {Ar6, Ai6}, b6 = {Br6, Bi6};
        uu[0] = cmul(t00, a6); uu[1] = cmul(t00, b6);
        uu[2] = cmul(t01, a6); uu[3] = cmul(t01, b6);
        uu[4] = cmul(t10, a6); uu[5] = cmul(t10, b6);
        uu[6] = cmul(t11, a6); uu[7] = cmul(t11, b6);
    }
    // vv[j], j = r&7 bits (r.b2, r.b1, r.b0) = wires 7,8,9
    c32 vv[8];
    {
        const c32 a7 = {Ar7, Ai7}, b7 = {Br7, Bi7};
        const c32 a8 = {Ar8, Ai8}, b8 = {Br8, Bi8};
        const c32 q00 = cmul(a7, a8), q01 = cmul(a7, b8);
        const c32 q10 = cmul(b7, a8), q11 = cmul(b7, b8);
        const c32 a9 = {Ar9, Ai9}, b9 = {Br9, Bi9};
        vv[0] = cmul(q00, a9); vv[1] = cmul(q00, b9);
        vv[2] = cmul(q01, a9); vv[3] = cmul(q01, b9);
        vv[4] = cmul(q10, a9); vv[5] = cmul(q10, b9);
        vv[6] = cmul(q11, a9); vv[7] = cmul(q11, b9);
    }

    h2 st[64];
#pragma unroll
    for (int r = 0; r < 64; ++r) {
        const c32 m = cmul(uu[r >> 3], vv[r & 7]);
        if (__popc(r & (r >> 1) & 0x1F) & 1)   // r-r CZ pairs: compile-time sign
            st[r] = __builtin_bit_cast(h2, __builtin_amdgcn_cvt_pkrtz(-m.re, -m.im));
        else
            st[r] = __builtin_bit_cast(h2, __builtin_amdgcn_cvt_pkrtz(m.re, m.im));
    }

    // ---- layers: R1 R2' R3 R4' R5 (rows 1..5; MOD at 2',4'); gamma_A after 2' ----
    ry_layer<false, false>(st, tw, 10,  0, sg);
    ry_layer<true , true >(st, tw, 20, 60, sg);
    ry_layer<false, false>(st, tw, 30,  0, sg);
    ry_layer<true , false>(st, tw, 40,  0, sg);
    ry_layer<false, false>(st, tw, 50,  0, sg);

    // ---- STREAMING probabilities + tree: st[r] dies at its fdot2 ----
    float f4 = 0.f, f5 = 0.f, f6 = 0.f, f7 = 0.f, f8 = 0.f, f9 = 0.f, pt = 0.f;
#pragma unroll
    for (int i = 0; i < 8; ++i) {
        float p[8];
#pragma unroll
        for (int j = 0; j < 8; ++j)
            p[j] = __builtin_amdgcn_fdot2(st[8*i + j], st[8*i + j], 0.f, false);
        const float a0 = p[0] + p[1], a1 = p[2] + p[3];
        const float a2 = p[4] + p[5], a3 = p[6] + p[7];
        f9 += (p[0] - p[1]) + (p[2] - p[3]) + (p[4] - p[5]) + (p[6] - p[7]);
        const float b0 = a0 + a1, b1 = a2 + a3;
        f8 += (a0 - a1) + (a2 - a3);
        const float c = b0 + b1;
        f7 += b0 - b1;
        f6 += (i & 1) ? -c : c;
        f5 += (i & 2) ? -c : c;
        f4 += (i & 4) ? -c : c;
        pt += c;
    }

    // ---- normalize NOW (f32) so the f16 packed butterflies can't overflow:
    //      deferred gamma_B^2 applied to the 7 accumulators (R17 inf fix) ----
    {
        const float gB2 = u2f(tw[61]);
        f4 *= gB2; f5 *= gB2; f6 *= gB2; f7 *= gB2;
        f8 *= gB2; f9 *= gB2; pt *= gB2;
    }

    // group sums for f4..f9: packed pairwise, 4-stage butterflies
    h2 p45 = __builtin_bit_cast(h2, __builtin_amdgcn_cvt_pkrtz(f4, f5));
    h2 p67 = __builtin_bit_cast(h2, __builtin_amdgcn_cvt_pkrtz(f6, f7));
    h2 p89 = __builtin_bit_cast(h2, __builtin_amdgcn_cvt_pkrtz(f8, f9));
    p45 += swzh<SW1>(p45);  p67 += swzh<SW1>(p67);  p89 += swzh<SW1>(p89);
    p45 += swzh<SW2>(p45);  p67 += swzh<SW2>(p67);  p89 += swzh<SW2>(p89);
    p45 += swzh<SW4>(p45);  p67 += swzh<SW4>(p67);  p89 += swzh<SW4>(p89);
    p45 += swzh<SW8>(p45);  p67 += swzh<SW8>(p67);  p89 += swzh<SW8>(p89);
    const float g4v = (float)p45[0], g5v = (float)p45[1];
    const float g6v = (float)p67[0], g7v = (float)p67[1];
    const float g8v = (float)p89[0], g9v = (float)p89[1];

    // 4-stage WHT on pt within group (f32)
    float v = pt;
    {
        float p;
        p = swzf<SW1>(v);  v = p + u2f(f2u(v) ^ ((g & 1) ? SGN : 0u));
        p = swzf<SW2>(v);  v = p + u2f(f2u(v) ^ ((g & 2) ? SGN : 0u));
        p = swzf<SW4>(v);  v = p + u2f(f2u(v) ^ ((g & 4) ? SGN : 0u));
        p = swzf<SW8>(v);  v = p + u2f(f2u(v) ^ ((g & 8) ? SGN : 0u));
    }
    const float e0 = swzf<GBC(8)>(v);   // wire0 <- group lane 8
    const float e1 = swzf<GBC(4)>(v);   // wire1
    const float e2 = swzf<GBC(2)>(v);   // wire2
    const float e3 = swzf<GBC(1)>(v);   // wire3

    // ---- linear head (accumulators already normalized) ----
    {
        const float* wr = w_cls + g * NQ;
        float dot = e0 * wr[0];
        dot = fmaf(e1,  wr[1], dot);
        dot = fmaf(e2,  wr[2], dot);
        dot = fmaf(e3,  wr[3], dot);
        dot = fmaf(g4v, wr[4], dot);
        dot = fmaf(g5v, wr[5], dot);
        dot = fmaf(g6v, wr[6], dot);
        dot = fmaf(g7v, wr[7], dot);
        dot = fmaf(g8v, wr[8], dot);
        dot = fmaf(g9v, wr[9], dot);
        out[b * NCLS + g] = dot + b_cls[g];
    }
}

extern "C" void kernel_launch(void* const* d_in, const int* in_sizes, int n_in,
                              void* d_out, int out_size, void* d_ws, size_t ws_size,
                              hipStream_t stream) {
    const float* x      = (const float*)d_in[0];
    const float* params = (const float*)d_in[1];
    const float* w_cls  = (const float*)d_in[2];
    const float* b_cls  = (const float*)d_in[3];
    float* out = (float*)d_out;
    u32*   ws  = (u32*)d_ws;

    const int batch = in_sizes[0] / NQ;            // 65536
    const int WAVES_PER_BLOCK = 4;                 // 256 threads
    const int ELEMS_PER_BLOCK = WAVES_PER_BLOCK * 4;

    hipLaunchKernelGGL(qnn_prep, dim3(1), dim3(64), 0, stream, params, ws);

    dim3 block(64 * WAVES_PER_BLOCK);
    dim3 grid(batch / ELEMS_PER_BLOCK);            // 65536/16 = 4096
    hipLaunchKernelGGL(qnn_kernel, grid, block, 0, stream,
                       x, (const u32*)ws, w_cls, b_cls, out, batch);
}

// Round 19
// 136.648 us; speedup vs baseline: 2.6859x; 1.0395x over previous
//
#include <hip/hip_runtime.h>
#include <math.h>

// Batched 10-qubit statevector sim — FOUR batch elements per wave.
// Each 16-lane group owns one element: amp a = (lane&15)<<6 | r, r in [0,64).
// State = 64 packed-f16 (re,im) regs per lane. Wire w acts on amp bit 9-w:
//   wires 0-3: cross within 16-group, masks 8/4/2/1 via ds_swizzle (DS pipe)
//   wires 4-9: in-register local shear (v_pk_fma_f16)
// Round-19: WIRE INTERLEAVE. R18 counters: VALU makespan 108us == DS 107us
// (balanced), but dur=142 — pipes ping-pong because each layer is 4 DS wires
// then 6 VALU wires. Single-qubit RY gates on distinct wires COMMUTE, so
// reorder within each layer: w0,w4,w1,w5,w2,w6,w3,w7,w8,w9 — alternating
// DS-heavy and VALU-only blocks so one wave feeds both pipes concurrently.
// Everything else identical to R18 (142us, absmax 0.0039):
//  - layer-0 folded into init (complex product state X = C R0 |enc>)
//  - layers base10(plain) 20(MOD) 30(plain) 40(MOD) 50(plain)
//  - gamma_A (rows 1-2) in-state after base20; gamma_B^2 (rows 3-5) applied
//    to the 7 f32 accumulators BEFORE f16 packing (R18 overflow fix)
//  - CZ absorbed: lane-lane mask 0x7 -> F sign; boundary -> beta4 flip on
//    odd lanes; r-r mask 0x1F -> sign at init; MOD wire signs per R15.

typedef unsigned int u32;
typedef _Float16 h2 __attribute__((ext_vector_type(2)));

constexpr int NQ = 10;
constexpr int NCLS = 16;
constexpr u32 SGN  = 0x80000000u;
constexpr u32 SGN2 = 0x80008000u;

__device__ __forceinline__ float i2f(int i) { return __builtin_bit_cast(float, i); }
__device__ __forceinline__ int   f2i(float f) { return __builtin_bit_cast(int, f); }
__device__ __forceinline__ u32   f2u(float f) { return __builtin_bit_cast(u32, f); }
__device__ __forceinline__ float u2f(u32 u)   { return __builtin_bit_cast(float, u); }
__device__ __forceinline__ u32   h2u(h2 v)    { return __builtin_bit_cast(u32, v); }
__device__ __forceinline__ h2    u2h(u32 u)   { return __builtin_bit_cast(h2, u); }

__device__ __forceinline__ h2 fma2(h2 a, h2 b, h2 c) {
    return __builtin_elementwise_fma(a, b, c);          // v_pk_fma_f16
}

template<int SWZ>
__device__ __forceinline__ h2 swzh(h2 v) {
    return u2h((u32)__builtin_amdgcn_ds_swizzle(__builtin_bit_cast(int, v), SWZ));
}
template<int SWZ>
__device__ __forceinline__ float swzf(float v) {
    return i2f(__builtin_amdgcn_ds_swizzle(f2i(v), SWZ));
}

constexpr int SW1 = 0x041F;   // lane^1 (within 16-group)
constexpr int SW2 = 0x081F;   // lane^2
constexpr int SW4 = 0x101F;   // lane^4
constexpr int SW8 = 0x201F;   // lane^8
#define GBC(q) (0x10 | ((q) << 5))   // 16-group broadcast of group-lane q

// ---- complex f32 helpers ----
struct c32 { float re, im; };
__device__ __forceinline__ c32 cmul(c32 a, c32 b) {
    return { fmaf(a.re, b.re, -(a.im * b.im)),
             fmaf(a.re, b.im,  a.im * b.re) };
}

// ---- cross shear: st[r] += ts * partner(st[r]) over all 64 regs ----
template<int SWZ>
__device__ __forceinline__ void cross_ry(h2 (&st)[64], h2 ts) {
#pragma unroll
    for (int r = 0; r < 64; ++r) st[r] = fma2(ts, swzh<SWZ>(st[r]), st[r]);
}

// ---- local shear on r-bit B; NB = compile-time neighbor-sign mask ----
template<int B, int NB>
__device__ __forceinline__ void local_ry(h2 (&st)[64], h2 t) {
#pragma unroll
    for (int r0 = 0; r0 < 64; ++r0) {
        if ((r0 & (1 << B)) == 0) {
            const int r1 = r0 | (1 << B);
            const h2 a0 = st[r0], a1 = st[r1];
            if ((__builtin_popcount(r0 & NB) & 1) == 0) {
                st[r0] = fma2(t, -a1, a0);
                st[r1] = fma2(t,  a0, a1);
            } else {
                st[r0] = fma2(t,  a1, a0);
                st[r1] = fma2(t, -a0, a1);
            }
        }
    }
}

// per-lane sign words: nX plain, mX CZ-conjugated; g4 = wire4 MOD lane word
struct Sgn { u32 n0, m0, n1, m1, n2, m2, n3, m3, g4; };

// One RY layer, wires INTERLEAVED (cross/local alternating — all commute).
template<bool MOD, bool GS>
__device__ __forceinline__ void ry_layer(h2 (&st)[64], const u32* __restrict__ tw,
                                         int base, int gi, const Sgn& sg) {
    // w0 (cross SW8) ∥ w4 (local bit5)
    { const h2 ts = u2h(tw[base + 0] ^ (MOD ? sg.m0 : sg.n0)); cross_ry<SW8>(st, ts); }
    { const h2 t = u2h(tw[base + 4] ^ (MOD ? sg.g4 : 0u));
      local_ry<5, MOD ? 0x10 : 0>(st, t); }
    // w1 (cross SW4) ∥ w5 (local bit4)
    { const h2 ts = u2h(tw[base + 1] ^ (MOD ? sg.m1 : sg.n1)); cross_ry<SW4>(st, ts); }
    local_ry<4, MOD ? 0x28 : 0>(st, u2h(tw[base + 5]));
    // w2 (cross SW2) ∥ w6 (local bit3)
    { const h2 ts = u2h(tw[base + 2] ^ (MOD ? sg.m2 : sg.n2)); cross_ry<SW2>(st, ts); }
    local_ry<3, MOD ? 0x14 : 0>(st, u2h(tw[base + 6]));
    // w3 (cross SW1; MOD: extra flip on r bit5 half) ∥ w7 (local bit2)
    {
        const h2 ts = u2h(tw[base + 3] ^ (MOD ? sg.m3 : sg.n3));
        if constexpr (MOD) {
            const h2 th = u2h(h2u(ts) ^ SGN2);
#pragma unroll
            for (int r = 0; r < 32; ++r)  st[r] = fma2(ts, swzh<SW1>(st[r]), st[r]);
#pragma unroll
            for (int r = 32; r < 64; ++r) st[r] = fma2(th, swzh<SW1>(st[r]), st[r]);
        } else {
            cross_ry<SW1>(st, ts);
        }
    }
    local_ry<2, MOD ? 0x0A : 0>(st, u2h(tw[base + 7]));
    // trailing pure-VALU wires
    local_ry<1, MOD ? 0x05 : 0>(st, u2h(tw[base + 8]));
    local_ry<0, MOD ? 0x02 : 0>(st, u2h(tw[base + 9]));
    if constexpr (GS) {
        const h2 g = u2h(tw[gi]);
#pragma unroll
        for (int r = 0; r < 64; ++r) st[r] = g * st[r];        // v_pk_mul_f16
    }
}

// ---- prep: tan table [10..59], gamma_A h2 [60], gamma_B^2 f32 [61],
//            layer-0 (cos,sin) f32 pairs [64..83] ----
__global__ void __launch_bounds__(64) qnn_prep(const float* __restrict__ params,
                                               u32* __restrict__ ws) {
    const int l = threadIdx.x;
    if (l < 60) {
        float s, c;
        __sincosf(params[l] * 0.5f, &s, &c);
        const float t = s / c;
        const h2 t2 = { (_Float16)t, (_Float16)t };
        ws[l] = h2u(t2);
    }
    if (l < 10) {
        float s, c;
        __sincosf(params[l] * 0.5f, &s, &c);
        ws[64 + 2*l]     = f2u(c);
        ws[64 + 2*l + 1] = f2u(s);
    }
    if (l == 0) {
        float gA = 1.f;
        for (int k = 10; k < 30; ++k) gA *= __cosf(params[k] * 0.5f);
        const h2 g2 = { (_Float16)gA, (_Float16)gA };
        ws[60] = h2u(g2);
        float gB = 1.f;
        for (int k = 30; k < 60; ++k) gB *= __cosf(params[k] * 0.5f);
        ws[61] = f2u(gB * gB);
    }
}

__global__ void __launch_bounds__(256) qnn_kernel(
    const float* __restrict__ x,       // (B, 10)
    const u32*   __restrict__ tw,      // (84,) tables (see prep)
    const float* __restrict__ w_cls,   // (16, 10)
    const float* __restrict__ b_cls,   // (16,)
    float* __restrict__ out,           // (B, 16)
    int batch)
{
    const int lane = threadIdx.x & 63;
    const int wid  = threadIdx.x >> 6;
    const int wave = blockIdx.x * (blockDim.x >> 6) + wid;
    const int g    = lane & 15;                   // group lane
    const int b    = wave * 4 + (lane >> 4);      // this lane's batch element

    // ---- own wire's complex 2-vector after RY layer 0:
    //      alpha = (ct*c, st*s), beta = (st*c, -ct*s) ----
    float Are, Aim, Bre, Bim;
    {
        const int q = (g < NQ) ? g : 0;
        float cxe, sxe;
        __sincosf(x[b * NQ + q] * 0.5f, &sxe, &cxe);
        const float ct = u2f(tw[64 + 2*q]), st_ = u2f(tw[64 + 2*q + 1]);
        Are = ct * cxe;  Aim = st_ * sxe;
        Bre = st_ * cxe; Bim = -(ct * sxe);
    }

    // group-local broadcasts of all 10 wires' (A,B)
#define BCW(Q) const float Ar##Q = swzf<GBC(Q)>(Are), Ai##Q = swzf<GBC(Q)>(Aim), \
                           Br##Q = swzf<GBC(Q)>(Bre), Bi##Q = swzf<GBC(Q)>(Bim);
    BCW(0) BCW(1) BCW(2) BCW(3) BCW(4) BCW(5) BCW(6) BCW(7) BCW(8) BCW(9)
#undef BCW

    // ---- sign words (unchanged from R15/16) ----
    Sgn sg;
    sg.n0 = (g & 8) ? 0 : SGN2;  sg.m0 = sg.n0 ^ ((g & 4) ? SGN2 : 0);
    sg.n1 = (g & 4) ? 0 : SGN2;  sg.m1 = sg.n1 ^ ((((g >> 3) ^ (g >> 1)) & 1) ? SGN2 : 0);
    sg.n2 = (g & 2) ? 0 : SGN2;  sg.m2 = sg.n2 ^ ((((g >> 2) ^ g) & 1) ? SGN2 : 0);
    sg.n3 = (g & 1) ? 0 : SGN2;  sg.m3 = sg.n3 ^ (((g >> 1) & 1) ? SGN2 : 0);
    sg.g4 = (g & 1) ? SGN2 : 0;

    // ---- X = C * R0 * |enc> built directly (complex tensor product) ----
    const c32 w0 = (g & 8) ? c32{Br0, Bi0} : c32{Ar0, Ai0};
    const c32 w1 = (g & 4) ? c32{Br1, Bi1} : c32{Ar1, Ai1};
    const c32 w2 = (g & 2) ? c32{Br2, Bi2} : c32{Ar2, Ai2};
    const c32 w3 = (g & 1) ? c32{Br3, Bi3} : c32{Ar3, Ai3};
    c32 F = cmul(cmul(w0, w1), cmul(w2, w3));
    const u32 lps = (__popc(g & (g >> 1) & 0x7) & 1) ? SGN : 0;  // lane-lane CZ
    F.re = u2f(f2u(F.re) ^ lps);
    F.im = u2f(f2u(F.im) ^ lps);

    // boundary CZ pair (wire3 = g.b0, wire4 = r.b5): negate beta4 on odd lanes
    const u32 bs = (g & 1) ? SGN : 0;
    const c32 a4 = {Ar4, Ai4};
    const c32 b4 = {u2f(f2u(Br4) ^ bs), u2f(f2u(Bi4) ^ bs)};

    // uu[k], k = r>>3 bits (r.b5, r.b4, r.b3) = wires 4,5,6
    c32 uu[8];
    {
        const c32 u0 = cmul(F, a4), u1 = cmul(F, b4);
        const c32 a5 = {Ar5, Ai5}, b5 = {Br5, Bi5};
        const c32 t00 = cmul(u0, a5), t01 = cmul(u0, b5);
        const c32 t10 = cmul(u1, a5), t11 = cmul(u1, b5);
        const c32 a6 = {Ar6, Ai6}, b6 = {Br6, Bi6};
        uu[0] = cmul(t00, a6); uu[1] = cmul(t00, b6);
        uu[2] = cmul(t01, a6); uu[3] = cmul(t01, b6);
        uu[4] = cmul(t10, a6); uu[5] = cmul(t10, b6);
        uu[6] = cmul(t11, a6); uu[7] = cmul(t11, b6);
    }
    // vv[j], j = r&7 bits (r.b2, r.b1, r.b0) = wires 7,8,9
    c32 vv[8];
    {
        const c32 a7 = {Ar7, Ai7}, b7 = {Br7, Bi7};
        const c32 a8 = {Ar8, Ai8}, b8 = {Br8, Bi8};
        const c32 q00 = cmul(a7, a8), q01 = cmul(a7, b8);
        const c32 q10 = cmul(b7, a8), q11 = cmul(b7, b8);
        const c32 a9 = {Ar9, Ai9}, b9 = {Br9, Bi9};
        vv[0] = cmul(q00, a9); vv[1] = cmul(q00, b9);
        vv[2] = cmul(q01, a9); vv[3] = cmul(q01, b9);
        vv[4] = cmul(q10, a9); vv[5] = cmul(q10, b9);
        vv[6] = cmul(q11, a9); vv[7] = cmul(q11, b9);
    }

    h2 st[64];
#pragma unroll
    for (int r = 0; r < 64; ++r) {
        const c32 m = cmul(uu[r >> 3], vv[r & 7]);
        if (__popc(r & (r >> 1) & 0x1F) & 1)   // r-r CZ pairs: compile-time sign
            st[r] = __builtin_bit_cast(h2, __builtin_amdgcn_cvt_pkrtz(-m.re, -m.im));
        else
            st[r] = __builtin_bit_cast(h2, __builtin_amdgcn_cvt_pkrtz(m.re, m.im));
    }

    // ---- layers: R1 R2' R3 R4' R5 (rows 1..5; MOD at 2',4'); gamma_A after 2' ----
    ry_layer<false, false>(st, tw, 10,  0, sg);
    ry_layer<true , true >(st, tw, 20, 60, sg);
    ry_layer<false, false>(st, tw, 30,  0, sg);
    ry_layer<true , false>(st, tw, 40,  0, sg);
    ry_layer<false, false>(st, tw, 50,  0, sg);

    // ---- STREAMING probabilities + tree: st[r] dies at its fdot2 ----
    float f4 = 0.f, f5 = 0.f, f6 = 0.f, f7 = 0.f, f8 = 0.f, f9 = 0.f, pt = 0.f;
#pragma unroll
    for (int i = 0; i < 8; ++i) {
        float p[8];
#pragma unroll
        for (int j = 0; j < 8; ++j)
            p[j] = __builtin_amdgcn_fdot2(st[8*i + j], st[8*i + j], 0.f, false);
        const float a0 = p[0] + p[1], a1 = p[2] + p[3];
        const float a2 = p[4] + p[5], a3 = p[6] + p[7];
        f9 += (p[0] - p[1]) + (p[2] - p[3]) + (p[4] - p[5]) + (p[6] - p[7]);
        const float b0 = a0 + a1, b1 = a2 + a3;
        f8 += (a0 - a1) + (a2 - a3);
        const float c = b0 + b1;
        f7 += b0 - b1;
        f6 += (i & 1) ? -c : c;
        f5 += (i & 2) ? -c : c;
        f4 += (i & 4) ? -c : c;
        pt += c;
    }

    // ---- normalize NOW (f32) so the f16 packed butterflies can't overflow ----
    {
        const float gB2 = u2f(tw[61]);
        f4 *= gB2; f5 *= gB2; f6 *= gB2; f7 *= gB2;
        f8 *= gB2; f9 *= gB2; pt *= gB2;
    }

    // group sums for f4..f9: packed pairwise, 4-stage butterflies
    h2 p45 = __builtin_bit_cast(h2, __builtin_amdgcn_cvt_pkrtz(f4, f5));
    h2 p67 = __builtin_bit_cast(h2, __builtin_amdgcn_cvt_pkrtz(f6, f7));
    h2 p89 = __builtin_bit_cast(h2, __builtin_amdgcn_cvt_pkrtz(f8, f9));
    p45 += swzh<SW1>(p45);  p67 += swzh<SW1>(p67);  p89 += swzh<SW1>(p89);
    p45 += swzh<SW2>(p45);  p67 += swzh<SW2>(p67);  p89 += swzh<SW2>(p89);
    p45 += swzh<SW4>(p45);  p67 += swzh<SW4>(p67);  p89 += swzh<SW4>(p89);
    p45 += swzh<SW8>(p45);  p67 += swzh<SW8>(p67);  p89 += swzh<SW8>(p89);
    const float g4v = (float)p45[0], g5v = (float)p45[1];
    const float g6v = (float)p67[0], g7v = (float)p67[1];
    const float g8v = (float)p89[0], g9v = (float)p89[1];

    // 4-stage WHT on pt within group (f32)
    float v = pt;
    {
        float p;
        p = swzf<SW1>(v);  v = p + u2f(f2u(v) ^ ((g & 1) ? SGN : 0u));
        p = swzf<SW2>(v);  v = p + u2f(f2u(v) ^ ((g & 2) ? SGN : 0u));
        p = swzf<SW4>(v);  v = p + u2f(f2u(v) ^ ((g & 4) ? SGN : 0u));
        p = swzf<SW8>(v);  v = p + u2f(f2u(v) ^ ((g & 8) ? SGN : 0u));
    }
    const float e0 = swzf<GBC(8)>(v);   // wire0 <- group lane 8
    const float e1 = swzf<GBC(4)>(v);   // wire1
    const float e2 = swzf<GBC(2)>(v);   // wire2
    const float e3 = swzf<GBC(1)>(v);   // wire3

    // ---- linear head (accumulators already normalized) ----
    {
        const float* wr = w_cls + g * NQ;
        float dot = e0 * wr[0];
        dot = fmaf(e1,  wr[1], dot);
        dot = fmaf(e2,  wr[2], dot);
        dot = fmaf(e3,  wr[3], dot);
        dot = fmaf(g4v, wr[4], dot);
        dot = fmaf(g5v, wr[5], dot);
        dot = fmaf(g6v, wr[6], dot);
        dot = fmaf(g7v, wr[7], dot);
        dot = fmaf(g8v, wr[8], dot);
        dot = fmaf(g9v, wr[9], dot);
        out[b * NCLS + g] = dot + b_cls[g];
    }
}

extern "C" void kernel_launch(void* const* d_in, const int* in_sizes, int n_in,
                              void* d_out, int out_size, void* d_ws, size_t ws_size,
                              hipStream_t stream) {
    const float* x      = (const float*)d_in[0];
    const float* params = (const float*)d_in[1];
    const float* w_cls  = (const float*)d_in[2];
    const float* b_cls  = (const float*)d_in[3];
    float* out = (float*)d_out;
    u32*   ws  = (u32*)d_ws;

    const int batch = in_sizes[0] / NQ;            // 65536
    const int WAVES_PER_BLOCK = 4;                 // 256 threads
    const int ELEMS_PER_BLOCK = WAVES_PER_BLOCK * 4;

    hipLaunchKernelGGL(qnn_prep, dim3(1), dim3(64), 0, stream, params, ws);

    dim3 block(64 * WAVES_PER_BLOCK);
    dim3 grid(batch / ELEMS_PER_BLOCK);            // 65536/16 = 4096
    hipLaunchKernelGGL(qnn_kernel, grid, block, 0, stream,
                       x, (const u32*)ws, w_cls, b_cls, out, batch);
}

// Round 20
// 135.728 us; speedup vs baseline: 2.7041x; 1.0068x over previous
//
#include <hip/hip_runtime.h>
#include <math.h>

// Batched 10-qubit statevector sim — FOUR batch elements per wave.
// Each 16-lane group owns one element: amp a = (lane&15)<<6 | r, r in [0,64).
// State = 64 packed-f16 (re,im) regs per lane. Wire w acts on amp bit 9-w:
//   wires 0-3: cross within 16-group, masks 8/4/2/1 via ds_swizzle (DS pipe)
//   wires 4-9: in-register local shear (v_pk_fma_f16), interleaved (R19)
// Round-20: REGISTER-PEAK SURGERY. R19: occupancy 40% (~160 VGPR — init
// holds 40 broadcast f32 + 32 f32 uu/vv while st[64] is built), VALU/DS
// makespans ~109/107us vs dur 136.6. Fix: (a) init consumes broadcasts
// just-in-time (vv first, then F as running product, then uu; peak ~110
// regs), (b) __launch_bounds__(256,4) pins allocator at <=128 VGPR ->
// 4 waves/SIMD. Gate loop / signs / epilogue identical to R19:
//  - layer-0 folded into init (complex product state X = C R0 |enc>)
//  - layers base10(plain) 20(MOD) 30(plain) 40(MOD) 50(plain), wires
//    interleaved w0,w4,w1,w5,w2,w6,w3,w7,w8,w9 (commuting)
//  - gamma_A in-state after base20; gamma_B^2 on f32 accumulators (R18 fix)
//  - CZ absorbed: lane-lane mask 0x7 -> F sign; boundary -> beta4 flip on
//    odd lanes; r-r mask 0x1F -> sign at init; MOD wire signs per R15.

typedef unsigned int u32;
typedef _Float16 h2 __attribute__((ext_vector_type(2)));

constexpr int NQ = 10;
constexpr int NCLS = 16;
constexpr u32 SGN  = 0x80000000u;
constexpr u32 SGN2 = 0x80008000u;

__device__ __forceinline__ float i2f(int i) { return __builtin_bit_cast(float, i); }
__device__ __forceinline__ int   f2i(float f) { return __builtin_bit_cast(int, f); }
__device__ __forceinline__ u32   f2u(float f) { return __builtin_bit_cast(u32, f); }
__device__ __forceinline__ float u2f(u32 u)   { return __builtin_bit_cast(float, u); }
__device__ __forceinline__ u32   h2u(h2 v)    { return __builtin_bit_cast(u32, v); }
__device__ __forceinline__ h2    u2h(u32 u)   { return __builtin_bit_cast(h2, u); }

__device__ __forceinline__ h2 fma2(h2 a, h2 b, h2 c) {
    return __builtin_elementwise_fma(a, b, c);          // v_pk_fma_f16
}

template<int SWZ>
__device__ __forceinline__ h2 swzh(h2 v) {
    return u2h((u32)__builtin_amdgcn_ds_swizzle(__builtin_bit_cast(int, v), SWZ));
}
template<int SWZ>
__device__ __forceinline__ float swzf(float v) {
    return i2f(__builtin_amdgcn_ds_swizzle(f2i(v), SWZ));
}

constexpr int SW1 = 0x041F;   // lane^1 (within 16-group)
constexpr int SW2 = 0x081F;   // lane^2
constexpr int SW4 = 0x101F;   // lane^4
constexpr int SW8 = 0x201F;   // lane^8
#define GBC(q) (0x10 | ((q) << 5))   // 16-group broadcast of group-lane q

// ---- complex f32 helpers ----
struct c32 { float re, im; };
__device__ __forceinline__ c32 cmul(c32 a, c32 b) {
    return { fmaf(a.re, b.re, -(a.im * b.im)),
             fmaf(a.re, b.im,  a.im * b.re) };
}

// ---- cross shear: st[r] += ts * partner(st[r]) over all 64 regs ----
template<int SWZ>
__device__ __forceinline__ void cross_ry(h2 (&st)[64], h2 ts) {
#pragma unroll
    for (int r = 0; r < 64; ++r) st[r] = fma2(ts, swzh<SWZ>(st[r]), st[r]);
}

// ---- local shear on r-bit B; NB = compile-time neighbor-sign mask ----
template<int B, int NB>
__device__ __forceinline__ void local_ry(h2 (&st)[64], h2 t) {
#pragma unroll
    for (int r0 = 0; r0 < 64; ++r0) {
        if ((r0 & (1 << B)) == 0) {
            const int r1 = r0 | (1 << B);
            const h2 a0 = st[r0], a1 = st[r1];
            if ((__builtin_popcount(r0 & NB) & 1) == 0) {
                st[r0] = fma2(t, -a1, a0);
                st[r1] = fma2(t,  a0, a1);
            } else {
                st[r0] = fma2(t,  a1, a0);
                st[r1] = fma2(t, -a0, a1);
            }
        }
    }
}

// per-lane sign words: nX plain, mX CZ-conjugated; g4 = wire4 MOD lane word
struct Sgn { u32 n0, m0, n1, m1, n2, m2, n3, m3, g4; };

// One RY layer, wires INTERLEAVED (cross/local alternating — all commute).
template<bool MOD, bool GS>
__device__ __forceinline__ void ry_layer(h2 (&st)[64], const u32* __restrict__ tw,
                                         int base, int gi, const Sgn& sg) {
    { const h2 ts = u2h(tw[base + 0] ^ (MOD ? sg.m0 : sg.n0)); cross_ry<SW8>(st, ts); }
    { const h2 t = u2h(tw[base + 4] ^ (MOD ? sg.g4 : 0u));
      local_ry<5, MOD ? 0x10 : 0>(st, t); }
    { const h2 ts = u2h(tw[base + 1] ^ (MOD ? sg.m1 : sg.n1)); cross_ry<SW4>(st, ts); }
    local_ry<4, MOD ? 0x28 : 0>(st, u2h(tw[base + 5]));
    { const h2 ts = u2h(tw[base + 2] ^ (MOD ? sg.m2 : sg.n2)); cross_ry<SW2>(st, ts); }
    local_ry<3, MOD ? 0x14 : 0>(st, u2h(tw[base + 6]));
    {
        const h2 ts = u2h(tw[base + 3] ^ (MOD ? sg.m3 : sg.n3));
        if constexpr (MOD) {
            const h2 th = u2h(h2u(ts) ^ SGN2);
#pragma unroll
            for (int r = 0; r < 32; ++r)  st[r] = fma2(ts, swzh<SW1>(st[r]), st[r]);
#pragma unroll
            for (int r = 32; r < 64; ++r) st[r] = fma2(th, swzh<SW1>(st[r]), st[r]);
        } else {
            cross_ry<SW1>(st, ts);
        }
    }
    local_ry<2, MOD ? 0x0A : 0>(st, u2h(tw[base + 7]));
    local_ry<1, MOD ? 0x05 : 0>(st, u2h(tw[base + 8]));
    local_ry<0, MOD ? 0x02 : 0>(st, u2h(tw[base + 9]));
    if constexpr (GS) {
        const h2 g = u2h(tw[gi]);
#pragma unroll
        for (int r = 0; r < 64; ++r) st[r] = g * st[r];        // v_pk_mul_f16
    }
}

// ---- prep: tan table [10..59], gamma_A h2 [60], gamma_B^2 f32 [61],
//            layer-0 (cos,sin) f32 pairs [64..83] ----
__global__ void __launch_bounds__(64) qnn_prep(const float* __restrict__ params,
                                               u32* __restrict__ ws) {
    const int l = threadIdx.x;
    if (l < 60) {
        float s, c;
        __sincosf(params[l] * 0.5f, &s, &c);
        const float t = s / c;
        const h2 t2 = { (_Float16)t, (_Float16)t };
        ws[l] = h2u(t2);
    }
    if (l < 10) {
        float s, c;
        __sincosf(params[l] * 0.5f, &s, &c);
        ws[64 + 2*l]     = f2u(c);
        ws[64 + 2*l + 1] = f2u(s);
    }
    if (l == 0) {
        float gA = 1.f;
        for (int k = 10; k < 30; ++k) gA *= __cosf(params[k] * 0.5f);
        const h2 g2 = { (_Float16)gA, (_Float16)gA };
        ws[60] = h2u(g2);
        float gB = 1.f;
        for (int k = 30; k < 60; ++k) gB *= __cosf(params[k] * 0.5f);
        ws[61] = f2u(gB * gB);
    }
}

__global__ void __launch_bounds__(256, 4) qnn_kernel(
    const float* __restrict__ x,       // (B, 10)
    const u32*   __restrict__ tw,      // (84,) tables (see prep)
    const float* __restrict__ w_cls,   // (16, 10)
    const float* __restrict__ b_cls,   // (16,)
    float* __restrict__ out,           // (B, 16)
    int batch)
{
    const int lane = threadIdx.x & 63;
    const int wid  = threadIdx.x >> 6;
    const int wave = blockIdx.x * (blockDim.x >> 6) + wid;
    const int g    = lane & 15;                   // group lane
    const int b    = wave * 4 + (lane >> 4);      // this lane's batch element

    // ---- own wire's complex 2-vector after RY layer 0 ----
    float Are, Aim, Bre, Bim;
    {
        const int q = (g < NQ) ? g : 0;
        float cxe, sxe;
        __sincosf(x[b * NQ + q] * 0.5f, &sxe, &cxe);
        const float ct = u2f(tw[64 + 2*q]), st_ = u2f(tw[64 + 2*q + 1]);
        Are = ct * cxe;  Aim = st_ * sxe;
        Bre = st_ * cxe; Bim = -(ct * sxe);
    }

    // JIT broadcast fetch of wire Q's (A,B) — consumed immediately (low liveness)
#define FETCH_AB(Q, ar, ai, br, bi) \
    const float ar = swzf<GBC(Q)>(Are), ai = swzf<GBC(Q)>(Aim), \
                br = swzf<GBC(Q)>(Bre), bi = swzf<GBC(Q)>(Bim);

    // ---- sign words ----
    Sgn sg;
    sg.n0 = (g & 8) ? 0 : SGN2;  sg.m0 = sg.n0 ^ ((g & 4) ? SGN2 : 0);
    sg.n1 = (g & 4) ? 0 : SGN2;  sg.m1 = sg.n1 ^ ((((g >> 3) ^ (g >> 1)) & 1) ? SGN2 : 0);
    sg.n2 = (g & 2) ? 0 : SGN2;  sg.m2 = sg.n2 ^ ((((g >> 2) ^ g) & 1) ? SGN2 : 0);
    sg.n3 = (g & 1) ? 0 : SGN2;  sg.m3 = sg.n3 ^ (((g >> 1) & 1) ? SGN2 : 0);
    sg.g4 = (g & 1) ? SGN2 : 0;

    // ---- vv[j] first (wires 7,8,9), JIT fetches ----
    c32 vv[8];
    {
        c32 q00, q01, q10, q11;
        {
            FETCH_AB(7, ar7, ai7, br7, bi7)
            FETCH_AB(8, ar8, ai8, br8, bi8)
            const c32 a7 = {ar7, ai7}, b7 = {br7, bi7};
            const c32 a8 = {ar8, ai8}, b8 = {br8, bi8};
            q00 = cmul(a7, a8); q01 = cmul(a7, b8);
            q10 = cmul(b7, a8); q11 = cmul(b7, b8);
        }
        FETCH_AB(9, ar9, ai9, br9, bi9)
        const c32 a9 = {ar9, ai9}, b9 = {br9, bi9};
        vv[0] = cmul(q00, a9); vv[1] = cmul(q00, b9);
        vv[2] = cmul(q01, a9); vv[3] = cmul(q01, b9);
        vv[4] = cmul(q10, a9); vv[5] = cmul(q10, b9);
        vv[6] = cmul(q11, a9); vv[7] = cmul(q11, b9);
    }

    // ---- F = product of wires 0-3 (selected by g bits), running product ----
    c32 F;
    {
        FETCH_AB(0, ar0, ai0, br0, bi0)
        F = (g & 8) ? c32{br0, bi0} : c32{ar0, ai0};
    }
    {
        FETCH_AB(1, ar1, ai1, br1, bi1)
        F = cmul(F, (g & 4) ? c32{br1, bi1} : c32{ar1, ai1});
    }
    {
        FETCH_AB(2, ar2, ai2, br2, bi2)
        F = cmul(F, (g & 2) ? c32{br2, bi2} : c32{ar2, ai2});
    }
    {
        FETCH_AB(3, ar3, ai3, br3, bi3)
        F = cmul(F, (g & 1) ? c32{br3, bi3} : c32{ar3, ai3});
    }
    const u32 lps = (__popc(g & (g >> 1) & 0x7) & 1) ? SGN : 0;  // lane-lane CZ
    F.re = u2f(f2u(F.re) ^ lps);
    F.im = u2f(f2u(F.im) ^ lps);

    // ---- uu[k] (wires 4,5,6), JIT fetches; boundary CZ folds into beta4 ----
    c32 uu[8];
    {
        c32 u0, u1;
        {
            FETCH_AB(4, ar4, ai4, br4, bi4)
            const u32 bs = (g & 1) ? SGN : 0;
            const c32 a4 = {ar4, ai4};
            const c32 b4 = {u2f(f2u(br4) ^ bs), u2f(f2u(bi4) ^ bs)};
            u0 = cmul(F, a4); u1 = cmul(F, b4);
        }
        c32 t00, t01, t10, t11;
        {
            FETCH_AB(5, ar5, ai5, br5, bi5)
            const c32 a5 = {ar5, ai5}, b5 = {br5, bi5};
            t00 = cmul(u0, a5); t01 = cmul(u0, b5);
            t10 = cmul(u1, a5); t11 = cmul(u1, b5);
        }
        FETCH_AB(6, ar6, ai6, br6, bi6)
        const c32 a6 = {ar6, ai6}, b6 = {br6, bi6};
        uu[0] = cmul(t00, a6); uu[1] = cmul(t00, b6);
        uu[2] = cmul(t01, a6); uu[3] = cmul(t01, b6);
        uu[4] = cmul(t10, a6); uu[5] = cmul(t10, b6);
        uu[6] = cmul(t11, a6); uu[7] = cmul(t11, b6);
    }
#undef FETCH_AB

    h2 st[64];
#pragma unroll
    for (int r = 0; r < 64; ++r) {
        const c32 m = cmul(uu[r >> 3], vv[r & 7]);
        if (__popc(r & (r >> 1) & 0x1F) & 1)   // r-r CZ pairs: compile-time sign
            st[r] = __builtin_bit_cast(h2, __builtin_amdgcn_cvt_pkrtz(-m.re, -m.im));
        else
            st[r] = __builtin_bit_cast(h2, __builtin_amdgcn_cvt_pkrtz(m.re, m.im));
    }

    // ---- layers: R1 R2' R3 R4' R5 (MOD at 2',4'); gamma_A after 2' ----
    ry_layer<false, false>(st, tw, 10,  0, sg);
    ry_layer<true , true >(st, tw, 20, 60, sg);
    ry_layer<false, false>(st, tw, 30,  0, sg);
    ry_layer<true , false>(st, tw, 40,  0, sg);
    ry_layer<false, false>(st, tw, 50,  0, sg);

    // ---- STREAMING probabilities + tree: st[r] dies at its fdot2 ----
    float f4 = 0.f, f5 = 0.f, f6 = 0.f, f7 = 0.f, f8 = 0.f, f9 = 0.f, pt = 0.f;
#pragma unroll
    for (int i = 0; i < 8; ++i) {
        float p[8];
#pragma unroll
        for (int j = 0; j < 8; ++j)
            p[j] = __builtin_amdgcn_fdot2(st[8*i + j], st[8*i + j], 0.f, false);
        const float a0 = p[0] + p[1], a1 = p[2] + p[3];
        const float a2 = p[4] + p[5], a3 = p[6] + p[7];
        f9 += (p[0] - p[1]) + (p[2] - p[3]) + (p[4] - p[5]) + (p[6] - p[7]);
        const float b0 = a0 + a1, b1 = a2 + a3;
        f8 += (a0 - a1) + (a2 - a3);
        const float c = b0 + b1;
        f7 += b0 - b1;
        f6 += (i & 1) ? -c : c;
        f5 += (i & 2) ? -c : c;
        f4 += (i & 4) ? -c : c;
        pt += c;
    }

    // ---- normalize (f32) before f16 packing: deferred gamma_B^2 ----
    {
        const float gB2 = u2f(tw[61]);
        f4 *= gB2; f5 *= gB2; f6 *= gB2; f7 *= gB2;
        f8 *= gB2; f9 *= gB2; pt *= gB2;
    }

    // group sums for f4..f9: packed pairwise, 4-stage butterflies
    h2 p45 = __builtin_bit_cast(h2, __builtin_amdgcn_cvt_pkrtz(f4, f5));
    h2 p67 = __builtin_bit_cast(h2, __builtin_amdgcn_cvt_pkrtz(f6, f7));
    h2 p89 = __builtin_bit_cast(h2, __builtin_amdgcn_cvt_pkrtz(f8, f9));
    p45 += swzh<SW1>(p45);  p67 += swzh<SW1>(p67);  p89 += swzh<SW1>(p89);
    p45 += swzh<SW2>(p45);  p67 += swzh<SW2>(p67);  p89 += swzh<SW2>(p89);
    p45 += swzh<SW4>(p45);  p67 += swzh<SW4>(p67);  p89 += swzh<SW4>(p89);
    p45 += swzh<SW8>(p45);  p67 += swzh<SW8>(p67);  p89 += swzh<SW8>(p89);
    const float g4v = (float)p45[0], g5v = (float)p45[1];
    const float g6v = (float)p67[0], g7v = (float)p67[1];
    const float g8v = (float)p89[0], g9v = (float)p89[1];

    // 4-stage WHT on pt within group (f32)
    float v = pt;
    {
        float p;
        p = swzf<SW1>(v);  v = p + u2f(f2u(v) ^ ((g & 1) ? SGN : 0u));
        p = swzf<SW2>(v);  v = p + u2f(f2u(v) ^ ((g & 2) ? SGN : 0u));
        p = swzf<SW4>(v);  v = p + u2f(f2u(v) ^ ((g & 4) ? SGN : 0u));
        p = swzf<SW8>(v);  v = p + u2f(f2u(v) ^ ((g & 8) ? SGN : 0u));
    }
    const float e0 = swzf<GBC(8)>(v);   // wire0 <- group lane 8
    const float e1 = swzf<GBC(4)>(v);   // wire1
    const float e2 = swzf<GBC(2)>(v);   // wire2
    const float e3 = swzf<GBC(1)>(v);   // wire3

    // ---- linear head ----
    {
        const float* wr = w_cls + g * NQ;
        float dot = e0 * wr[0];
        dot = fmaf(e1,  wr[1], dot);
        dot = fmaf(e2,  wr[2], dot);
        dot = fmaf(e3,  wr[3], dot);
        dot = fmaf(g4v, wr[4], dot);
        dot = fmaf(g5v, wr[5], dot);
        dot = fmaf(g6v, wr[6], dot);
        dot = fmaf(g7v, wr[7], dot);
        dot = fmaf(g8v, wr[8], dot);
        dot = fmaf(g9v, wr[9], dot);
        out[b * NCLS + g] = dot + b_cls[g];
    }
}

extern "C" void kernel_launch(void* const* d_in, const int* in_sizes, int n_in,
                              void* d_out, int out_size, void* d_ws, size_t ws_size,
                              hipStream_t stream) {
    const float* x      = (const float*)d_in[0];
    const float* params = (const float*)d_in[1];
    const float* w_cls  = (const float*)d_in[2];
    const float* b_cls  = (const float*)d_in[3];
    float* out = (float*)d_out;
    u32*   ws  = (u32*)d_ws;

    const int batch = in_sizes[0] / NQ;            // 65536
    const int WAVES_PER_BLOCK = 4;                 // 256 threads
    const int ELEMS_PER_BLOCK = WAVES_PER_BLOCK * 4;

    hipLaunchKernelGGL(qnn_prep, dim3(1), dim3(64), 0, stream, params, ws);

    dim3 block(64 * WAVES_PER_BLOCK);
    dim3 grid(batch / ELEMS_PER_BLOCK);            // 65536/16 = 4096
    hipLaunchKernelGGL(qnn_kernel, grid, block, 0, stream,
                       x, (const u32*)ws, w_cls, b_cls, out, batch);
}